// Round 5
// baseline (19757.146 us; speedup 1.0000x reference)
//
#include <hip/hip_runtime.h>
#include <math.h>

#define T_STEPS 128
#define BATCH   512
#define NTOK    512
#define NINP    512
#define NHID    600
#define NBK     6
#define BS      100
#define HH      4
#define DK      64
#define DV      85
#define ATT     340
#define H2      4
#define DK2     32
#define DV2     32
#define G3      300
#define VN      340      // v cols in chunk GEMM out
#define KAPN    400      // kappa cols
#define CN      740      // real cols (VN+KAPN)
#define CNP     768      // padded
#define UNP     384      // U N padded 300->384
#define UK0     128      // U per-segment K (85 pad 128)
#define KV0     512      // chunk per-segment K
#define DECKP   640
#define NSAMP   2

typedef __attribute__((ext_vector_type(8))) short short8;
typedef __attribute__((ext_vector_type(4))) float f32x4;

__device__ __forceinline__ float sigf(float x) { return 1.f / (1.f + expf(-x)); }
__device__ __forceinline__ unsigned short f2b(float f) {
    unsigned u = __float_as_uint(f);
    unsigned r = (u + 0x7fffu + ((u >> 16) & 1u)) >> 16;
    return (unsigned short)r;
}
__device__ __forceinline__ float b2f(unsigned short u) {
    return __uint_as_float(((unsigned)u) << 16);
}
// 3-way split: x ~= hi + mid + lo (each bf16); residual ~2^-25 |x|
__device__ __forceinline__ void split3(float x, unsigned short& hi,
                                       unsigned short& mid, unsigned short& lo) {
    hi = f2b(x);
    float r1 = x - b2f(hi);
    mid = f2b(r1);
    lo = f2b(r1 - b2f(mid));
}

struct ZOff { int div; long s1; long s2; };
__device__ __forceinline__ long zoff(ZOff z, int bz) {
    return (long)(bz / z.div) * z.s1 + (long)(bz % z.div) * z.s2;
}

// ===== bf16x6 MFMA GEMM: fp32-class C = A@B^T (+bias) via 6 segment passes =====
// A [rows][3*K0] (segments hi|mid|lo), B transposed [Ntiles*128][3*K0] same layout.
// Pass p multiplies A seg segA[p] by B seg segB[p], all into one fp32 accumulator.
__global__ __launch_bounds__(256) void gemm6(
    const unsigned short* __restrict__ A, long aZ, int aZdiv,
    const unsigned short* __restrict__ B, long bZ,
    float* __restrict__ C, long cZ, int ldc, int Nreal,
    const float* __restrict__ bias, int K0)
{
    const int z = blockIdx.z;
    A += (long)(z / aZdiv) * aZ;
    B += (long)z * bZ;
    C += (long)z * cZ;
    const int LDA = 3 * K0;
    const int m0 = blockIdx.y * 128, n0 = blockIdx.x * 128;
    __shared__ __align__(16) unsigned short As[128 * 64];
    __shared__ __align__(16) unsigned short Bs[128 * 64];
    const int tid = threadIdx.x;
    const int lane = tid & 63;
    const int wid = tid >> 6;
    const int wr = wid >> 1, wc = wid & 1;

    f32x4 acc[4][4];
#pragma unroll
    for (int m = 0; m < 4; m++)
#pragma unroll
        for (int n = 0; n < 4; n++)
#pragma unroll
            for (int v = 0; v < 4; v++) acc[m][n][v] = 0.f;

    const int segA[6] = {0, 0, 1, 0, 2, 1};
    const int segB[6] = {0, 1, 0, 2, 0, 1};
    for (int p = 0; p < 6; p++) {
        const unsigned short* Ap = A + segA[p] * K0;
        const unsigned short* Bp = B + segB[p] * K0;
        for (int k0 = 0; k0 < K0; k0 += 64) {
            short8 ra[4], rb[4];
#pragma unroll
            for (int q = 0; q < 4; q++) {
                int idx = (q << 8) + tid;
                int r = idx >> 3, ce = (idx & 7) << 3;
                ra[q] = *(const short8*)&Ap[(long)(m0 + r) * LDA + k0 + ce];
                rb[q] = *(const short8*)&Bp[(long)(n0 + r) * LDA + k0 + ce];
            }
            __syncthreads();
#pragma unroll
            for (int q = 0; q < 4; q++) {
                int idx = (q << 8) + tid;
                int r = idx >> 3, ce = (idx & 7) << 3;
                *(short8*)&As[r * 64 + ce] = ra[q];
                *(short8*)&Bs[r * 64 + ce] = rb[q];
            }
            __syncthreads();
#pragma unroll
            for (int kk = 0; kk < 2; kk++) {
                short8 af[4], bfr[4];
#pragma unroll
                for (int m = 0; m < 4; m++)
                    af[m] = *(const short8*)&As[(wr * 64 + m * 16 + (lane & 15)) * 64 + kk * 32 + (lane >> 4) * 8];
#pragma unroll
                for (int n = 0; n < 4; n++)
                    bfr[n] = *(const short8*)&Bs[(wc * 64 + n * 16 + (lane & 15)) * 64 + kk * 32 + (lane >> 4) * 8];
#pragma unroll
                for (int m = 0; m < 4; m++)
#pragma unroll
                    for (int n = 0; n < 4; n++)
                        acc[m][n] = __builtin_amdgcn_mfma_f32_16x16x32_bf16(af[m], bfr[n], acc[m][n], 0, 0, 0);
            }
        }
    }
#pragma unroll
    for (int m = 0; m < 4; m++) {
        int rbase = m0 + wr * 64 + m * 16 + (lane >> 4) * 4;
#pragma unroll
        for (int n = 0; n < 4; n++) {
            int col = n0 + wc * 64 + n * 16 + (lane & 15);
            if (col < Nreal) {
                float bv = bias ? bias[col] : 0.f;
#pragma unroll
                for (int v = 0; v < 4; v++)
                    C[(long)(rbase + v) * ldc + col] = acc[m][n][v] + bv;
            }
        }
    }
}

// ===== plain bf16 MFMA GEMM (decoder only; output-side, proven safe in R3) =====
__global__ __launch_bounds__(256) void gemm_mfma(
    const unsigned short* __restrict__ A,
    const unsigned short* __restrict__ B,
    float* __restrict__ C, int ldc,
    const float* __restrict__ bias, int Kp)
{
    const int m0 = blockIdx.y * 128, n0 = blockIdx.x * 128;
    __shared__ __align__(16) unsigned short As[128 * 64];
    __shared__ __align__(16) unsigned short Bs[128 * 64];
    const int tid = threadIdx.x;
    const int lane = tid & 63;
    const int wid = tid >> 6;
    const int wr = wid >> 1, wc = wid & 1;

    f32x4 acc[4][4];
#pragma unroll
    for (int m = 0; m < 4; m++)
#pragma unroll
        for (int n = 0; n < 4; n++)
#pragma unroll
            for (int v = 0; v < 4; v++) acc[m][n][v] = 0.f;

    for (int k0 = 0; k0 < Kp; k0 += 64) {
        short8 ra[4], rb[4];
#pragma unroll
        for (int q = 0; q < 4; q++) {
            int idx = (q << 8) + tid;
            int r = idx >> 3, ce = (idx & 7) << 3;
            ra[q] = *(const short8*)&A[(long)(m0 + r) * Kp + k0 + ce];
            rb[q] = *(const short8*)&B[(long)(n0 + r) * Kp + k0 + ce];
        }
        __syncthreads();
#pragma unroll
        for (int q = 0; q < 4; q++) {
            int idx = (q << 8) + tid;
            int r = idx >> 3, ce = (idx & 7) << 3;
            *(short8*)&As[r * 64 + ce] = ra[q];
            *(short8*)&Bs[r * 64 + ce] = rb[q];
        }
        __syncthreads();
#pragma unroll
        for (int kk = 0; kk < 2; kk++) {
            short8 af[4], bfr[4];
#pragma unroll
            for (int m = 0; m < 4; m++)
                af[m] = *(const short8*)&As[(wr * 64 + m * 16 + (lane & 15)) * 64 + kk * 32 + (lane >> 4) * 8];
#pragma unroll
            for (int n = 0; n < 4; n++)
                bfr[n] = *(const short8*)&Bs[(wc * 64 + n * 16 + (lane & 15)) * 64 + kk * 32 + (lane >> 4) * 8];
#pragma unroll
            for (int m = 0; m < 4; m++)
#pragma unroll
                for (int n = 0; n < 4; n++)
                    acc[m][n] = __builtin_amdgcn_mfma_f32_16x16x32_bf16(af[m], bfr[n], acc[m][n], 0, 0, 0);
        }
    }
#pragma unroll
    for (int m = 0; m < 4; m++) {
        int rbase = m0 + wr * 64 + m * 16 + (lane >> 4) * 4;
#pragma unroll
        for (int n = 0; n < 4; n++) {
            int col = n0 + wc * 64 + n * 16 + (lane & 15);
            float bv = bias ? bias[col] : 0.f;
#pragma unroll
            for (int v = 0; v < 4; v++)
                C[(long)(rbase + v) * ldc + col] = acc[m][n][v] + bv;
        }
    }
}

// ===== fp32 SGEMM (setup-only small jobs) =====
__global__ __launch_bounds__(256) void sgemm(
    const float* __restrict__ A, ZOff za, int lda,
    const float* __restrict__ B, ZOff zb, int ldb,
    float* __restrict__ C, ZOff zc, int ldc,
    int M, int N, int K)
{
    const int bz = blockIdx.z;
    A += zoff(za, bz);
    B += zoff(zb, bz);
    C += zoff(zc, bz);
    const int m0 = blockIdx.y * 128, n0 = blockIdx.x * 64;
    __shared__ float As[16][132];
    __shared__ float Bs[16][68];
    const int tid = threadIdx.x;
    const int tm = tid >> 4, tn = tid & 15;
    const int ar = tid >> 1, ak = (tid & 1) * 8;
    const int bk = tid >> 4, bn = (tid & 15) * 4;

    float acc[8][4];
#pragma unroll
    for (int i = 0; i < 8; i++)
#pragma unroll
        for (int j = 0; j < 4; j++) acc[i][j] = 0.f;

    for (int k0 = 0; k0 < K; k0 += 16) {
        float av[8], bv[4];
#pragma unroll
        for (int j = 0; j < 8; j++) {
            int gk = k0 + ak + j;
            av[j] = (gk < K) ? A[(long)(m0 + ar) * lda + gk] : 0.f;
        }
#pragma unroll
        for (int j = 0; j < 4; j++) {
            int gk = k0 + bk, gn = n0 + bn + j;
            bv[j] = (gk < K && gn < N) ? B[(long)gk * ldb + gn] : 0.f;
        }
        __syncthreads();
#pragma unroll
        for (int j = 0; j < 8; j++) As[ak + j][ar] = av[j];
#pragma unroll
        for (int j = 0; j < 4; j++) Bs[bk][bn + j] = bv[j];
        __syncthreads();
#pragma unroll
        for (int kk = 0; kk < 16; kk++) {
            float a[8], b[4];
#pragma unroll
            for (int i = 0; i < 8; i++) a[i] = As[kk][tm * 8 + i];
#pragma unroll
            for (int j = 0; j < 4; j++) b[j] = Bs[kk][tn * 4 + j];
#pragma unroll
            for (int i = 0; i < 8; i++)
#pragma unroll
                for (int j = 0; j < 4; j++)
                    acc[i][j] += a[i] * b[j];
        }
    }
#pragma unroll
    for (int i = 0; i < 8; i++) {
        int gm = m0 + tm * 8 + i;
#pragma unroll
        for (int j = 0; j < 4; j++) {
            int gn = n0 + tn * 4 + j;
            if (gn < N) C[(long)gm * ldc + gn] = acc[i][j];
        }
    }
}

// ===== prep kernels =====
// WqT[h][d][w] = Wq_in[w][h*64+d]
__global__ __launch_bounds__(256) void prep_wqt(const float* __restrict__ Wq_in,
                                                float* __restrict__ WqT)
{
    int idx = blockIdx.x * 256 + threadIdx.x;
    if (idx >= HH * DK * BS) return;
    int h = idx / (DK * BS), r = idx - h * DK * BS, d = r / BS, w = r - d * BS;
    WqT[idx] = Wq_in[w * (HH * DK) + h * DK + d];
}

// kbf[256] = enc_b @ Wk_in
__global__ __launch_bounds__(256) void bias_k(const float* __restrict__ enc_b,
                                              const float* __restrict__ Wk,
                                              float* __restrict__ kbf)
{
    int j = threadIdx.x;
    if (j >= HH * DK) return;
    float acc = 0.f;
    for (int d = 0; d < NINP; d++) acc += enc_b[d] * Wk[d * (HH * DK) + j];
    kbf[j] = acc;
}

// bias_c[768]: cols<340: enc_b@Wv ; 340..739: kbf[h-slice]@WqT ; else 0
__global__ __launch_bounds__(256) void bias_c_kernel(const float* __restrict__ enc_b,
                                                     const float* __restrict__ Wv,
                                                     const float* __restrict__ kbf,
                                                     const float* __restrict__ WqT,
                                                     float* __restrict__ bias_c)
{
    int j = blockIdx.x * 256 + threadIdx.x;
    if (j >= CNP) return;
    float acc = 0.f;
    if (j < VN) {
        for (int d = 0; d < NINP; d++) acc += enc_b[d] * Wv[d * (HH * DV) + j];
    } else if (j < CN) {
        int r = j - VN;
        int h = r / BS, w = r - h * BS;
        for (int d = 0; d < DK; d++)
            acc += kbf[h * DK + d] * WqT[(h * DK + d) * BS + w];
    }
    bias_c[j] = acc;
}

// B_dec[512][640] bf16
__global__ __launch_bounds__(256) void cvt_dec(const float* __restrict__ dec_W,
                                               unsigned short* __restrict__ dst)
{
    int idx = blockIdx.x * 256 + threadIdx.x;
    if (idx >= NTOK * DECKP) return;
    int n = idx / DECKP, k = idx - n * DECKP;
    dst[idx] = f2b(k < NHID ? dec_W[k * NTOK + n] : 0.f);
}

// EWfull fp32 [512][768] -> B_vkap split [768][1536]
__global__ __launch_bounds__(256) void cvt_split_ew(const float* __restrict__ EWfull,
                                                    unsigned short* __restrict__ dst)
{
    int idx = blockIdx.x * 256 + threadIdx.x;
    if (idx >= CNP * NTOK) return;
    int n = idx / NTOK, k = idx - n * NTOK;
    float x = (n < CN) ? EWfull[(long)k * CNP + n] : 0.f;
    unsigned short hi, mid, lo;
    split3(x, hi, mid, lo);
    long base = (long)n * (3 * KV0) + k;
    dst[base] = hi;
    dst[base + KV0] = mid;
    dst[base + 2 * KV0] = lo;
}

// W_ih -> B_U split [24][384][384]
__global__ __launch_bounds__(256) void cvt_split_bu(const float* __restrict__ W_ih,
                                                    unsigned short* __restrict__ dst)
{
    int idx = blockIdx.x * 256 + threadIdx.x;
    if (idx >= 24 * UNP * UK0) return;
    int z = idx / (UNP * UK0), r = idx - z * (UNP * UK0);
    int e = r / UK0, kk = r - e * UK0;
    int h = z / NBK, n = z - h * NBK;
    float x = 0.f;
    if (kk < DV && e < G3) x = W_ih[((long)n * ATT + h * DV + kk) * G3 + e];
    unsigned short hi, mid, lo;
    split3(x, hi, mid, lo);
    long base = ((long)z * UNP + e) * (3 * UK0) + kk;
    dst[base] = hi;
    dst[base + UK0] = mid;
    dst[base + 2 * UK0] = lo;
}

// input chunk -> A_in split [rows][1536]
__global__ __launch_bounds__(256) void cvt_split_in(const float* __restrict__ src,
                                                    unsigned short* __restrict__ dst, long rows)
{
    long total = rows * NTOK;
    long i = (long)blockIdx.x * 256 + threadIdx.x;
    long stride = (long)gridDim.x * 256;
    for (; i < total; i += stride) {
        long row = i / NTOK; int k = (int)(i - row * NTOK);
        unsigned short hi, mid, lo;
        split3(src[i], hi, mid, lo);
        long base = row * (3 * KV0) + k;
        dst[base] = hi;
        dst[base + KV0] = mid;
        dst[base + 2 * KV0] = lo;
    }
}

// v-part of Cbuf -> A_U split [4][MU][384]
__global__ __launch_bounds__(256) void cvt_split_vu(const float* __restrict__ Cbuf,
                                                    unsigned short* __restrict__ dst, int MU)
{
    long total = (long)HH * MU * UK0;
    long i = (long)blockIdx.x * 256 + threadIdx.x;
    long stride = (long)gridDim.x * 256;
    for (; i < total; i += stride) {
        int h = (int)(i / ((long)MU * UK0));
        long r = i - (long)h * MU * UK0;
        long row = r / UK0; int kk = (int)(r - row * UK0);
        float x = (kk < DV) ? Cbuf[row * CNP + h * DV + kk] : 0.f;
        unsigned short hi, mid, lo;
        split3(x, hi, mid, lo);
        long base = ((long)h * MU + row) * (3 * UK0) + kk;
        dst[base] = hi;
        dst[base + UK0] = mid;
        dst[base + 2 * UK0] = lo;
    }
}

// ===== fused per-step kernel, NSAMP samples per block =====
__global__ __launch_bounds__(256) void step_fused(
    const float* __restrict__ h_prev,       // [512,600]
    const float* __restrict__ masks_t,      // [512]
    const float* __restrict__ Cbuf,         // [MU,768]: v 0..339, kap 340..739
    const float* __restrict__ U,            // [24,MU,300]
    const float* __restrict__ b_ih,         // [6,300]
    const float* __restrict__ b_hh,         // [6,300]
    const float* __restrict__ W_hh,         // [6,100,300]
    const float* __restrict__ Wq_c, const float* __restrict__ Wk_c,
    const float* __restrict__ Wv_c, const float* __restrict__ Wo_c,
    float* __restrict__ h_out,              // [512,600]
    unsigned short* __restrict__ A_dec,     // [MU,640] bf16
    int s, int MU)
{
    const int b0 = blockIdx.x * NSAMP, tid = threadIdx.x;
    __shared__ float hb[NSAMP][NHID], hn[NSAMP][NHID];
    __shared__ float kp[NSAMP][KAPN];
    __shared__ float qc[NSAMP][NBK * 128], kc[NSAMP][NBK * 128];
    __shared__ float vc[NSAMP][NBK * 128], co[NSAMP][NBK * 128];
    __shared__ float part[NSAMP][96];
    __shared__ float att[NSAMP][24], acts[NSAMP][NBK], mk[NSAMP][NBK];
    __shared__ float lg[NSAMP][H2 * NBK * NBK];
    __shared__ float kthv[NSAMP];

    // load h (with episode-reset mask) and kappa
    for (int i = tid; i < NSAMP * NHID; i += 256) {
        int sm = i / NHID, j = i - sm * NHID;
        hb[sm][j] = h_prev[(long)(b0 + sm) * NHID + j] * masks_t[b0 + sm];
    }
    for (int i = tid; i < NSAMP * KAPN; i += 256) {
        int sm = i / KAPN, j = i - sm * KAPN;
        kp[sm][j] = Cbuf[((long)s * BATCH + b0 + sm) * CNP + VN + j];
    }
    __syncthreads();
    // input-attention logits (partial dots)
    if (tid < NSAMP * 96) {
        int sm = tid / 96, r = tid - sm * 96;
        int pair = r >> 2, pi = r & 3;        // pair = n*4+h
        int n = pair >> 2, h = pair & 3;
        float s0 = 0.f;
        int w0 = pi * 25;
        for (int w = w0; w < w0 + 25; w++) s0 += hb[sm][n * BS + w] * kp[sm][h * BS + w];
        part[sm][r] = s0;
    }
    __syncthreads();
    if (tid < NSAMP * 24) {
        int sm = tid / 24, r = tid - sm * 24;
        float l = part[sm][r * 4] + part[sm][r * 4 + 1] + part[sm][r * 4 + 2] + part[sm][r * 4 + 3];
        att[sm][r] = sigf(l * 0.125f);        // softmax([l,0])[0] == sigmoid(l)
    }
    __syncthreads();
    if (tid < NSAMP * NBK) {
        int sm = tid / NBK, n = tid - sm * NBK;
        acts[sm][n] = 0.25f * (att[sm][n * 4] + att[sm][n * 4 + 1] + att[sm][n * 4 + 2] + att[sm][n * 4 + 3]);
    }
    __syncthreads();
    if (tid < NSAMP) {
        float a[NBK];
        for (int i = 0; i < NBK; i++) a[i] = acts[tid][i];
        for (int i = 0; i < 4; i++) {
            int mx = i;
            for (int j = i + 1; j < NBK; j++) if (a[j] > a[mx]) mx = j;
            float t = a[i]; a[i] = a[mx]; a[mx] = t;
        }
        kthv[tid] = a[3];
    }
    __syncthreads();
    if (tid < NSAMP * NBK) {
        int sm = tid / NBK, n = tid - sm * NBK;
        mk[sm][n] = (acts[sm][n] >= kthv[sm]) ? 1.f : 0.f;
    }
    // GRU: gi from U gather (att-weighted), gh as matvec over W_hh
    for (int i = tid; i < NSAMP * NHID; i += 256) {
        int sm = i / NHID, j = i - sm * NHID;
        int n = j / BS, w = j - n * BS;
        long rowd = (long)s * BATCH + b0 + sm;
        float gi0 = b_ih[n * G3 + w];
        float gi1 = b_ih[n * G3 + BS + w];
        float gi2 = b_ih[n * G3 + 2 * BS + w];
#pragma unroll
        for (int h = 0; h < HH; h++) {
            float a = att[sm][n * 4 + h];
            const float* Up = U + ((long)(h * NBK + n) * MU + rowd) * G3 + w;
            gi0 += a * Up[0];
            gi1 += a * Up[BS];
            gi2 += a * Up[2 * BS];
        }
        float gh0 = b_hh[n * G3 + w];
        float gh1 = b_hh[n * G3 + BS + w];
        float gh2 = b_hh[n * G3 + 2 * BS + w];
        const float* Wp = W_hh + (long)n * BS * G3 + w;
        for (int d = 0; d < BS; d++) {
            float hv = hb[sm][n * BS + d];
            const float* Wr = Wp + (long)d * G3;
            gh0 += hv * Wr[0];
            gh1 += hv * Wr[BS];
            gh2 += hv * Wr[2 * BS];
        }
        float r = sigf(gi0 + gh0);
        float z = sigf(gi1 + gh1);
        float ng = tanhf(gi2 + r * gh2);
        hn[sm][j] = (1.f - z) * ng + z * hb[sm][j];
    }
    __syncthreads();
    // communication attention projections
    for (int idx = tid; idx < NSAMP * 3 * NBK * 128; idx += 256) {
        int sm = idx / (3 * NBK * 128), r2 = idx - sm * (3 * NBK * 128);
        int mat = r2 / (NBK * 128); r2 -= mat * (NBK * 128);
        int n = r2 >> 7, c2 = r2 & 127;
        const float* W = (mat == 0) ? Wq_c : ((mat == 1) ? Wk_c : Wv_c);
        float a = 0.f;
        for (int d = 0; d < BS; d++) a += hn[sm][n * BS + d] * W[d * 128 + c2];
        float* dst = (mat == 0) ? qc[sm] : ((mat == 1) ? kc[sm] : vc[sm]);
        dst[n * 128 + c2] = a;
    }
    __syncthreads();
    for (int idx = tid; idx < NSAMP * H2 * NBK * NBK; idx += 256) {
        int sm = idx / (H2 * NBK * NBK), r2 = idx - sm * (H2 * NBK * NBK);
        int h = r2 / 36, r3 = r2 - h * 36, n = r3 / NBK, m = r3 - n * NBK;
        float sv = 0.f;
        for (int e = 0; e < DK2; e++) sv += qc[sm][n * 128 + h * DK2 + e] * kc[sm][m * 128 + h * DK2 + e];
        lg[sm][h * 36 + n * NBK + m] = sv * 0.17677669529663687f;
    }
    __syncthreads();
    if (tid < NSAMP * H2 * NBK) {
        int sm = tid / (H2 * NBK), r2 = tid - sm * (H2 * NBK);
        int h = r2 / NBK, n = r2 - h * NBK;
        float* row = &lg[sm][h * 36 + n * NBK];
        float mx = row[0];
        for (int m = 1; m < NBK; m++) mx = fmaxf(mx, row[m]);
        float sv = 0.f;
        for (int m = 0; m < NBK; m++) { row[m] = expf(row[m] - mx); sv += row[m]; }
        float inv = 1.f / sv;
        for (int m = 0; m < NBK; m++) row[m] *= inv;
    }
    __syncthreads();
    for (int idx = tid; idx < NSAMP * NBK * 128; idx += 256) {
        int sm = idx / (NBK * 128), r2 = idx - sm * (NBK * 128);
        int n = r2 >> 7, d = r2 & 127, h = d >> 5;
        float a = 0.f;
        for (int m = 0; m < NBK; m++) a += lg[sm][h * 36 + n * NBK + m] * vc[sm][m * 128 + d];
        co[sm][r2] = a;
    }
    __syncthreads();
    for (int idx = tid; idx < NSAMP * DECKP; idx += 256) {
        int sm = idx / DECKP, i = idx - sm * DECKP;
        long rowd = (long)s * BATCH + b0 + sm;
        float hf = 0.f;
        if (i < NHID) {
            int n = i / BS, w = i - n * BS;
            float a = 0.f;
            for (int d = 0; d < 128; d++) a += co[sm][n * 128 + d] * Wo_c[d * BS + w];
            float hc = hn[sm][i] + a;
            hf = (mk[sm][n] > 0.5f) ? hc : hb[sm][i];
            h_out[(long)(b0 + sm) * NHID + i] = hf;
        }
        A_dec[rowd * DECKP + i] = f2b(hf);
    }
}

// ===== host launch =====
extern "C" void kernel_launch(void* const* d_in, const int* in_sizes, int n_in,
                              void* d_out, int out_size, void* d_ws, size_t ws_size,
                              hipStream_t stream)
{
    const float* input = (const float*)d_in[0];
    const float* h0    = (const float*)d_in[1];
    const float* masks = (const float*)d_in[2];
    const float* enc_W = (const float*)d_in[3];
    const float* enc_b = (const float*)d_in[4];
    const float* Wq_in = (const float*)d_in[5];
    const float* Wk_in = (const float*)d_in[6];
    const float* Wv_in = (const float*)d_in[7];
    const float* W_ih  = (const float*)d_in[8];
    const float* W_hh  = (const float*)d_in[9];
    const float* b_ih  = (const float*)d_in[10];
    const float* b_hh  = (const float*)d_in[11];
    const float* Wq_c  = (const float*)d_in[12];
    const float* Wk_c  = (const float*)d_in[13];
    const float* Wv_c  = (const float*)d_in[14];
    const float* Wo_c  = (const float*)d_in[15];
    const float* dec_W = (const float*)d_in[16];
    const float* dec_b = (const float*)d_in[17];
    float* out = (float*)d_out;

    const size_t AL = 256;
    auto pad = [&](size_t x) { return (x + AL - 1) & ~(AL - 1); };
    size_t fixedB = pad((size_t)NTOK * CNP * 4)            // EWfull
                  + pad((size_t)NTOK * 256 * 4)            // EWk
                  + pad((size_t)HH * DK * BS * 4)          // WqT
                  + pad((size_t)256 * 4)                   // kbf
                  + pad((size_t)CNP * 4)                   // bias_c
                  + pad((size_t)CNP * 3 * KV0 * 2)         // B_vkap
                  + pad((size_t)24 * UNP * 3 * UK0 * 2)    // B_U
                  + pad((size_t)NTOK * DECKP * 2)          // B_dec
                  + 2 * pad((size_t)BATCH * NHID * 4);     // hA,hB
    auto perC = [&](int C) {
        size_t MU = (size_t)C * BATCH;
        return pad(MU * 3 * KV0 * 2)             // A_in split
             + pad(MU * CNP * 4)                 // Cbuf fp32
             + pad((size_t)HH * MU * 3 * UK0 * 2)// A_U split
             + pad((size_t)24 * MU * G3 * 4)     // Ubuf fp32
             + pad(MU * DECKP * 2);              // A_dec
    };
    int C = 8;
    while (C > 1 && fixedB + perC(C) > ws_size) C >>= 1;
    const int MU = C * BATCH;
    const int NCH = T_STEPS / C;

    char* p = (char*)d_ws;
    auto alloc = [&](size_t bytes) { char* r = p; p += pad(bytes); return r; };
    float*          EWfull = (float*)alloc((size_t)NTOK * CNP * 4);
    float*          EWk    = (float*)alloc((size_t)NTOK * 256 * 4);
    float*          WqT    = (float*)alloc((size_t)HH * DK * BS * 4);
    float*          kbf    = (float*)alloc((size_t)256 * 4);
    float*          bias_c = (float*)alloc((size_t)CNP * 4);
    unsigned short* B_vkap = (unsigned short*)alloc((size_t)CNP * 3 * KV0 * 2);
    unsigned short* B_U    = (unsigned short*)alloc((size_t)24 * UNP * 3 * UK0 * 2);
    unsigned short* B_dec  = (unsigned short*)alloc((size_t)NTOK * DECKP * 2);
    float*          hA     = (float*)alloc((size_t)BATCH * NHID * 4);
    float*          hB     = (float*)alloc((size_t)BATCH * NHID * 4);
    unsigned short* A_in   = (unsigned short*)alloc((size_t)MU * 3 * KV0 * 2);
    float*          Cbuf   = (float*)alloc((size_t)MU * CNP * 4);
    unsigned short* A_U    = (unsigned short*)alloc((size_t)HH * MU * 3 * UK0 * 2);
    float*          Ubuf   = (float*)alloc((size_t)24 * MU * G3 * 4);
    unsigned short* A_dec  = (unsigned short*)alloc((size_t)MU * DECKP * 2);

    dim3 blk(256);
    ZOff z0 = {1, 0, 0};

    // ---- setup (fp32 sgemm path; tiny) ----
    // EWfull[:,0:340] = enc_W @ Wv_in
    sgemm<<<dim3(6, 4, 1), blk, 0, stream>>>(
        enc_W, z0, NINP, Wv_in, z0, HH * DV, EWfull, z0, CNP, NTOK, VN, NINP);
    // EWk = enc_W @ Wk_in
    sgemm<<<dim3(4, 4, 1), blk, 0, stream>>>(
        enc_W, z0, NINP, Wk_in, z0, HH * DK, EWk, z0, 256, NTOK, HH * DK, NINP);
    prep_wqt<<<dim3((HH * DK * BS + 255) / 256), blk, 0, stream>>>(Wq_in, WqT);
    // EWfull[:,340+h*100:+100] = EWk[:,h*64:+64] @ WqT[h]
    sgemm<<<dim3(2, 4, HH), blk, 0, stream>>>(
        EWk, ZOff{1, DK, 0}, 256, WqT, ZOff{1, (long)DK * BS, 0}, BS,
        EWfull + VN, ZOff{1, BS, 0}, CNP, NTOK, BS, DK);
    bias_k<<<dim3(1), blk, 0, stream>>>(enc_b, Wk_in, kbf);
    bias_c_kernel<<<dim3(3), blk, 0, stream>>>(enc_b, Wv_in, kbf, WqT, bias_c);
    cvt_split_ew<<<dim3((CNP * NTOK + 255) / 256), blk, 0, stream>>>(EWfull, B_vkap);
    cvt_split_bu<<<dim3((24 * UNP * UK0 + 255) / 256), blk, 0, stream>>>(W_ih, B_U);
    cvt_dec<<<dim3((NTOK * DECKP + 255) / 256), blk, 0, stream>>>(dec_W, B_dec);

    const float* hp = h0;
    float* hbufs[2] = { hA, hB };
    int t = 0;
    for (int c = 0; c < NCH; c++) {
        // input chunk -> 3-way split bf16
        cvt_split_in<<<dim3(2048), blk, 0, stream>>>(
            input + (size_t)c * MU * NTOK, A_in, MU);
        // Cbuf = input @ [EWv | KW] + bias  (fp32-class via 6 passes)
        gemm6<<<dim3(CNP / 128, MU / 128, 1), blk, 0, stream>>>(
            A_in, 0, 1, B_vkap, 0, Cbuf, 0, CNP, CN, bias_c, KV0);
        // A_U splits from v-part of Cbuf
        cvt_split_vu<<<dim3(2048), blk, 0, stream>>>(Cbuf, A_U, MU);
        // U[z=h*6+n] = v_h @ W_ih[n,h-slice]  (fp32-class)
        gemm6<<<dim3(UNP / 128, MU / 128, 24), blk, 0, stream>>>(
            A_U, (long)MU * 3 * UK0, NBK, B_U, (long)UNP * 3 * UK0,
            Ubuf, (long)MU * G3, G3, G3, nullptr, UK0);
        for (int s = 0; s < C; s++, t++) {
            float* hout = hbufs[t & 1];
            step_fused<<<dim3(BATCH / NSAMP), blk, 0, stream>>>(
                hp, masks + (size_t)t * BATCH, Cbuf, Ubuf, b_ih, b_hh, W_hh,
                Wq_c, Wk_c, Wv_c, Wo_c, hout, A_dec, s, MU);
            hp = hout;
        }
        // decoder (plain bf16 MFMA, output-side only)
        gemm_mfma<<<dim3(NTOK / 128, MU / 128, 1), blk, 0, stream>>>(
            A_dec, B_dec, out + (size_t)c * MU * NTOK, NTOK, dec_b, DECKP);
    }
}

// Round 6
// 12781.377 us; speedup vs baseline: 1.5458x; 1.5458x over previous
//
#include <hip/hip_runtime.h>
#include <math.h>

#define T_STEPS 128
#define BATCH   512
#define NTOK    512
#define NINP    512
#define NHID    600
#define NBK     6
#define BS      100
#define HH      4
#define DK      64
#define DV      85
#define ATT     340
#define H2      4
#define DK2     32
#define DV2     32
#define G3      300
#define VN      340      // v cols in chunk GEMM out
#define KAPN    400      // kappa cols
#define CN      740      // real cols (VN+KAPN)
#define CNP     768      // padded
#define UNP     384      // U N padded 300->384
#define UK0     128      // U per-segment K (85 pad 128)
#define KV0     512      // chunk per-segment K
#define DECKP   640
#define NSAMP   2

typedef __attribute__((ext_vector_type(8))) short short8;
typedef __attribute__((ext_vector_type(4))) float f32x4;

__device__ __forceinline__ float sigf(float x) { return 1.f / (1.f + expf(-x)); }
__device__ __forceinline__ unsigned short f2b(float f) {
    unsigned u = __float_as_uint(f);
    unsigned r = (u + 0x7fffu + ((u >> 16) & 1u)) >> 16;
    return (unsigned short)r;
}
__device__ __forceinline__ float b2f(unsigned short u) {
    return __uint_as_float(((unsigned)u) << 16);
}
// 3-way split: x ~= hi + mid + lo (each bf16); residual ~2^-25 |x|
__device__ __forceinline__ void split3(float x, unsigned short& hi,
                                       unsigned short& mid, unsigned short& lo) {
    hi = f2b(x);
    float r1 = x - b2f(hi);
    mid = f2b(r1);
    lo = f2b(r1 - b2f(mid));
}

struct ZOff { int div; long s1; long s2; };
__device__ __forceinline__ long zoff(ZOff z, int bz) {
    return (long)(bz / z.div) * z.s1 + (long)(bz % z.div) * z.s2;
}

// ===== bf16x6 MFMA GEMM: fp32-class C = A@B^T (+bias) via 6 segment passes =====
__global__ __launch_bounds__(256) void gemm6(
    const unsigned short* __restrict__ A, long aZ, int aZdiv,
    const unsigned short* __restrict__ B, long bZ,
    float* __restrict__ C, long cZ, int ldc, int Nreal,
    const float* __restrict__ bias, int K0)
{
    const int z = blockIdx.z;
    A += (long)(z / aZdiv) * aZ;
    B += (long)z * bZ;
    C += (long)z * cZ;
    const int LDA = 3 * K0;
    const int m0 = blockIdx.y * 128, n0 = blockIdx.x * 128;
    __shared__ __align__(16) unsigned short As[128 * 64];
    __shared__ __align__(16) unsigned short Bs[128 * 64];
    const int tid = threadIdx.x;
    const int lane = tid & 63;
    const int wid = tid >> 6;
    const int wr = wid >> 1, wc = wid & 1;

    f32x4 acc[4][4];
#pragma unroll
    for (int m = 0; m < 4; m++)
#pragma unroll
        for (int n = 0; n < 4; n++)
#pragma unroll
            for (int v = 0; v < 4; v++) acc[m][n][v] = 0.f;

    const int segA[6] = {0, 0, 1, 0, 2, 1};
    const int segB[6] = {0, 1, 0, 2, 0, 1};
    for (int p = 0; p < 6; p++) {
        const unsigned short* Ap = A + segA[p] * K0;
        const unsigned short* Bp = B + segB[p] * K0;
        for (int k0 = 0; k0 < K0; k0 += 64) {
            short8 ra[4], rb[4];
#pragma unroll
            for (int q = 0; q < 4; q++) {
                int idx = (q << 8) + tid;
                int r = idx >> 3, ce = (idx & 7) << 3;
                ra[q] = *(const short8*)&Ap[(long)(m0 + r) * LDA + k0 + ce];
                rb[q] = *(const short8*)&Bp[(long)(n0 + r) * LDA + k0 + ce];
            }
            __syncthreads();
#pragma unroll
            for (int q = 0; q < 4; q++) {
                int idx = (q << 8) + tid;
                int r = idx >> 3, ce = (idx & 7) << 3;
                *(short8*)&As[r * 64 + ce] = ra[q];
                *(short8*)&Bs[r * 64 + ce] = rb[q];
            }
            __syncthreads();
#pragma unroll
            for (int kk = 0; kk < 2; kk++) {
                short8 af[4], bfr[4];
#pragma unroll
                for (int m = 0; m < 4; m++)
                    af[m] = *(const short8*)&As[(wr * 64 + m * 16 + (lane & 15)) * 64 + kk * 32 + (lane >> 4) * 8];
#pragma unroll
                for (int n = 0; n < 4; n++)
                    bfr[n] = *(const short8*)&Bs[(wc * 64 + n * 16 + (lane & 15)) * 64 + kk * 32 + (lane >> 4) * 8];
#pragma unroll
                for (int m = 0; m < 4; m++)
#pragma unroll
                    for (int n = 0; n < 4; n++)
                        acc[m][n] = __builtin_amdgcn_mfma_f32_16x16x32_bf16(af[m], bfr[n], acc[m][n], 0, 0, 0);
            }
        }
    }
#pragma unroll
    for (int m = 0; m < 4; m++) {
        int rbase = m0 + wr * 64 + m * 16 + (lane >> 4) * 4;
#pragma unroll
        for (int n = 0; n < 4; n++) {
            int col = n0 + wc * 64 + n * 16 + (lane & 15);
            if (col < Nreal) {
                float bv = bias ? bias[col] : 0.f;
#pragma unroll
                for (int v = 0; v < 4; v++)
                    C[(long)(rbase + v) * ldc + col] = acc[m][n][v] + bv;
            }
        }
    }
}

// ===== plain bf16 MFMA GEMM (decoder only; output-side, proven safe) =====
__global__ __launch_bounds__(256) void gemm_mfma(
    const unsigned short* __restrict__ A,
    const unsigned short* __restrict__ B,
    float* __restrict__ C, int ldc,
    const float* __restrict__ bias, int Kp)
{
    const int m0 = blockIdx.y * 128, n0 = blockIdx.x * 128;
    __shared__ __align__(16) unsigned short As[128 * 64];
    __shared__ __align__(16) unsigned short Bs[128 * 64];
    const int tid = threadIdx.x;
    const int lane = tid & 63;
    const int wid = tid >> 6;
    const int wr = wid >> 1, wc = wid & 1;

    f32x4 acc[4][4];
#pragma unroll
    for (int m = 0; m < 4; m++)
#pragma unroll
        for (int n = 0; n < 4; n++)
#pragma unroll
            for (int v = 0; v < 4; v++) acc[m][n][v] = 0.f;

    for (int k0 = 0; k0 < Kp; k0 += 64) {
        short8 ra[4], rb[4];
#pragma unroll
        for (int q = 0; q < 4; q++) {
            int idx = (q << 8) + tid;
            int r = idx >> 3, ce = (idx & 7) << 3;
            ra[q] = *(const short8*)&A[(long)(m0 + r) * Kp + k0 + ce];
            rb[q] = *(const short8*)&B[(long)(n0 + r) * Kp + k0 + ce];
        }
        __syncthreads();
#pragma unroll
        for (int q = 0; q < 4; q++) {
            int idx = (q << 8) + tid;
            int r = idx >> 3, ce = (idx & 7) << 3;
            *(short8*)&As[r * 64 + ce] = ra[q];
            *(short8*)&Bs[r * 64 + ce] = rb[q];
        }
        __syncthreads();
#pragma unroll
        for (int kk = 0; kk < 2; kk++) {
            short8 af[4], bfr[4];
#pragma unroll
            for (int m = 0; m < 4; m++)
                af[m] = *(const short8*)&As[(wr * 64 + m * 16 + (lane & 15)) * 64 + kk * 32 + (lane >> 4) * 8];
#pragma unroll
            for (int n = 0; n < 4; n++)
                bfr[n] = *(const short8*)&Bs[(wc * 64 + n * 16 + (lane & 15)) * 64 + kk * 32 + (lane >> 4) * 8];
#pragma unroll
            for (int m = 0; m < 4; m++)
#pragma unroll
                for (int n = 0; n < 4; n++)
                    acc[m][n] = __builtin_amdgcn_mfma_f32_16x16x32_bf16(af[m], bfr[n], acc[m][n], 0, 0, 0);
        }
    }
#pragma unroll
    for (int m = 0; m < 4; m++) {
        int rbase = m0 + wr * 64 + m * 16 + (lane >> 4) * 4;
#pragma unroll
        for (int n = 0; n < 4; n++) {
            int col = n0 + wc * 64 + n * 16 + (lane & 15);
            float bv = bias ? bias[col] : 0.f;
#pragma unroll
            for (int v = 0; v < 4; v++)
                C[(long)(rbase + v) * ldc + col] = acc[m][n][v] + bv;
        }
    }
}

// ===== fp32 SGEMM (setup-only small jobs) =====
__global__ __launch_bounds__(256) void sgemm(
    const float* __restrict__ A, ZOff za, int lda,
    const float* __restrict__ B, ZOff zb, int ldb,
    float* __restrict__ C, ZOff zc, int ldc,
    int M, int N, int K)
{
    const int bz = blockIdx.z;
    A += zoff(za, bz);
    B += zoff(zb, bz);
    C += zoff(zc, bz);
    const int m0 = blockIdx.y * 128, n0 = blockIdx.x * 64;
    __shared__ float As[16][132];
    __shared__ float Bs[16][68];
    const int tid = threadIdx.x;
    const int tm = tid >> 4, tn = tid & 15;
    const int ar = tid >> 1, ak = (tid & 1) * 8;
    const int bk = tid >> 4, bn = (tid & 15) * 4;

    float acc[8][4];
#pragma unroll
    for (int i = 0; i < 8; i++)
#pragma unroll
        for (int j = 0; j < 4; j++) acc[i][j] = 0.f;

    for (int k0 = 0; k0 < K; k0 += 16) {
        float av[8], bv[4];
#pragma unroll
        for (int j = 0; j < 8; j++) {
            int gk = k0 + ak + j;
            av[j] = (gk < K) ? A[(long)(m0 + ar) * lda + gk] : 0.f;
        }
#pragma unroll
        for (int j = 0; j < 4; j++) {
            int gk = k0 + bk, gn = n0 + bn + j;
            bv[j] = (gk < K && gn < N) ? B[(long)gk * ldb + gn] : 0.f;
        }
        __syncthreads();
#pragma unroll
        for (int j = 0; j < 8; j++) As[ak + j][ar] = av[j];
#pragma unroll
        for (int j = 0; j < 4; j++) Bs[bk][bn + j] = bv[j];
        __syncthreads();
#pragma unroll
        for (int kk = 0; kk < 16; kk++) {
            float a[8], b[4];
#pragma unroll
            for (int i = 0; i < 8; i++) a[i] = As[kk][tm * 8 + i];
#pragma unroll
            for (int j = 0; j < 4; j++) b[j] = Bs[kk][tn * 4 + j];
#pragma unroll
            for (int i = 0; i < 8; i++)
#pragma unroll
                for (int j = 0; j < 4; j++)
                    acc[i][j] += a[i] * b[j];
        }
    }
#pragma unroll
    for (int i = 0; i < 8; i++) {
        int gm = m0 + tm * 8 + i;
#pragma unroll
        for (int j = 0; j < 4; j++) {
            int gn = n0 + tn * 4 + j;
            if (gn < N) C[(long)gm * ldc + gn] = acc[i][j];
        }
    }
}

// ===== prep kernels =====
__global__ __launch_bounds__(256) void prep_wqt(const float* __restrict__ Wq_in,
                                                float* __restrict__ WqT)
{
    int idx = blockIdx.x * 256 + threadIdx.x;
    if (idx >= HH * DK * BS) return;
    int h = idx / (DK * BS), r = idx - h * DK * BS, d = r / BS, w = r - d * BS;
    WqT[idx] = Wq_in[w * (HH * DK) + h * DK + d];
}

__global__ __launch_bounds__(256) void bias_k(const float* __restrict__ enc_b,
                                              const float* __restrict__ Wk,
                                              float* __restrict__ kbf)
{
    int j = threadIdx.x;
    if (j >= HH * DK) return;
    float acc = 0.f;
    for (int d = 0; d < NINP; d++) acc += enc_b[d] * Wk[d * (HH * DK) + j];
    kbf[j] = acc;
}

__global__ __launch_bounds__(256) void bias_c_kernel(const float* __restrict__ enc_b,
                                                     const float* __restrict__ Wv,
                                                     const float* __restrict__ kbf,
                                                     const float* __restrict__ WqT,
                                                     float* __restrict__ bias_c)
{
    int j = blockIdx.x * 256 + threadIdx.x;
    if (j >= CNP) return;
    float acc = 0.f;
    if (j < VN) {
        for (int d = 0; d < NINP; d++) acc += enc_b[d] * Wv[d * (HH * DV) + j];
    } else if (j < CN) {
        int r = j - VN;
        int h = r / BS, w = r - h * BS;
        for (int d = 0; d < DK; d++)
            acc += kbf[h * DK + d] * WqT[(h * DK + d) * BS + w];
    }
    bias_c[j] = acc;
}

__global__ __launch_bounds__(256) void cvt_dec(const float* __restrict__ dec_W,
                                               unsigned short* __restrict__ dst)
{
    int idx = blockIdx.x * 256 + threadIdx.x;
    if (idx >= NTOK * DECKP) return;
    int n = idx / DECKP, k = idx - n * DECKP;
    dst[idx] = f2b(k < NHID ? dec_W[k * NTOK + n] : 0.f);
}

__global__ __launch_bounds__(256) void cvt_split_ew(const float* __restrict__ EWfull,
                                                    unsigned short* __restrict__ dst)
{
    int idx = blockIdx.x * 256 + threadIdx.x;
    if (idx >= CNP * NTOK) return;
    int n = idx / NTOK, k = idx - n * NTOK;
    float x = (n < CN) ? EWfull[(long)k * CNP + n] : 0.f;
    unsigned short hi, mid, lo;
    split3(x, hi, mid, lo);
    long base = (long)n * (3 * KV0) + k;
    dst[base] = hi;
    dst[base + KV0] = mid;
    dst[base + 2 * KV0] = lo;
}

__global__ __launch_bounds__(256) void cvt_split_bu(const float* __restrict__ W_ih,
                                                    unsigned short* __restrict__ dst)
{
    int idx = blockIdx.x * 256 + threadIdx.x;
    if (idx >= 24 * UNP * UK0) return;
    int z = idx / (UNP * UK0), r = idx - z * (UNP * UK0);
    int e = r / UK0, kk = r - e * UK0;
    int h = z / NBK, n = z - h * NBK;
    float x = 0.f;
    if (kk < DV && e < G3) x = W_ih[((long)n * ATT + h * DV + kk) * G3 + e];
    unsigned short hi, mid, lo;
    split3(x, hi, mid, lo);
    long base = ((long)z * UNP + e) * (3 * UK0) + kk;
    dst[base] = hi;
    dst[base + UK0] = mid;
    dst[base + 2 * UK0] = lo;
}

__global__ __launch_bounds__(256) void cvt_split_in(const float* __restrict__ src,
                                                    unsigned short* __restrict__ dst, long rows)
{
    long total = rows * NTOK;
    long i = (long)blockIdx.x * 256 + threadIdx.x;
    long stride = (long)gridDim.x * 256;
    for (; i < total; i += stride) {
        long row = i / NTOK; int k = (int)(i - row * NTOK);
        unsigned short hi, mid, lo;
        split3(src[i], hi, mid, lo);
        long base = row * (3 * KV0) + k;
        dst[base] = hi;
        dst[base + KV0] = mid;
        dst[base + 2 * KV0] = lo;
    }
}

__global__ __launch_bounds__(256) void cvt_split_vu(const float* __restrict__ Cbuf,
                                                    unsigned short* __restrict__ dst, int MU)
{
    long total = (long)HH * MU * UK0;
    long i = (long)blockIdx.x * 256 + threadIdx.x;
    long stride = (long)gridDim.x * 256;
    for (; i < total; i += stride) {
        int h = (int)(i / ((long)MU * UK0));
        long r = i - (long)h * MU * UK0;
        long row = r / UK0; int kk = (int)(r - row * UK0);
        float x = (kk < DV) ? Cbuf[row * CNP + h * DV + kk] : 0.f;
        unsigned short hi, mid, lo;
        split3(x, hi, mid, lo);
        long base = ((long)h * MU + row) * (3 * UK0) + kk;
        dst[base] = hi;
        dst[base + UK0] = mid;
        dst[base + 2 * UK0] = lo;
    }
}

// ===== fused per-step kernel v2: LDS-staged weight panels, reg-prefetch =====
// grid 256 blocks (2 samples each), 256 threads.
__global__ __launch_bounds__(256) void step_fused(
    const float* __restrict__ h_prev,       // [512,600]
    const float* __restrict__ masks_t,      // [512]
    const float* __restrict__ Cbuf,         // [MU,768]: v 0..339, kap 340..739
    const float* __restrict__ U,            // [24,MU,300]
    const float* __restrict__ b_ih, const float* __restrict__ b_hh,
    const float* __restrict__ W_hh,         // [6,100,300]
    const float* __restrict__ Wq_c, const float* __restrict__ Wk_c,
    const float* __restrict__ Wv_c, const float* __restrict__ Wo_c,
    float* __restrict__ h_out,              // [512,600]
    unsigned short* __restrict__ A_dec,     // [MU,640] bf16
    int s, int MU)
{
    const int b0 = blockIdx.x * NSAMP, tid = threadIdx.x;
    __shared__ float hb[NSAMP][NHID], hn[NSAMP][NHID];
    __shared__ float kp[NSAMP][KAPN];
    __shared__ float qcv[3][NSAMP][NBK * 128];
    __shared__ float co[NSAMP][NBK * 128];
    __shared__ float part[NSAMP][96], att[NSAMP][24], acts[NSAMP][NBK], mk[NSAMP][NBK];
    __shared__ float lg[NSAMP][H2 * NBK * NBK];
    __shared__ float kthv[NSAMP];
    __shared__ __align__(16) float wbuf[7680];   // 30 KB weight-panel staging

    f32x4 pref[8];
    // issue W_hh chunk 0 (25 rows x 300 = 7500 floats = 1875 f32x4) ASAP
    {
        const f32x4* src = (const f32x4*)W_hh;
#pragma unroll
        for (int k = 0; k < 8; k++) {
            int fi = tid + (k << 8);
            if (fi < 1875) pref[k] = src[fi];
        }
    }

    const long rowd0 = (long)s * BATCH + b0;
    // ---- P0: load state ----
    for (int i = tid; i < NSAMP * NHID; i += 256) {
        int sm = i / NHID, j = i - sm * NHID;
        hb[sm][j] = h_prev[(long)(b0 + sm) * NHID + j] * masks_t[b0 + sm];
    }
    for (int i = tid; i < NSAMP * KAPN; i += 256) {
        int sm = i / KAPN, j = i - sm * KAPN;
        kp[sm][j] = Cbuf[(rowd0 + sm) * CNP + VN + j];
    }
    __syncthreads();
    // ---- P1: input attention + top-k ----
    if (tid < NSAMP * 96) {
        int sm = tid / 96, r = tid - sm * 96;
        int pair = r >> 2, pi = r & 3;
        int n = pair >> 2, h = pair & 3;
        float s0 = 0.f;
        int w0 = pi * 25;
        for (int w = w0; w < w0 + 25; w++) s0 += hb[sm][n * BS + w] * kp[sm][h * BS + w];
        part[sm][r] = s0;
    }
    __syncthreads();
    if (tid < NSAMP * 24) {
        int sm = tid / 24, r = tid - sm * 24;
        float l = part[sm][r * 4] + part[sm][r * 4 + 1] + part[sm][r * 4 + 2] + part[sm][r * 4 + 3];
        att[sm][r] = sigf(l * 0.125f);          // softmax([l,0])[0] == sigmoid(l)
    }
    __syncthreads();
    if (tid < NSAMP * NBK) {
        int sm = tid / NBK, n = tid - sm * NBK;
        acts[sm][n] = 0.25f * (att[sm][n * 4] + att[sm][n * 4 + 1] + att[sm][n * 4 + 2] + att[sm][n * 4 + 3]);
    }
    __syncthreads();
    if (tid < NSAMP) {
        float a[NBK];
        for (int i = 0; i < NBK; i++) a[i] = acts[tid][i];
        for (int i = 0; i < 4; i++) {
            int mx = i;
            for (int j = i + 1; j < NBK; j++) if (a[j] > a[mx]) mx = j;
            float t = a[i]; a[i] = a[mx]; a[mx] = t;
        }
        kthv[tid] = a[3];
    }
    __syncthreads();
    if (tid < NSAMP * NBK) {
        int sm = tid / NBK, n = tid - sm * NBK;
        mk[sm][n] = (acts[sm][n] >= kthv[sm]) ? 1.f : 0.f;
    }
    // ---- P2: per-GRU-block gh (LDS-staged W_hh) + gi gather + GRU pointwise ----
    const int sm2 = (tid >= 100) ? 1 : 0;
    const int w2 = tid - sm2 * 100;
    const bool act_th = tid < 200;
    for (int n = 0; n < NBK; n++) {
        float uv[12];
        if (act_th) {
            long rowd = rowd0 + sm2;
#pragma unroll
            for (int h = 0; h < HH; h++) {
                const float* Up = U + ((long)(h * NBK + n) * MU + rowd) * G3 + w2;
                uv[h * 3 + 0] = Up[0];
                uv[h * 3 + 1] = Up[BS];
                uv[h * 3 + 2] = Up[2 * BS];
            }
        }
        float gh0 = 0.f, gh1 = 0.f, gh2 = 0.f;
        if (act_th) {
            gh0 = b_hh[n * G3 + w2];
            gh1 = b_hh[n * G3 + BS + w2];
            gh2 = b_hh[n * G3 + 2 * BS + w2];
        }
        for (int c = 0; c < 4; c++) {
            __syncthreads();
#pragma unroll
            for (int k = 0; k < 8; k++) {
                int fi = tid + (k << 8);
                if (fi < 1875) ((f32x4*)wbuf)[fi] = pref[k];
            }
            __syncthreads();
            int cc = n * 4 + c + 1;
            if (cc < 24) {                      // prefetch next panel during compute
                const f32x4* src = (const f32x4*)(W_hh + cc * 7500);
#pragma unroll
                for (int k = 0; k < 8; k++) {
                    int fi = tid + (k << 8);
                    if (fi < 1875) pref[k] = src[fi];
                }
            }
            if (act_th) {
                const int base = n * BS + c * 25;
#pragma unroll
                for (int dl = 0; dl < 25; dl++) {
                    float hv = hb[sm2][base + dl];
                    gh0 += hv * wbuf[dl * 300 + w2];
                    gh1 += hv * wbuf[dl * 300 + 100 + w2];
                    gh2 += hv * wbuf[dl * 300 + 200 + w2];
                }
            }
        }
        if (act_th) {
            float gi0 = b_ih[n * G3 + w2];
            float gi1 = b_ih[n * G3 + BS + w2];
            float gi2 = b_ih[n * G3 + 2 * BS + w2];
#pragma unroll
            for (int h = 0; h < HH; h++) {
                float a = att[sm2][n * 4 + h];
                gi0 += a * uv[h * 3 + 0];
                gi1 += a * uv[h * 3 + 1];
                gi2 += a * uv[h * 3 + 2];
            }
            float r = sigf(gi0 + gh0);
            float z = sigf(gi1 + gh1);
            float ng = tanhf(gi2 + r * gh2);
            hn[sm2][n * BS + w2] = (1.f - z) * ng + z * hb[sm2][n * BS + w2];
        }
    }
    // ---- P3: comm projections qc/kc/vc (LDS-staged Wq/k/v_c, 2 chunks of 50x128) ----
    for (int m = 0; m < 3; m++) {
        const float* W = (m == 0) ? Wq_c : ((m == 1) ? Wk_c : Wv_c);
        {
            const f32x4* src = (const f32x4*)W;
#pragma unroll
            for (int k = 0; k < 7; k++) {
                int fi = tid + (k << 8);
                if (fi < 1600) pref[k] = src[fi];
            }
        }
        float acc[6];
#pragma unroll
        for (int j = 0; j < 6; j++) acc[j] = 0.f;
        for (int ch = 0; ch < 2; ch++) {
            __syncthreads();
#pragma unroll
            for (int k = 0; k < 7; k++) {
                int fi = tid + (k << 8);
                if (fi < 1600) ((f32x4*)wbuf)[fi] = pref[k];
            }
            __syncthreads();
            if (ch == 0) {
                const f32x4* src = (const f32x4*)(W + 6400);
#pragma unroll
                for (int k = 0; k < 7; k++) {
                    int fi = tid + (k << 8);
                    if (fi < 1600) pref[k] = src[fi];
                }
            }
#pragma unroll
            for (int j = 0; j < 6; j++) {
                int o = tid + (j << 8);
                int sm = o / 768, r = o - sm * 768;
                int n = r >> 7, cc2 = r & 127;
                float a = acc[j];
                const int hbase = n * BS + ch * 50;
#pragma unroll 10
                for (int d = 0; d < 50; d++)
                    a += hn[sm][hbase + d] * wbuf[d * 128 + cc2];
                acc[j] = a;
            }
        }
#pragma unroll
        for (int j = 0; j < 6; j++) {
            int o = tid + (j << 8);
            int sm = o / 768, r = o - sm * 768;
            qcv[m][sm][r] = acc[j];
        }
    }
    __syncthreads();
    // ---- P4: comm attention softmax + co ----
    for (int idx = tid; idx < NSAMP * H2 * NBK * NBK; idx += 256) {
        int sm = idx / (H2 * NBK * NBK), r2 = idx - sm * (H2 * NBK * NBK);
        int h = r2 / 36, r3 = r2 - h * 36, n = r3 / NBK, m = r3 - n * NBK;
        float sv = 0.f;
        for (int e = 0; e < DK2; e++)
            sv += qcv[0][sm][n * 128 + h * DK2 + e] * qcv[1][sm][m * 128 + h * DK2 + e];
        lg[sm][h * 36 + n * NBK + m] = sv * 0.17677669529663687f;
    }
    __syncthreads();
    if (tid < NSAMP * H2 * NBK) {
        int sm = tid / (H2 * NBK), r2 = tid - sm * (H2 * NBK);
        int h = r2 / NBK, n = r2 - h * NBK;
        float* row = &lg[sm][h * 36 + n * NBK];
        float mx = row[0];
        for (int m = 1; m < NBK; m++) mx = fmaxf(mx, row[m]);
        float sv = 0.f;
        for (int m = 0; m < NBK; m++) { row[m] = expf(row[m] - mx); sv += row[m]; }
        float inv = 1.f / sv;
        for (int m = 0; m < NBK; m++) row[m] *= inv;
    }
    __syncthreads();
    for (int idx = tid; idx < NSAMP * NBK * 128; idx += 256) {
        int sm = idx / (NBK * 128), r2 = idx - sm * (NBK * 128);
        int n = r2 >> 7, d = r2 & 127, h = d >> 5;
        float a = 0.f;
#pragma unroll
        for (int m = 0; m < NBK; m++) a += lg[sm][h * 36 + n * NBK + m] * qcv[2][sm][m * 128 + d];
        co[sm][r2] = a;
    }
    // ---- P5: co @ Wo_c (LDS-staged, 2 chunks of 64x100) ----
    {
        const f32x4* src = (const f32x4*)Wo_c;
#pragma unroll
        for (int k = 0; k < 7; k++) {
            int fi = tid + (k << 8);
            if (fi < 1600) pref[k] = src[fi];
        }
    }
    float accA[5];
#pragma unroll
    for (int j = 0; j < 5; j++) accA[j] = 0.f;
    for (int ch = 0; ch < 2; ch++) {
        __syncthreads();
#pragma unroll
        for (int k = 0; k < 7; k++) {
            int fi = tid + (k << 8);
            if (fi < 1600) ((f32x4*)wbuf)[fi] = pref[k];
        }
        __syncthreads();
        if (ch == 0) {
            const f32x4* src = (const f32x4*)(Wo_c + 6400);
#pragma unroll
            for (int k = 0; k < 7; k++) {
                int fi = tid + (k << 8);
                if (fi < 1600) pref[k] = src[fi];
            }
        }
#pragma unroll
        for (int j = 0; j < 5; j++) {
            int o = tid + (j << 8);
            if (o < NSAMP * NHID) {
                int sm = o / NHID, i = o - sm * NHID;
                int n = i / BS, w = i - n * BS;
                float a = accA[j];
                const int cbase = n * 128 + ch * 64;
#pragma unroll 8
                for (int d = 0; d < 64; d++)
                    a += co[sm][cbase + d] * wbuf[d * 100 + w];
                accA[j] = a;
            }
        }
    }
    // ---- P6: masked select + writes ----
#pragma unroll
    for (int j = 0; j < 5; j++) {
        int o = tid + (j << 8);
        if (o < NSAMP * NHID) {
            int sm = o / NHID, i = o - sm * NHID;
            int n = i / BS;
            float hc = hn[sm][i] + accA[j];
            float hf = (mk[sm][n] > 0.5f) ? hc : hb[sm][i];
            h_out[(long)(b0 + sm) * NHID + i] = hf;
            hb[sm][i] = hf;        // reuse hb as staging for A_dec
        }
    }
    __syncthreads();
    for (int o = tid; o < NSAMP * DECKP; o += 256) {
        int sm = o / DECKP, i = o - sm * DECKP;
        A_dec[(rowd0 + sm) * DECKP + i] = f2b(i < NHID ? hb[sm][i] : 0.f);
    }
}

// ===== host launch =====
extern "C" void kernel_launch(void* const* d_in, const int* in_sizes, int n_in,
                              void* d_out, int out_size, void* d_ws, size_t ws_size,
                              hipStream_t stream)
{
    const float* input = (const float*)d_in[0];
    const float* h0    = (const float*)d_in[1];
    const float* masks = (const float*)d_in[2];
    const float* enc_W = (const float*)d_in[3];
    const float* enc_b = (const float*)d_in[4];
    const float* Wq_in = (const float*)d_in[5];
    const float* Wk_in = (const float*)d_in[6];
    const float* Wv_in = (const float*)d_in[7];
    const float* W_ih  = (const float*)d_in[8];
    const float* W_hh  = (const float*)d_in[9];
    const float* b_ih  = (const float*)d_in[10];
    const float* b_hh  = (const float*)d_in[11];
    const float* Wq_c  = (const float*)d_in[12];
    const float* Wk_c  = (const float*)d_in[13];
    const float* Wv_c  = (const float*)d_in[14];
    const float* Wo_c  = (const float*)d_in[15];
    const float* dec_W = (const float*)d_in[16];
    const float* dec_b = (const float*)d_in[17];
    float* out = (float*)d_out;

    const size_t AL = 256;
    auto pad = [&](size_t x) { return (x + AL - 1) & ~(AL - 1); };
    size_t fixedB = pad((size_t)NTOK * CNP * 4)
                  + pad((size_t)NTOK * 256 * 4)
                  + pad((size_t)HH * DK * BS * 4)
                  + pad((size_t)256 * 4)
                  + pad((size_t)CNP * 4)
                  + pad((size_t)CNP * 3 * KV0 * 2)
                  + pad((size_t)24 * UNP * 3 * UK0 * 2)
                  + pad((size_t)NTOK * DECKP * 2)
                  + 2 * pad((size_t)BATCH * NHID * 4);
    auto perC = [&](int C) {
        size_t MU = (size_t)C * BATCH;
        return pad(MU * 3 * KV0 * 2)
             + pad(MU * CNP * 4)
             + pad((size_t)HH * MU * 3 * UK0 * 2)
             + pad((size_t)24 * MU * G3 * 4)
             + pad(MU * DECKP * 2);
    };
    int C = 8;
    while (C > 1 && fixedB + perC(C) > ws_size) C >>= 1;
    const int MU = C * BATCH;
    const int NCH = T_STEPS / C;

    char* p = (char*)d_ws;
    auto alloc = [&](size_t bytes) { char* r = p; p += pad(bytes); return r; };
    float*          EWfull = (float*)alloc((size_t)NTOK * CNP * 4);
    float*          EWk    = (float*)alloc((size_t)NTOK * 256 * 4);
    float*          WqT    = (float*)alloc((size_t)HH * DK * BS * 4);
    float*          kbf    = (float*)alloc((size_t)256 * 4);
    float*          bias_c = (float*)alloc((size_t)CNP * 4);
    unsigned short* B_vkap = (unsigned short*)alloc((size_t)CNP * 3 * KV0 * 2);
    unsigned short* B_U    = (unsigned short*)alloc((size_t)24 * UNP * 3 * UK0 * 2);
    unsigned short* B_dec  = (unsigned short*)alloc((size_t)NTOK * DECKP * 2);
    float*          hA     = (float*)alloc((size_t)BATCH * NHID * 4);
    float*          hB     = (float*)alloc((size_t)BATCH * NHID * 4);
    unsigned short* A_in   = (unsigned short*)alloc((size_t)MU * 3 * KV0 * 2);
    float*          Cbuf   = (float*)alloc((size_t)MU * CNP * 4);
    unsigned short* A_U    = (unsigned short*)alloc((size_t)HH * MU * 3 * UK0 * 2);
    float*          Ubuf   = (float*)alloc((size_t)24 * MU * G3 * 4);
    unsigned short* A_dec  = (unsigned short*)alloc((size_t)MU * DECKP * 2);

    dim3 blk(256);
    ZOff z0 = {1, 0, 0};

    // ---- setup ----
    sgemm<<<dim3(6, 4, 1), blk, 0, stream>>>(
        enc_W, z0, NINP, Wv_in, z0, HH * DV, EWfull, z0, CNP, NTOK, VN, NINP);
    sgemm<<<dim3(4, 4, 1), blk, 0, stream>>>(
        enc_W, z0, NINP, Wk_in, z0, HH * DK, EWk, z0, 256, NTOK, HH * DK, NINP);
    prep_wqt<<<dim3((HH * DK * BS + 255) / 256), blk, 0, stream>>>(Wq_in, WqT);
    sgemm<<<dim3(2, 4, HH), blk, 0, stream>>>(
        EWk, ZOff{1, DK, 0}, 256, WqT, ZOff{1, (long)DK * BS, 0}, BS,
        EWfull + VN, ZOff{1, BS, 0}, CNP, NTOK, BS, DK);
    bias_k<<<dim3(1), blk, 0, stream>>>(enc_b, Wk_in, kbf);
    bias_c_kernel<<<dim3(3), blk, 0, stream>>>(enc_b, Wv_in, kbf, WqT, bias_c);
    cvt_split_ew<<<dim3((CNP * NTOK + 255) / 256), blk, 0, stream>>>(EWfull, B_vkap);
    cvt_split_bu<<<dim3((24 * UNP * UK0 + 255) / 256), blk, 0, stream>>>(W_ih, B_U);
    cvt_dec<<<dim3((NTOK * DECKP + 255) / 256), blk, 0, stream>>>(dec_W, B_dec);

    const float* hp = h0;
    float* hbufs[2] = { hA, hB };
    int t = 0;
    for (int c = 0; c < NCH; c++) {
        cvt_split_in<<<dim3(2048), blk, 0, stream>>>(
            input + (size_t)c * MU * NTOK, A_in, MU);
        gemm6<<<dim3(CNP / 128, MU / 128, 1), blk, 0, stream>>>(
            A_in, 0, 1, B_vkap, 0, Cbuf, 0, CNP, CN, bias_c, KV0);
        cvt_split_vu<<<dim3(2048), blk, 0, stream>>>(Cbuf, A_U, MU);
        gemm6<<<dim3(UNP / 128, MU / 128, 24), blk, 0, stream>>>(
            A_U, (long)MU * 3 * UK0, NBK, B_U, (long)UNP * 3 * UK0,
            Ubuf, (long)MU * G3, G3, G3, nullptr, UK0);
        for (int s = 0; s < C; s++, t++) {
            float* hout = hbufs[t & 1];
            step_fused<<<dim3(BATCH / NSAMP), blk, 0, stream>>>(
                hp, masks + (size_t)t * BATCH, Cbuf, Ubuf, b_ih, b_hh, W_hh,
                Wq_c, Wk_c, Wv_c, Wo_c, hout, A_dec, s, MU);
            hp = hout;
        }
        gemm_mfma<<<dim3(NTOK / 128, MU / 128, 1), blk, 0, stream>>>(
            A_dec, B_dec, out + (size_t)c * MU * NTOK, NTOK, dec_b, DECKP);
    }
}

// Round 7
// 11061.955 us; speedup vs baseline: 1.7860x; 1.1554x over previous
//
#include <hip/hip_runtime.h>
#include <math.h>

#define T_STEPS 128
#define BATCH   512
#define NTOK    512
#define NINP    512
#define NHID    600
#define NBK     6
#define BS      100
#define HH      4
#define DK      64
#define DV      85
#define ATT     340
#define H2      4
#define DK2     32
#define DV2     32
#define G3      300
#define VN      340
#define KAPN    400
#define CN      740
#define CNP     768
#define UNP     384
#define UK0     128
#define KV0     512
#define DECKP   640
#define SW      4        // samples per step-block

typedef __attribute__((ext_vector_type(8))) short short8;
typedef __attribute__((ext_vector_type(4))) float f32x4;

__device__ __forceinline__ float sigf(float x) { return 1.f / (1.f + expf(-x)); }
__device__ __forceinline__ unsigned short f2b(float f) {
    unsigned u = __float_as_uint(f);
    unsigned r = (u + 0x7fffu + ((u >> 16) & 1u)) >> 16;
    return (unsigned short)r;
}
__device__ __forceinline__ float b2f(unsigned short u) {
    return __uint_as_float(((unsigned)u) << 16);
}
__device__ __forceinline__ void split3(float x, unsigned short& hi,
                                       unsigned short& mid, unsigned short& lo) {
    hi = f2b(x);
    float r1 = x - b2f(hi);
    mid = f2b(r1);
    lo = f2b(r1 - b2f(mid));
}

struct ZOff { int div; long s1; long s2; };
__device__ __forceinline__ long zoff(ZOff z, int bz) {
    return (long)(bz / z.div) * z.s1 + (long)(bz % z.div) * z.s2;
}

// ===== bf16x6 MFMA GEMM: fp32-class C = A@B^T (+bias) via 6 segment passes =====
__global__ __launch_bounds__(256) void gemm6(
    const unsigned short* __restrict__ A, long aZ, int aZdiv,
    const unsigned short* __restrict__ B, long bZ,
    float* __restrict__ C, long cZ, int ldc, int Nreal,
    const float* __restrict__ bias, int K0)
{
    const int z = blockIdx.z;
    A += (long)(z / aZdiv) * aZ;
    B += (long)z * bZ;
    C += (long)z * cZ;
    const int LDA = 3 * K0;
    const int m0 = blockIdx.y * 128, n0 = blockIdx.x * 128;
    __shared__ __align__(16) unsigned short As[128 * 64];
    __shared__ __align__(16) unsigned short Bs[128 * 64];
    const int tid = threadIdx.x;
    const int lane = tid & 63;
    const int wid = tid >> 6;
    const int wr = wid >> 1, wc = wid & 1;

    f32x4 acc[4][4];
#pragma unroll
    for (int m = 0; m < 4; m++)
#pragma unroll
        for (int n = 0; n < 4; n++)
#pragma unroll
            for (int v = 0; v < 4; v++) acc[m][n][v] = 0.f;

    const int segA[6] = {0, 0, 1, 0, 2, 1};
    const int segB[6] = {0, 1, 0, 2, 0, 1};
    for (int p = 0; p < 6; p++) {
        const unsigned short* Ap = A + segA[p] * K0;
        const unsigned short* Bp = B + segB[p] * K0;
        for (int k0 = 0; k0 < K0; k0 += 64) {
            short8 ra[4], rb[4];
#pragma unroll
            for (int q = 0; q < 4; q++) {
                int idx = (q << 8) + tid;
                int r = idx >> 3, ce = (idx & 7) << 3;
                ra[q] = *(const short8*)&Ap[(long)(m0 + r) * LDA + k0 + ce];
                rb[q] = *(const short8*)&Bp[(long)(n0 + r) * LDA + k0 + ce];
            }
            __syncthreads();
#pragma unroll
            for (int q = 0; q < 4; q++) {
                int idx = (q << 8) + tid;
                int r = idx >> 3, ce = (idx & 7) << 3;
                *(short8*)&As[r * 64 + ce] = ra[q];
                *(short8*)&Bs[r * 64 + ce] = rb[q];
            }
            __syncthreads();
#pragma unroll
            for (int kk = 0; kk < 2; kk++) {
                short8 af[4], bfr[4];
#pragma unroll
                for (int m = 0; m < 4; m++)
                    af[m] = *(const short8*)&As[(wr * 64 + m * 16 + (lane & 15)) * 64 + kk * 32 + (lane >> 4) * 8];
#pragma unroll
                for (int n = 0; n < 4; n++)
                    bfr[n] = *(const short8*)&Bs[(wc * 64 + n * 16 + (lane & 15)) * 64 + kk * 32 + (lane >> 4) * 8];
#pragma unroll
                for (int m = 0; m < 4; m++)
#pragma unroll
                    for (int n = 0; n < 4; n++)
                        acc[m][n] = __builtin_amdgcn_mfma_f32_16x16x32_bf16(af[m], bfr[n], acc[m][n], 0, 0, 0);
            }
        }
    }
#pragma unroll
    for (int m = 0; m < 4; m++) {
        int rbase = m0 + wr * 64 + m * 16 + (lane >> 4) * 4;
#pragma unroll
        for (int n = 0; n < 4; n++) {
            int col = n0 + wc * 64 + n * 16 + (lane & 15);
            if (col < Nreal) {
                float bv = bias ? bias[col] : 0.f;
#pragma unroll
                for (int v = 0; v < 4; v++)
                    C[(long)(rbase + v) * ldc + col] = acc[m][n][v] + bv;
            }
        }
    }
}

// ===== plain bf16 MFMA GEMM (decoder only) =====
__global__ __launch_bounds__(256) void gemm_mfma(
    const unsigned short* __restrict__ A,
    const unsigned short* __restrict__ B,
    float* __restrict__ C, int ldc,
    const float* __restrict__ bias, int Kp)
{
    const int m0 = blockIdx.y * 128, n0 = blockIdx.x * 128;
    __shared__ __align__(16) unsigned short As[128 * 64];
    __shared__ __align__(16) unsigned short Bs[128 * 64];
    const int tid = threadIdx.x;
    const int lane = tid & 63;
    const int wid = tid >> 6;
    const int wr = wid >> 1, wc = wid & 1;

    f32x4 acc[4][4];
#pragma unroll
    for (int m = 0; m < 4; m++)
#pragma unroll
        for (int n = 0; n < 4; n++)
#pragma unroll
            for (int v = 0; v < 4; v++) acc[m][n][v] = 0.f;

    for (int k0 = 0; k0 < Kp; k0 += 64) {
        short8 ra[4], rb[4];
#pragma unroll
        for (int q = 0; q < 4; q++) {
            int idx = (q << 8) + tid;
            int r = idx >> 3, ce = (idx & 7) << 3;
            ra[q] = *(const short8*)&A[(long)(m0 + r) * Kp + k0 + ce];
            rb[q] = *(const short8*)&B[(long)(n0 + r) * Kp + k0 + ce];
        }
        __syncthreads();
#pragma unroll
        for (int q = 0; q < 4; q++) {
            int idx = (q << 8) + tid;
            int r = idx >> 3, ce = (idx & 7) << 3;
            *(short8*)&As[r * 64 + ce] = ra[q];
            *(short8*)&Bs[r * 64 + ce] = rb[q];
        }
        __syncthreads();
#pragma unroll
        for (int kk = 0; kk < 2; kk++) {
            short8 af[4], bfr[4];
#pragma unroll
            for (int m = 0; m < 4; m++)
                af[m] = *(const short8*)&As[(wr * 64 + m * 16 + (lane & 15)) * 64 + kk * 32 + (lane >> 4) * 8];
#pragma unroll
            for (int n = 0; n < 4; n++)
                bfr[n] = *(const short8*)&Bs[(wc * 64 + n * 16 + (lane & 15)) * 64 + kk * 32 + (lane >> 4) * 8];
#pragma unroll
            for (int m = 0; m < 4; m++)
#pragma unroll
                for (int n = 0; n < 4; n++)
                    acc[m][n] = __builtin_amdgcn_mfma_f32_16x16x32_bf16(af[m], bfr[n], acc[m][n], 0, 0, 0);
        }
    }
#pragma unroll
    for (int m = 0; m < 4; m++) {
        int rbase = m0 + wr * 64 + m * 16 + (lane >> 4) * 4;
#pragma unroll
        for (int n = 0; n < 4; n++) {
            int col = n0 + wc * 64 + n * 16 + (lane & 15);
            float bv = bias ? bias[col] : 0.f;
#pragma unroll
            for (int v = 0; v < 4; v++)
                C[(long)(rbase + v) * ldc + col] = acc[m][n][v] + bv;
        }
    }
}

// ===== fp32 SGEMM (setup-only small jobs) =====
__global__ __launch_bounds__(256) void sgemm(
    const float* __restrict__ A, ZOff za, int lda,
    const float* __restrict__ B, ZOff zb, int ldb,
    float* __restrict__ C, ZOff zc, int ldc,
    int M, int N, int K)
{
    const int bz = blockIdx.z;
    A += zoff(za, bz);
    B += zoff(zb, bz);
    C += zoff(zc, bz);
    const int m0 = blockIdx.y * 128, n0 = blockIdx.x * 64;
    __shared__ float As[16][132];
    __shared__ float Bs[16][68];
    const int tid = threadIdx.x;
    const int tm = tid >> 4, tn = tid & 15;
    const int ar = tid >> 1, ak = (tid & 1) * 8;
    const int bk = tid >> 4, bn = (tid & 15) * 4;

    float acc[8][4];
#pragma unroll
    for (int i = 0; i < 8; i++)
#pragma unroll
        for (int j = 0; j < 4; j++) acc[i][j] = 0.f;

    for (int k0 = 0; k0 < K; k0 += 16) {
        float av[8], bv[4];
#pragma unroll
        for (int j = 0; j < 8; j++) {
            int gk = k0 + ak + j;
            av[j] = (gk < K) ? A[(long)(m0 + ar) * lda + gk] : 0.f;
        }
#pragma unroll
        for (int j = 0; j < 4; j++) {
            int gk = k0 + bk, gn = n0 + bn + j;
            bv[j] = (gk < K && gn < N) ? B[(long)gk * ldb + gn] : 0.f;
        }
        __syncthreads();
#pragma unroll
        for (int j = 0; j < 8; j++) As[ak + j][ar] = av[j];
#pragma unroll
        for (int j = 0; j < 4; j++) Bs[bk][bn + j] = bv[j];
        __syncthreads();
#pragma unroll
        for (int kk = 0; kk < 16; kk++) {
            float a[8], b[4];
#pragma unroll
            for (int i = 0; i < 8; i++) a[i] = As[kk][tm * 8 + i];
#pragma unroll
            for (int j = 0; j < 4; j++) b[j] = Bs[kk][tn * 4 + j];
#pragma unroll
            for (int i = 0; i < 8; i++)
#pragma unroll
                for (int j = 0; j < 4; j++)
                    acc[i][j] += a[i] * b[j];
        }
    }
#pragma unroll
    for (int i = 0; i < 8; i++) {
        int gm = m0 + tm * 8 + i;
#pragma unroll
        for (int j = 0; j < 4; j++) {
            int gn = n0 + tn * 4 + j;
            if (gn < N) C[(long)gm * ldc + gn] = acc[i][j];
        }
    }
}

// ===== prep kernels (unchanged) =====
__global__ __launch_bounds__(256) void prep_wqt(const float* __restrict__ Wq_in,
                                                float* __restrict__ WqT)
{
    int idx = blockIdx.x * 256 + threadIdx.x;
    if (idx >= HH * DK * BS) return;
    int h = idx / (DK * BS), r = idx - h * DK * BS, d = r / BS, w = r - d * BS;
    WqT[idx] = Wq_in[w * (HH * DK) + h * DK + d];
}

__global__ __launch_bounds__(256) void bias_k(const float* __restrict__ enc_b,
                                              const float* __restrict__ Wk,
                                              float* __restrict__ kbf)
{
    int j = threadIdx.x;
    if (j >= HH * DK) return;
    float acc = 0.f;
    for (int d = 0; d < NINP; d++) acc += enc_b[d] * Wk[d * (HH * DK) + j];
    kbf[j] = acc;
}

__global__ __launch_bounds__(256) void bias_c_kernel(const float* __restrict__ enc_b,
                                                     const float* __restrict__ Wv,
                                                     const float* __restrict__ kbf,
                                                     const float* __restrict__ WqT,
                                                     float* __restrict__ bias_c)
{
    int j = blockIdx.x * 256 + threadIdx.x;
    if (j >= CNP) return;
    float acc = 0.f;
    if (j < VN) {
        for (int d = 0; d < NINP; d++) acc += enc_b[d] * Wv[d * (HH * DV) + j];
    } else if (j < CN) {
        int r = j - VN;
        int h = r / BS, w = r - h * BS;
        for (int d = 0; d < DK; d++)
            acc += kbf[h * DK + d] * WqT[(h * DK + d) * BS + w];
    }
    bias_c[j] = acc;
}

__global__ __launch_bounds__(256) void cvt_dec(const float* __restrict__ dec_W,
                                               unsigned short* __restrict__ dst)
{
    int idx = blockIdx.x * 256 + threadIdx.x;
    if (idx >= NTOK * DECKP) return;
    int n = idx / DECKP, k = idx - n * DECKP;
    dst[idx] = f2b(k < NHID ? dec_W[k * NTOK + n] : 0.f);
}

__global__ __launch_bounds__(256) void cvt_split_ew(const float* __restrict__ EWfull,
                                                    unsigned short* __restrict__ dst)
{
    int idx = blockIdx.x * 256 + threadIdx.x;
    if (idx >= CNP * NTOK) return;
    int n = idx / NTOK, k = idx - n * NTOK;
    float x = (n < CN) ? EWfull[(long)k * CNP + n] : 0.f;
    unsigned short hi, mid, lo;
    split3(x, hi, mid, lo);
    long base = (long)n * (3 * KV0) + k;
    dst[base] = hi;
    dst[base + KV0] = mid;
    dst[base + 2 * KV0] = lo;
}

__global__ __launch_bounds__(256) void cvt_split_bu(const float* __restrict__ W_ih,
                                                    unsigned short* __restrict__ dst)
{
    int idx = blockIdx.x * 256 + threadIdx.x;
    if (idx >= 24 * UNP * UK0) return;
    int z = idx / (UNP * UK0), r = idx - z * (UNP * UK0);
    int e = r / UK0, kk = r - e * UK0;
    int h = z / NBK, n = z - h * NBK;
    float x = 0.f;
    if (kk < DV && e < G3) x = W_ih[((long)n * ATT + h * DV + kk) * G3 + e];
    unsigned short hi, mid, lo;
    split3(x, hi, mid, lo);
    long base = ((long)z * UNP + e) * (3 * UK0) + kk;
    dst[base] = hi;
    dst[base + UK0] = mid;
    dst[base + 2 * UK0] = lo;
}

__global__ __launch_bounds__(256) void cvt_split_in(const float* __restrict__ src,
                                                    unsigned short* __restrict__ dst, long rows)
{
    long total = rows * NTOK;
    long i = (long)blockIdx.x * 256 + threadIdx.x;
    long stride = (long)gridDim.x * 256;
    for (; i < total; i += stride) {
        long row = i / NTOK; int k = (int)(i - row * NTOK);
        unsigned short hi, mid, lo;
        split3(src[i], hi, mid, lo);
        long base = row * (3 * KV0) + k;
        dst[base] = hi;
        dst[base + KV0] = mid;
        dst[base + 2 * KV0] = lo;
    }
}

__global__ __launch_bounds__(256) void cvt_split_vu(const float* __restrict__ Cbuf,
                                                    unsigned short* __restrict__ dst, int MU)
{
    long total = (long)HH * MU * UK0;
    long i = (long)blockIdx.x * 256 + threadIdx.x;
    long stride = (long)gridDim.x * 256;
    for (; i < total; i += stride) {
        int h = (int)(i / ((long)MU * UK0));
        long r = i - (long)h * MU * UK0;
        long row = r / UK0; int kk = (int)(r - row * UK0);
        float x = (kk < DV) ? Cbuf[row * CNP + h * DV + kk] : 0.f;
        unsigned short hi, mid, lo;
        split3(x, hi, mid, lo);
        long base = ((long)h * MU + row) * (3 * UK0) + kk;
        dst[base] = hi;
        dst[base + UK0] = mid;
        dst[base + 2 * UK0] = lo;
    }
}

// ===== step kernel v3: 4 samples/block, transposed state, dbuf panels =====
// grid 128 blocks, 256 threads
__global__ __launch_bounds__(256) void step_fused(
    const float* __restrict__ h_prev,       // [512,600]
    const float* __restrict__ masks_t,      // [512]
    const float* __restrict__ Cbuf,         // [MU,768]
    const float* __restrict__ U,            // [24,MU,300]
    const float* __restrict__ b_ih, const float* __restrict__ b_hh,
    const float* __restrict__ W_hh,         // [6,100,300]
    const float* __restrict__ Wq_c, const float* __restrict__ Wk_c,
    const float* __restrict__ Wv_c, const float* __restrict__ Wo_c,
    float* __restrict__ h_out,              // [512,600]
    unsigned short* __restrict__ A_dec,     // [MU,640] bf16
    int s_step, int MU)
{
    const int b0 = blockIdx.x * SW, tid = threadIdx.x;
    __shared__ __align__(16) float hbT[NHID][SW];
    __shared__ __align__(16) float hnT[NHID][SW];
    __shared__ __align__(16) float kp[SW][KAPN];
    __shared__ __align__(16) float qcb[SW][768], kcb[SW][768], vcb[SW][768];
    __shared__ __align__(16) float coT[768][SW];
    __shared__ float att[SW][24], acts[SW][NBK], mk[SW][NBK], kth[SW];
    __shared__ float lg[SW][144];
    __shared__ __align__(16) float wdf[12000];   // 48 KB panel dbuf

    const long rowd0 = (long)s_step * BATCH + b0;

    // ---- P0: load state (transposed) + kappa ----
    for (int i = tid; i < SW * NHID; i += 256) {
        int s = i / NHID, j = i - s * NHID;
        hbT[j][s] = h_prev[(long)(b0 + s) * NHID + j] * masks_t[b0 + s];
    }
    for (int i = tid; i < SW * KAPN; i += 256) {
        int s = i / KAPN, j = i - s * KAPN;
        kp[s][j] = Cbuf[(rowd0 + s) * CNP + VN + j];
    }
    __syncthreads();
    // ---- P1: input attention logits + top-k ----
    if (tid < SW * 24) {
        int s = tid / 24, r = tid - s * 24;
        int n = r >> 2, h = r & 3;
        float acc = 0.f;
        for (int w = 0; w < BS; w++) acc += hbT[n * BS + w][s] * kp[s][h * BS + w];
        att[s][r] = sigf(acc * 0.125f);          // softmax([l,0])[0] == sigmoid(l)
    }
    __syncthreads();
    if (tid < SW * NBK) {
        int s = tid / NBK, n = tid - s * NBK;
        acts[s][n] = 0.25f * (att[s][n * 4] + att[s][n * 4 + 1] + att[s][n * 4 + 2] + att[s][n * 4 + 3]);
    }
    __syncthreads();
    if (tid < SW) {
        float a[NBK];
        for (int i = 0; i < NBK; i++) a[i] = acts[tid][i];
        for (int i = 0; i < 4; i++) {
            int mx = i;
            for (int j = i + 1; j < NBK; j++) if (a[j] > a[mx]) mx = j;
            float t = a[i]; a[i] = a[mx]; a[mx] = t;
        }
        kth[tid] = a[3];
    }
    __syncthreads();
    if (tid < SW * NBK) {
        int s = tid / NBK, n = tid - s * NBK;
        mk[s][n] = (acts[s][n] >= kth[s]) ? 1.f : 0.f;
    }

    // ---- P2: gh via dbuf W_hh panels + gi gather + GRU pointwise ----
    const int np2 = tid < 200 ? tid / 100 : 0;
    const int w2 = tid < 200 ? tid - np2 * 100 : 0;
    for (int p = 0; p < 3; p++) {
        const int n = 2 * p + np2;
        const f32x4* Wp4 = (const f32x4*)(W_hh + (size_t)p * 60000);
        f32x4 pref[6];
        // preload chunk 0 (rows 0..9 of both n's of the pair)
#pragma unroll
        for (int k = 0; k < 6; k++) {
            int f4 = tid + (k << 8);
            if (f4 < 1500) pref[k] = Wp4[(f4 / 750) * 6750 + f4];
        }
        // issue U gather early (consumed after chunk loop)
        float uval[48];
        if (tid < 200) {
#pragma unroll
            for (int h = 0; h < HH; h++) {
                const float* Uh = U + ((size_t)(h * NBK + n) * MU + rowd0) * G3 + w2;
#pragma unroll
                for (int g = 0; g < 3; g++)
#pragma unroll
                    for (int s = 0; s < SW; s++)
                        uval[h * 12 + g * 4 + s] = Uh[(size_t)s * G3 + g * BS];
            }
        }
        float gh0[SW], gh1[SW], gh2[SW];
        {
            float bh0 = b_hh[n * G3 + w2], bh1 = b_hh[n * G3 + BS + w2], bh2 = b_hh[n * G3 + 2 * BS + w2];
#pragma unroll
            for (int s = 0; s < SW; s++) { gh0[s] = bh0; gh1[s] = bh1; gh2[s] = bh2; }
        }
        // write buf0 (safe: no one reads wdf buf0 until next barrier)
#pragma unroll
        for (int k = 0; k < 6; k++) {
            int f4 = tid + (k << 8);
            if (f4 < 1500) ((f32x4*)&wdf[0])[f4] = pref[k];
        }
        for (int c = 0; c < 10; c++) {
            __syncthreads();
            if (c < 9) {
                const f32x4* src = Wp4 + (c + 1) * 750;
#pragma unroll
                for (int k = 0; k < 6; k++) {
                    int f4 = tid + (k << 8);
                    if (f4 < 1500) pref[k] = src[(f4 / 750) * 6750 + f4];
                }
            }
            if (tid < 200) {
                const float* wb = &wdf[(c & 1) * 6000 + np2 * 3000];
#pragma unroll
                for (int r = 0; r < 10; r++) {
                    f32x4 hv = *(const f32x4*)&hbT[n * BS + c * 10 + r][0];
                    float w0v = wb[r * 300 + w2];
                    float w1v = wb[r * 300 + 100 + w2];
                    float w2v = wb[r * 300 + 200 + w2];
#pragma unroll
                    for (int s = 0; s < SW; s++) {
                        gh0[s] += w0v * hv[s];
                        gh1[s] += w1v * hv[s];
                        gh2[s] += w2v * hv[s];
                    }
                }
            }
            if (c < 9) {
#pragma unroll
                for (int k = 0; k < 6; k++) {
                    int f4 = tid + (k << 8);
                    if (f4 < 1500) ((f32x4*)&wdf[((c + 1) & 1) * 6000])[f4] = pref[k];
                }
            }
        }
        // GRU pointwise for this pair
        if (tid < 200) {
            float bi0 = b_ih[n * G3 + w2], bi1 = b_ih[n * G3 + BS + w2], bi2 = b_ih[n * G3 + 2 * BS + w2];
            f32x4 hnv;
#pragma unroll
            for (int s = 0; s < SW; s++) {
                float gi0 = bi0, gi1 = bi1, gi2 = bi2;
#pragma unroll
                for (int h = 0; h < HH; h++) {
                    float a = att[s][n * 4 + h];
                    gi0 += a * uval[h * 12 + 0 + s];
                    gi1 += a * uval[h * 12 + 4 + s];
                    gi2 += a * uval[h * 12 + 8 + s];
                }
                float rr = sigf(gi0 + gh0[s]);
                float zz = sigf(gi1 + gh1[s]);
                float ng = tanhf(gi2 + rr * gh2[s]);
                hnv[s] = (1.f - zz) * ng + zz * hbT[n * BS + w2][s];
            }
            *(f32x4*)&hnT[n * BS + w2][0] = hnv;
        }
    }

    // ---- P3: comm projections, all 6 n in registers, dbuf weight chunks ----
    {
        const int sm2 = tid >> 7;               // sample half: {0,1} -> samples {2*sm2, 2*sm2+1}
        const int c2 = tid & 127;
        float accq[NBK][2], acck[NBK][2], accv[NBK][2];
#pragma unroll
        for (int n = 0; n < NBK; n++)
#pragma unroll
            for (int ss = 0; ss < 2; ss++) { accq[n][ss] = 0.f; acck[n][ss] = 0.f; accv[n][ss] = 0.f; }
        f32x4 pref[4];
        // preload chunk 0: rows 0..9 of Wq,Wk,Wv (each 320 f32x4)
#pragma unroll
        for (int k = 0; k < 4; k++) {
            int f = tid + (k << 8);
            if (f < 960) {
                int m = f / 320, rem = f - m * 320;
                const f32x4* base = (m == 0) ? (const f32x4*)Wq_c : ((m == 1) ? (const f32x4*)Wk_c : (const f32x4*)Wv_c);
                pref[k] = base[rem];
            }
        }
#pragma unroll
        for (int k = 0; k < 4; k++) {
            int f = tid + (k << 8);
            if (f < 960) ((f32x4*)&wdf[0])[f] = pref[k];
        }
        for (int c = 0; c < 10; c++) {
            __syncthreads();
            if (c < 9) {
#pragma unroll
                for (int k = 0; k < 4; k++) {
                    int f = tid + (k << 8);
                    if (f < 960) {
                        int m = f / 320, rem = f - m * 320;
                        const f32x4* base = (m == 0) ? (const f32x4*)Wq_c : ((m == 1) ? (const f32x4*)Wk_c : (const f32x4*)Wv_c);
                        pref[k] = base[(c + 1) * 320 + rem];
                    }
                }
            }
            {
                const float* wb = &wdf[(c & 1) * 3840];
#pragma unroll
                for (int dl = 0; dl < 10; dl++) {
                    int d = c * 10 + dl;
                    float wq = wb[dl * 128 + c2];
                    float wk = wb[1280 + dl * 128 + c2];
                    float wv = wb[2560 + dl * 128 + c2];
#pragma unroll
                    for (int n = 0; n < NBK; n++) {
                        float2 hv = *(const float2*)&hnT[n * BS + d][sm2 * 2];
                        accq[n][0] += wq * hv.x; accq[n][1] += wq * hv.y;
                        acck[n][0] += wk * hv.x; acck[n][1] += wk * hv.y;
                        accv[n][0] += wv * hv.x; accv[n][1] += wv * hv.y;
                    }
                }
            }
            if (c < 9) {
#pragma unroll
                for (int k = 0; k < 4; k++) {
                    int f = tid + (k << 8);
                    if (f < 960) ((f32x4*)&wdf[((c + 1) & 1) * 3840])[f] = pref[k];
                }
            }
        }
#pragma unroll
        for (int n = 0; n < NBK; n++)
#pragma unroll
            for (int ss = 0; ss < 2; ss++) {
                qcb[sm2 * 2 + ss][n * 128 + c2] = accq[n][ss];
                kcb[sm2 * 2 + ss][n * 128 + c2] = acck[n][ss];
                vcb[sm2 * 2 + ss][n * 128 + c2] = accv[n][ss];
            }
    }
    __syncthreads();

    // ---- P4: comm attention (logits, softmax, co) ; stage Wo half0 meanwhile ----
    f32x4 wopref[7];
#pragma unroll
    for (int k = 0; k < 7; k++) {
        int f = tid + (k << 8);
        if (f < 1600) wopref[k] = ((const f32x4*)Wo_c)[f];
    }
    for (int idx = tid; idx < SW * 144; idx += 256) {
        int s = idx / 144, r = idx - s * 144;
        int h = r / 36, r2 = r - h * 36, n = r2 / NBK, m = r2 - n * NBK;
        float sv = 0.f;
#pragma unroll
        for (int e4 = 0; e4 < 8; e4++) {
            f32x4 qv = *(const f32x4*)&qcb[s][n * 128 + h * 32 + e4 * 4];
            f32x4 kv = *(const f32x4*)&kcb[s][m * 128 + h * 32 + e4 * 4];
            sv += qv[0] * kv[0] + qv[1] * kv[1] + qv[2] * kv[2] + qv[3] * kv[3];
        }
        lg[s][r] = sv * 0.17677669529663687f;
    }
    __syncthreads();
    if (tid < SW * 24) {
        int s = tid / 24, r = tid - s * 24;
        float* row = &lg[s][r * NBK];
        float mx = row[0];
        for (int m = 1; m < NBK; m++) mx = fmaxf(mx, row[m]);
        float sv = 0.f;
        for (int m = 0; m < NBK; m++) { row[m] = expf(row[m] - mx); sv += row[m]; }
        float inv = 1.f / sv;
        for (int m = 0; m < NBK; m++) row[m] *= inv;
    }
    __syncthreads();
    for (int idx = tid; idx < SW * 768; idx += 256) {
        int s = idx / 768, r = idx - s * 768;
        int n = r >> 7, d = r & 127, h = d >> 5;
        float a = 0.f;
#pragma unroll
        for (int m = 0; m < NBK; m++) a += lg[s][h * 36 + n * NBK + m] * vcb[s][m * 128 + d];
        coT[r][s] = a;
    }
    // write Wo half0 into wdf (wdf free since P3 end-barrier)
#pragma unroll
    for (int k = 0; k < 7; k++) {
        int f = tid + (k << 8);
        if (f < 1600) ((f32x4*)&wdf[0])[f] = wopref[k];
    }
    // issue Wo half1 loads
#pragma unroll
    for (int k = 0; k < 7; k++) {
        int f = tid + (k << 8);
        if (f < 1600) wopref[k] = ((const f32x4*)(Wo_c + 6400))[f];
    }
    __syncthreads();

    // ---- P5: co @ Wo_c in 2 d-halves + select ----
    const int n5 = tid / 40;                    // 0..5 for tid<240
    const int r5 = tid - n5 * 40;
    const int sm5 = r5 / 20;                    // sample half
    const int ws5 = (r5 - sm5 * 20) * 5;        // w base (5 outputs)
    float acc5[5][2];
#pragma unroll
    for (int j = 0; j < 5; j++) { acc5[j][0] = 0.f; acc5[j][1] = 0.f; }
    for (int dg = 0; dg < 2; dg++) {
        if (tid < 240) {
            for (int d = 0; d < 64; d++) {
                int dd = dg * 64 + d;
                float2 cv = *(const float2*)&coT[n5 * 128 + dd][sm5 * 2];
#pragma unroll
                for (int j = 0; j < 5; j++) {
                    float wv = wdf[d * 100 + ws5 + j];
                    acc5[j][0] += cv.x * wv;
                    acc5[j][1] += cv.y * wv;
                }
            }
        }
        __syncthreads();
        if (dg == 0) {
            // write half1 weights, then barrier before dg1 compute
#pragma unroll
            for (int k = 0; k < 7; k++) {
                int f = tid + (k << 8);
                if (f < 1600) ((f32x4*)&wdf[0])[f] = wopref[k];
            }
            __syncthreads();
        }
    }
    // select: hf = mk ? hn + co@Wo : hb  -> store into hbT
    if (tid < 240) {
        float mk0 = mk[sm5 * 2 + 0][n5], mk1 = mk[sm5 * 2 + 1][n5];
#pragma unroll
        for (int j = 0; j < 5; j++) {
            int o = n5 * BS + ws5 + j;
            float2 hnv = *(const float2*)&hnT[o][sm5 * 2];
            float2 hbv = *(const float2*)&hbT[o][sm5 * 2];
            float2 rv;
            rv.x = (mk0 > 0.5f) ? hnv.x + acc5[j][0] : hbv.x;
            rv.y = (mk1 > 0.5f) ? hnv.y + acc5[j][1] : hbv.y;
            *(float2*)&hbT[o][sm5 * 2] = rv;
        }
    }
    __syncthreads();
    // ---- P6: coalesced global writes ----
    for (int i = tid; i < SW * NHID; i += 256) {
        int s = i / NHID, j = i - s * NHID;
        h_out[(long)(b0 + s) * NHID + j] = hbT[j][s];
    }
    for (int i = tid; i < SW * DECKP; i += 256) {
        int s = i / DECKP, col = i - s * DECKP;
        A_dec[(rowd0 + s) * DECKP + col] = f2b(col < NHID ? hbT[col][s] : 0.f);
    }
}

// ===== host launch =====
extern "C" void kernel_launch(void* const* d_in, const int* in_sizes, int n_in,
                              void* d_out, int out_size, void* d_ws, size_t ws_size,
                              hipStream_t stream)
{
    const float* input = (const float*)d_in[0];
    const float* h0    = (const float*)d_in[1];
    const float* masks = (const float*)d_in[2];
    const float* enc_W = (const float*)d_in[3];
    const float* enc_b = (const float*)d_in[4];
    const float* Wq_in = (const float*)d_in[5];
    const float* Wk_in = (const float*)d_in[6];
    const float* Wv_in = (const float*)d_in[7];
    const float* W_ih  = (const float*)d_in[8];
    const float* W_hh  = (const float*)d_in[9];
    const float* b_ih  = (const float*)d_in[10];
    const float* b_hh  = (const float*)d_in[11];
    const float* Wq_c  = (const float*)d_in[12];
    const float* Wk_c  = (const float*)d_in[13];
    const float* Wv_c  = (const float*)d_in[14];
    const float* Wo_c  = (const float*)d_in[15];
    const float* dec_W = (const float*)d_in[16];
    const float* dec_b = (const float*)d_in[17];
    float* out = (float*)d_out;

    const size_t AL = 256;
    auto pad = [&](size_t x) { return (x + AL - 1) & ~(AL - 1); };
    size_t fixedB = pad((size_t)NTOK * CNP * 4)
                  + pad((size_t)NTOK * 256 * 4)
                  + pad((size_t)HH * DK * BS * 4)
                  + pad((size_t)256 * 4)
                  + pad((size_t)CNP * 4)
                  + pad((size_t)CNP * 3 * KV0 * 2)
                  + pad((size_t)24 * UNP * 3 * UK0 * 2)
                  + pad((size_t)NTOK * DECKP * 2)
                  + 2 * pad((size_t)BATCH * NHID * 4);
    auto perC = [&](int C) {
        size_t MU = (size_t)C * BATCH;
        return pad(MU * 3 * KV0 * 2)
             + pad(MU * CNP * 4)
             + pad((size_t)HH * MU * 3 * UK0 * 2)
             + pad((size_t)24 * MU * G3 * 4)
             + pad(MU * DECKP * 2);
    };
    int C = 8;
    while (C > 1 && fixedB + perC(C) > ws_size) C >>= 1;
    const int MU = C * BATCH;
    const int NCH = T_STEPS / C;

    char* p = (char*)d_ws;
    auto alloc = [&](size_t bytes) { char* r = p; p += pad(bytes); return r; };
    float*          EWfull = (float*)alloc((size_t)NTOK * CNP * 4);
    float*          EWk    = (float*)alloc((size_t)NTOK * 256 * 4);
    float*          WqT    = (float*)alloc((size_t)HH * DK * BS * 4);
    float*          kbf    = (float*)alloc((size_t)256 * 4);
    float*          bias_c = (float*)alloc((size_t)CNP * 4);
    unsigned short* B_vkap = (unsigned short*)alloc((size_t)CNP * 3 * KV0 * 2);
    unsigned short* B_U    = (unsigned short*)alloc((size_t)24 * UNP * 3 * UK0 * 2);
    unsigned short* B_dec  = (unsigned short*)alloc((size_t)NTOK * DECKP * 2);
    float*          hA     = (float*)alloc((size_t)BATCH * NHID * 4);
    float*          hB     = (float*)alloc((size_t)BATCH * NHID * 4);
    unsigned short* A_in   = (unsigned short*)alloc((size_t)MU * 3 * KV0 * 2);
    float*          Cbuf   = (float*)alloc((size_t)MU * CNP * 4);
    unsigned short* A_U    = (unsigned short*)alloc((size_t)HH * MU * 3 * UK0 * 2);
    float*          Ubuf   = (float*)alloc((size_t)24 * MU * G3 * 4);
    unsigned short* A_dec  = (unsigned short*)alloc((size_t)MU * DECKP * 2);

    dim3 blk(256);
    ZOff z0 = {1, 0, 0};

    // ---- setup ----
    sgemm<<<dim3(6, 4, 1), blk, 0, stream>>>(
        enc_W, z0, NINP, Wv_in, z0, HH * DV, EWfull, z0, CNP, NTOK, VN, NINP);
    sgemm<<<dim3(4, 4, 1), blk, 0, stream>>>(
        enc_W, z0, NINP, Wk_in, z0, HH * DK, EWk, z0, 256, NTOK, HH * DK, NINP);
    prep_wqt<<<dim3((HH * DK * BS + 255) / 256), blk, 0, stream>>>(Wq_in, WqT);
    sgemm<<<dim3(2, 4, HH), blk, 0, stream>>>(
        EWk, ZOff{1, DK, 0}, 256, WqT, ZOff{1, (long)DK * BS, 0}, BS,
        EWfull + VN, ZOff{1, BS, 0}, CNP, NTOK, BS, DK);
    bias_k<<<dim3(1), blk, 0, stream>>>(enc_b, Wk_in, kbf);
    bias_c_kernel<<<dim3(3), blk, 0, stream>>>(enc_b, Wv_in, kbf, WqT, bias_c);
    cvt_split_ew<<<dim3((CNP * NTOK + 255) / 256), blk, 0, stream>>>(EWfull, B_vkap);
    cvt_split_bu<<<dim3((24 * UNP * UK0 + 255) / 256), blk, 0, stream>>>(W_ih, B_U);
    cvt_dec<<<dim3((NTOK * DECKP + 255) / 256), blk, 0, stream>>>(dec_W, B_dec);

    const float* hp = h0;
    float* hbufs[2] = { hA, hB };
    int t = 0;
    for (int c = 0; c < NCH; c++) {
        cvt_split_in<<<dim3(2048), blk, 0, stream>>>(
            input + (size_t)c * MU * NTOK, A_in, MU);
        gemm6<<<dim3(CNP / 128, MU / 128, 1), blk, 0, stream>>>(
            A_in, 0, 1, B_vkap, 0, Cbuf, 0, CNP, CN, bias_c, KV0);
        cvt_split_vu<<<dim3(2048), blk, 0, stream>>>(Cbuf, A_U, MU);
        gemm6<<<dim3(UNP / 128, MU / 128, 24), blk, 0, stream>>>(
            A_U, (long)MU * 3 * UK0, NBK, B_U, (long)UNP * 3 * UK0,
            Ubuf, (long)MU * G3, G3, G3, nullptr, UK0);
        for (int s = 0; s < C; s++, t++) {
            float* hout = hbufs[t & 1];
            step_fused<<<dim3(BATCH / SW), blk, 0, stream>>>(
                hp, masks + (size_t)t * BATCH, Cbuf, Ubuf, b_ih, b_hh, W_hh,
                Wq_c, Wk_c, Wv_c, Wo_c, hout, A_dec, s, MU);
            hp = hout;
        }
        gemm_mfma<<<dim3(NTOK / 128, MU / 128, 1), blk, 0, stream>>>(
            A_dec, B_dec, out + (size_t)c * MU * NTOK, NTOK, dec_b, DECKP);
    }
}

// Round 8
// 7540.098 us; speedup vs baseline: 2.6203x; 1.4671x over previous
//
#include <hip/hip_runtime.h>
#include <math.h>

#define T_STEPS 128
#define BATCH   512
#define NTOK    512
#define NINP    512
#define NHID    600
#define NBK     6
#define BS      100
#define HH      4
#define DK      64
#define DV      85
#define ATT     340
#define H2      4
#define DK2     32
#define DV2     32
#define G3      300
#define VN      340
#define KAPN    400
#define CN      740
#define CNP     768
#define UNP     384
#define UK0     128
#define KV0     512
#define DECKP   640
#define SW      4        // samples per step-block

typedef __attribute__((ext_vector_type(8))) short short8;
typedef __attribute__((ext_vector_type(4))) float f32x4;

__device__ __forceinline__ float sigf(float x) { return 1.f / (1.f + expf(-x)); }
__device__ __forceinline__ unsigned short f2b(float f) {
    unsigned u = __float_as_uint(f);
    unsigned r = (u + 0x7fffu + ((u >> 16) & 1u)) >> 16;
    return (unsigned short)r;
}
__device__ __forceinline__ float b2f(unsigned short u) {
    return __uint_as_float(((unsigned)u) << 16);
}
__device__ __forceinline__ void split3(float x, unsigned short& hi,
                                       unsigned short& mid, unsigned short& lo) {
    hi = f2b(x);
    float r1 = x - b2f(hi);
    mid = f2b(r1);
    lo = f2b(r1 - b2f(mid));
}

struct ZOff { int div; long s1; long s2; };
__device__ __forceinline__ long zoff(ZOff z, int bz) {
    return (long)(bz / z.div) * z.s1 + (long)(bz % z.div) * z.s2;
}

// ===== bf16x6 MFMA GEMM: fp32-class C = A@B^T (+bias) via 6 segment passes =====
__global__ __launch_bounds__(256) void gemm6(
    const unsigned short* __restrict__ A, long aZ, int aZdiv,
    const unsigned short* __restrict__ B, long bZ,
    float* __restrict__ C, long cZ, int ldc, int Nreal,
    const float* __restrict__ bias, int K0)
{
    const int z = blockIdx.z;
    A += (long)(z / aZdiv) * aZ;
    B += (long)z * bZ;
    C += (long)z * cZ;
    const int LDA = 3 * K0;
    const int m0 = blockIdx.y * 128, n0 = blockIdx.x * 128;
    __shared__ __align__(16) unsigned short As[128 * 64];
    __shared__ __align__(16) unsigned short Bs[128 * 64];
    const int tid = threadIdx.x;
    const int lane = tid & 63;
    const int wid = tid >> 6;
    const int wr = wid >> 1, wc = wid & 1;

    f32x4 acc[4][4];
#pragma unroll
    for (int m = 0; m < 4; m++)
#pragma unroll
        for (int n = 0; n < 4; n++)
#pragma unroll
            for (int v = 0; v < 4; v++) acc[m][n][v] = 0.f;

    const int segA[6] = {0, 0, 1, 0, 2, 1};
    const int segB[6] = {0, 1, 0, 2, 0, 1};
    for (int p = 0; p < 6; p++) {
        const unsigned short* Ap = A + segA[p] * K0;
        const unsigned short* Bp = B + segB[p] * K0;
        for (int k0 = 0; k0 < K0; k0 += 64) {
            short8 ra[4], rb[4];
#pragma unroll
            for (int q = 0; q < 4; q++) {
                int idx = (q << 8) + tid;
                int r = idx >> 3, ce = (idx & 7) << 3;
                ra[q] = *(const short8*)&Ap[(long)(m0 + r) * LDA + k0 + ce];
                rb[q] = *(const short8*)&Bp[(long)(n0 + r) * LDA + k0 + ce];
            }
            __syncthreads();
#pragma unroll
            for (int q = 0; q < 4; q++) {
                int idx = (q << 8) + tid;
                int r = idx >> 3, ce = (idx & 7) << 3;
                *(short8*)&As[r * 64 + ce] = ra[q];
                *(short8*)&Bs[r * 64 + ce] = rb[q];
            }
            __syncthreads();
#pragma unroll
            for (int kk = 0; kk < 2; kk++) {
                short8 af[4], bfr[4];
#pragma unroll
                for (int m = 0; m < 4; m++)
                    af[m] = *(const short8*)&As[(wr * 64 + m * 16 + (lane & 15)) * 64 + kk * 32 + (lane >> 4) * 8];
#pragma unroll
                for (int n = 0; n < 4; n++)
                    bfr[n] = *(const short8*)&Bs[(wc * 64 + n * 16 + (lane & 15)) * 64 + kk * 32 + (lane >> 4) * 8];
#pragma unroll
                for (int m = 0; m < 4; m++)
#pragma unroll
                    for (int n = 0; n < 4; n++)
                        acc[m][n] = __builtin_amdgcn_mfma_f32_16x16x32_bf16(af[m], bfr[n], acc[m][n], 0, 0, 0);
            }
        }
    }
#pragma unroll
    for (int m = 0; m < 4; m++) {
        int rbase = m0 + wr * 64 + m * 16 + (lane >> 4) * 4;
#pragma unroll
        for (int n = 0; n < 4; n++) {
            int col = n0 + wc * 64 + n * 16 + (lane & 15);
            if (col < Nreal) {
                float bv = bias ? bias[col] : 0.f;
#pragma unroll
                for (int v = 0; v < 4; v++)
                    C[(long)(rbase + v) * ldc + col] = acc[m][n][v] + bv;
            }
        }
    }
}

// ===== plain bf16 MFMA GEMM (decoder only) =====
__global__ __launch_bounds__(256) void gemm_mfma(
    const unsigned short* __restrict__ A,
    const unsigned short* __restrict__ B,
    float* __restrict__ C, int ldc,
    const float* __restrict__ bias, int Kp)
{
    const int m0 = blockIdx.y * 128, n0 = blockIdx.x * 128;
    __shared__ __align__(16) unsigned short As[128 * 64];
    __shared__ __align__(16) unsigned short Bs[128 * 64];
    const int tid = threadIdx.x;
    const int lane = tid & 63;
    const int wid = tid >> 6;
    const int wr = wid >> 1, wc = wid & 1;

    f32x4 acc[4][4];
#pragma unroll
    for (int m = 0; m < 4; m++)
#pragma unroll
        for (int n = 0; n < 4; n++)
#pragma unroll
            for (int v = 0; v < 4; v++) acc[m][n][v] = 0.f;

    for (int k0 = 0; k0 < Kp; k0 += 64) {
        short8 ra[4], rb[4];
#pragma unroll
        for (int q = 0; q < 4; q++) {
            int idx = (q << 8) + tid;
            int r = idx >> 3, ce = (idx & 7) << 3;
            ra[q] = *(const short8*)&A[(long)(m0 + r) * Kp + k0 + ce];
            rb[q] = *(const short8*)&B[(long)(n0 + r) * Kp + k0 + ce];
        }
        __syncthreads();
#pragma unroll
        for (int q = 0; q < 4; q++) {
            int idx = (q << 8) + tid;
            int r = idx >> 3, ce = (idx & 7) << 3;
            *(short8*)&As[r * 64 + ce] = ra[q];
            *(short8*)&Bs[r * 64 + ce] = rb[q];
        }
        __syncthreads();
#pragma unroll
        for (int kk = 0; kk < 2; kk++) {
            short8 af[4], bfr[4];
#pragma unroll
            for (int m = 0; m < 4; m++)
                af[m] = *(const short8*)&As[(wr * 64 + m * 16 + (lane & 15)) * 64 + kk * 32 + (lane >> 4) * 8];
#pragma unroll
            for (int n = 0; n < 4; n++)
                bfr[n] = *(const short8*)&Bs[(wc * 64 + n * 16 + (lane & 15)) * 64 + kk * 32 + (lane >> 4) * 8];
#pragma unroll
            for (int m = 0; m < 4; m++)
#pragma unroll
                for (int n = 0; n < 4; n++)
                    acc[m][n] = __builtin_amdgcn_mfma_f32_16x16x32_bf16(af[m], bfr[n], acc[m][n], 0, 0, 0);
        }
    }
#pragma unroll
    for (int m = 0; m < 4; m++) {
        int rbase = m0 + wr * 64 + m * 16 + (lane >> 4) * 4;
#pragma unroll
        for (int n = 0; n < 4; n++) {
            int col = n0 + wc * 64 + n * 16 + (lane & 15);
            float bv = bias ? bias[col] : 0.f;
#pragma unroll
            for (int v = 0; v < 4; v++)
                C[(long)(rbase + v) * ldc + col] = acc[m][n][v] + bv;
        }
    }
}

// ===== fp32 SGEMM (setup-only small jobs) =====
__global__ __launch_bounds__(256) void sgemm(
    const float* __restrict__ A, ZOff za, int lda,
    const float* __restrict__ B, ZOff zb, int ldb,
    float* __restrict__ C, ZOff zc, int ldc,
    int M, int N, int K)
{
    const int bz = blockIdx.z;
    A += zoff(za, bz);
    B += zoff(zb, bz);
    C += zoff(zc, bz);
    const int m0 = blockIdx.y * 128, n0 = blockIdx.x * 64;
    __shared__ float As[16][132];
    __shared__ float Bs[16][68];
    const int tid = threadIdx.x;
    const int tm = tid >> 4, tn = tid & 15;
    const int ar = tid >> 1, ak = (tid & 1) * 8;
    const int bk = tid >> 4, bn = (tid & 15) * 4;

    float acc[8][4];
#pragma unroll
    for (int i = 0; i < 8; i++)
#pragma unroll
        for (int j = 0; j < 4; j++) acc[i][j] = 0.f;

    for (int k0 = 0; k0 < K; k0 += 16) {
        float av[8], bv[4];
#pragma unroll
        for (int j = 0; j < 8; j++) {
            int gk = k0 + ak + j;
            av[j] = (gk < K) ? A[(long)(m0 + ar) * lda + gk] : 0.f;
        }
#pragma unroll
        for (int j = 0; j < 4; j++) {
            int gk = k0 + bk, gn = n0 + bn + j;
            bv[j] = (gk < K && gn < N) ? B[(long)gk * ldb + gn] : 0.f;
        }
        __syncthreads();
#pragma unroll
        for (int j = 0; j < 8; j++) As[ak + j][ar] = av[j];
#pragma unroll
        for (int j = 0; j < 4; j++) Bs[bk][bn + j] = bv[j];
        __syncthreads();
#pragma unroll
        for (int kk = 0; kk < 16; kk++) {
            float a[8], b[4];
#pragma unroll
            for (int i = 0; i < 8; i++) a[i] = As[kk][tm * 8 + i];
#pragma unroll
            for (int j = 0; j < 4; j++) b[j] = Bs[kk][tn * 4 + j];
#pragma unroll
            for (int i = 0; i < 8; i++)
#pragma unroll
                for (int j = 0; j < 4; j++)
                    acc[i][j] += a[i] * b[j];
        }
    }
#pragma unroll
    for (int i = 0; i < 8; i++) {
        int gm = m0 + tm * 8 + i;
#pragma unroll
        for (int j = 0; j < 4; j++) {
            int gn = n0 + tn * 4 + j;
            if (gn < N) C[(long)gm * ldc + gn] = acc[i][j];
        }
    }
}

// ===== prep kernels (unchanged) =====
__global__ __launch_bounds__(256) void prep_wqt(const float* __restrict__ Wq_in,
                                                float* __restrict__ WqT)
{
    int idx = blockIdx.x * 256 + threadIdx.x;
    if (idx >= HH * DK * BS) return;
    int h = idx / (DK * BS), r = idx - h * DK * BS, d = r / BS, w = r - d * BS;
    WqT[idx] = Wq_in[w * (HH * DK) + h * DK + d];
}

__global__ __launch_bounds__(256) void bias_k(const float* __restrict__ enc_b,
                                              const float* __restrict__ Wk,
                                              float* __restrict__ kbf)
{
    int j = threadIdx.x;
    if (j >= HH * DK) return;
    float acc = 0.f;
    for (int d = 0; d < NINP; d++) acc += enc_b[d] * Wk[d * (HH * DK) + j];
    kbf[j] = acc;
}

__global__ __launch_bounds__(256) void bias_c_kernel(const float* __restrict__ enc_b,
                                                     const float* __restrict__ Wv,
                                                     const float* __restrict__ kbf,
                                                     const float* __restrict__ WqT,
                                                     float* __restrict__ bias_c)
{
    int j = blockIdx.x * 256 + threadIdx.x;
    if (j >= CNP) return;
    float acc = 0.f;
    if (j < VN) {
        for (int d = 0; d < NINP; d++) acc += enc_b[d] * Wv[d * (HH * DV) + j];
    } else if (j < CN) {
        int r = j - VN;
        int h = r / BS, w = r - h * BS;
        for (int d = 0; d < DK; d++)
            acc += kbf[h * DK + d] * WqT[(h * DK + d) * BS + w];
    }
    bias_c[j] = acc;
}

__global__ __launch_bounds__(256) void cvt_dec(const float* __restrict__ dec_W,
                                               unsigned short* __restrict__ dst)
{
    int idx = blockIdx.x * 256 + threadIdx.x;
    if (idx >= NTOK * DECKP) return;
    int n = idx / DECKP, k = idx - n * DECKP;
    dst[idx] = f2b(k < NHID ? dec_W[k * NTOK + n] : 0.f);
}

__global__ __launch_bounds__(256) void cvt_split_ew(const float* __restrict__ EWfull,
                                                    unsigned short* __restrict__ dst)
{
    int idx = blockIdx.x * 256 + threadIdx.x;
    if (idx >= CNP * NTOK) return;
    int n = idx / NTOK, k = idx - n * NTOK;
    float x = (n < CN) ? EWfull[(long)k * CNP + n] : 0.f;
    unsigned short hi, mid, lo;
    split3(x, hi, mid, lo);
    long base = (long)n * (3 * KV0) + k;
    dst[base] = hi;
    dst[base + KV0] = mid;
    dst[base + 2 * KV0] = lo;
}

__global__ __launch_bounds__(256) void cvt_split_bu(const float* __restrict__ W_ih,
                                                    unsigned short* __restrict__ dst)
{
    int idx = blockIdx.x * 256 + threadIdx.x;
    if (idx >= 24 * UNP * UK0) return;
    int z = idx / (UNP * UK0), r = idx - z * (UNP * UK0);
    int e = r / UK0, kk = r - e * UK0;
    int h = z / NBK, n = z - h * NBK;
    float x = 0.f;
    if (kk < DV && e < G3) x = W_ih[((long)n * ATT + h * DV + kk) * G3 + e];
    unsigned short hi, mid, lo;
    split3(x, hi, mid, lo);
    long base = ((long)z * UNP + e) * (3 * UK0) + kk;
    dst[base] = hi;
    dst[base + UK0] = mid;
    dst[base + 2 * UK0] = lo;
}

__global__ __launch_bounds__(256) void cvt_split_in(const float* __restrict__ src,
                                                    unsigned short* __restrict__ dst, long rows)
{
    long total = rows * NTOK;
    long i = (long)blockIdx.x * 256 + threadIdx.x;
    long stride = (long)gridDim.x * 256;
    for (; i < total; i += stride) {
        long row = i / NTOK; int k = (int)(i - row * NTOK);
        unsigned short hi, mid, lo;
        split3(src[i], hi, mid, lo);
        long base = row * (3 * KV0) + k;
        dst[base] = hi;
        dst[base + KV0] = mid;
        dst[base + 2 * KV0] = lo;
    }
}

__global__ __launch_bounds__(256) void cvt_split_vu(const float* __restrict__ Cbuf,
                                                    unsigned short* __restrict__ dst, int MU)
{
    long total = (long)HH * MU * UK0;
    long i = (long)blockIdx.x * 256 + threadIdx.x;
    long stride = (long)gridDim.x * 256;
    for (; i < total; i += stride) {
        int h = (int)(i / ((long)MU * UK0));
        long r = i - (long)h * MU * UK0;
        long row = r / UK0; int kk = (int)(r - row * UK0);
        float x = (kk < DV) ? Cbuf[row * CNP + h * DV + kk] : 0.f;
        unsigned short hi, mid, lo;
        split3(x, hi, mid, lo);
        long base = ((long)h * MU + row) * (3 * UK0) + kk;
        dst[base] = hi;
        dst[base + UK0] = mid;
        dst[base + 2 * UK0] = lo;
    }
}

// ===== step kernel v4: 1024 threads (16 waves), 4 samples, direct-L2 weights =====
// grid 128 blocks. Weights read coalesced from L2; latency hidden by 4 waves/SIMD.
__global__ __launch_bounds__(1024) void step_fused(
    const float* __restrict__ h_prev,       // [512,600]
    const float* __restrict__ masks_t,      // [512]
    const float* __restrict__ Cbuf,         // [MU,768]
    const float* __restrict__ U,            // [24,MU,300]
    const float* __restrict__ b_ih, const float* __restrict__ b_hh,
    const float* __restrict__ W_hh,         // [6,100,300]
    const float* __restrict__ Wq_c, const float* __restrict__ Wk_c,
    const float* __restrict__ Wv_c, const float* __restrict__ Wo_c,
    float* __restrict__ h_out,              // [512,600]
    unsigned short* __restrict__ A_dec,     // [MU,640] bf16
    int s_step, int MU)
{
    const int b0 = blockIdx.x * SW, tid = threadIdx.x;
    __shared__ __align__(16) float hbT[NHID][SW];
    __shared__ __align__(16) float hnT[NHID][SW];
    __shared__ __align__(16) float kp[SW][KAPN];
    __shared__ __align__(16) float qcb[SW][768], kcb[SW][768], vcb[SW][768];
    __shared__ __align__(16) float coT[NBK * 128][SW];
    __shared__ float part[384];
    __shared__ float att[SW][24], mk[SW][NBK];
    __shared__ float lg[SW][144];

    const long rowd0 = (long)s_step * BATCH + b0;

    // ---- P0: load state (transposed) + kappa ----
    for (int i = tid; i < SW * NHID; i += 1024) {
        int s = i / NHID, j = i - s * NHID;
        hbT[j][s] = h_prev[(long)(b0 + s) * NHID + j] * masks_t[b0 + s];
    }
    for (int i = tid; i < SW * KAPN; i += 1024) {
        int s = i / KAPN, j = i - s * KAPN;
        kp[s][j] = Cbuf[(rowd0 + s) * CNP + VN + j];
    }
    __syncthreads();
    // ---- P1: input-attention logits (partial dots over 4x25) ----
    if (tid < 384) {
        int g = tid >> 2, q = tid & 3;      // g = s*24 + (n*4+h)
        int s = g / 24, r = g - s * 24;
        int n = r >> 2, h = r & 3;
        float acc = 0.f;
        int w0 = q * 25;
        for (int w = w0; w < w0 + 25; w++) acc += hbT[n * BS + w][s] * kp[s][h * BS + w];
        part[tid] = acc;
    }
    __syncthreads();
    if (tid < 96) {
        int s = tid / 24, r = tid - s * 24;
        float l = part[tid * 4] + part[tid * 4 + 1] + part[tid * 4 + 2] + part[tid * 4 + 3];
        att[s][r] = sigf(l * 0.125f);        // softmax([l,0])[0] == sigmoid(l)
    }
    __syncthreads();
    // top-k mask: one thread per sample (consumed only in P5; barriers in between)
    if (tid < SW) {
        float a[NBK], av[NBK];
        for (int n = 0; n < NBK; n++) {
            av[n] = 0.25f * (att[tid][n * 4] + att[tid][n * 4 + 1] + att[tid][n * 4 + 2] + att[tid][n * 4 + 3]);
            a[n] = av[n];
        }
        for (int i = 0; i < 4; i++) {
            int mx = i;
            for (int j = i + 1; j < NBK; j++) if (a[j] > a[mx]) mx = j;
            float t = a[i]; a[i] = a[mx]; a[mx] = t;
        }
        float kth = a[3];
        for (int n = 0; n < NBK; n++) mk[tid][n] = (av[n] >= kth) ? 1.f : 0.f;
    }

    // ---- P2: GRU — gi (U gather, att-weighted) + gh (direct-L2 W_hh) + pointwise ----
    if (tid < 600) {
        const int n2 = tid / 100, w2 = tid - n2 * 100;
        float gi[3][SW], gh[3][SW];
#pragma unroll
        for (int g = 0; g < 3; g++) {
            float bi = b_ih[n2 * G3 + g * BS + w2];
            float bh = b_hh[n2 * G3 + g * BS + w2];
#pragma unroll
            for (int s = 0; s < SW; s++) { gi[g][s] = bi; gh[g][s] = bh; }
        }
#pragma unroll
        for (int h = 0; h < HH; h++) {
            const float* Uh = U + ((long)(h * NBK + n2) * MU + rowd0) * G3;
#pragma unroll
            for (int s = 0; s < SW; s++) {
                float a = att[s][n2 * 4 + h];
#pragma unroll
                for (int g = 0; g < 3; g++)
                    gi[g][s] += a * Uh[(long)s * G3 + g * BS + w2];
            }
        }
        const float* Wn = W_hh + (long)n2 * BS * G3;
#pragma unroll 4
        for (int d = 0; d < BS; d++) {
            float w0v = Wn[d * G3 + w2];
            float w1v = Wn[d * G3 + BS + w2];
            float w2v = Wn[d * G3 + 2 * BS + w2];
            f32x4 hv = *(const f32x4*)&hbT[n2 * BS + d][0];
#pragma unroll
            for (int s = 0; s < SW; s++) {
                gh[0][s] += w0v * hv[s];
                gh[1][s] += w1v * hv[s];
                gh[2][s] += w2v * hv[s];
            }
        }
        f32x4 hnv;
#pragma unroll
        for (int s = 0; s < SW; s++) {
            float rr = sigf(gi[0][s] + gh[0][s]);
            float zz = sigf(gi[1][s] + gh[1][s]);
            float ng = tanhf(gi[2][s] + rr * gh[2][s]);
            hnv[s] = (1.f - zz) * ng + zz * hbT[n2 * BS + w2][s];
        }
        *(f32x4*)&hnT[n2 * BS + w2][0] = hnv;
    }
    __syncthreads();

    // ---- P3: comm projections (direct-L2 Wq/k/v_c; thread = (mat, ng, c)) ----
    if (tid < 768) {
        const int mat = tid >> 8, r = tid & 255, ng = r >> 7, c = r & 127;
        const float* W = (mat == 0) ? Wq_c : ((mat == 1) ? Wk_c : Wv_c);
        float acc[3][SW];
#pragma unroll
        for (int j = 0; j < 3; j++)
#pragma unroll
            for (int s = 0; s < SW; s++) acc[j][s] = 0.f;
#pragma unroll 4
        for (int d = 0; d < BS; d++) {
            float wv = W[d * 128 + c];
#pragma unroll
            for (int j = 0; j < 3; j++) {
                f32x4 hv = *(const f32x4*)&hnT[(ng * 3 + j) * BS + d][0];
#pragma unroll
                for (int s = 0; s < SW; s++) acc[j][s] += wv * hv[s];
            }
        }
        float (*dst)[768] = (mat == 0) ? qcb : ((mat == 1) ? kcb : vcb);
#pragma unroll
        for (int j = 0; j < 3; j++)
#pragma unroll
            for (int s = 0; s < SW; s++)
                dst[s][(ng * 3 + j) * 128 + c] = acc[j][s];
    }
    __syncthreads();

    // ---- P4: comm attention logits + softmax + co ----
    if (tid < SW * 144) {
        int s = tid / 144, r = tid - s * 144;
        int h = r / 36, r2 = r - h * 36, n = r2 / NBK, m = r2 - n * NBK;
        float sv = 0.f;
#pragma unroll
        for (int e4 = 0; e4 < 8; e4++) {
            f32x4 qv = *(const f32x4*)&qcb[s][n * 128 + h * 32 + e4 * 4];
            f32x4 kv = *(const f32x4*)&kcb[s][m * 128 + h * 32 + e4 * 4];
            sv += qv[0] * kv[0] + qv[1] * kv[1] + qv[2] * kv[2] + qv[3] * kv[3];
        }
        lg[s][r] = sv * 0.17677669529663687f;
    }
    __syncthreads();
    if (tid < SW * 24) {
        int s = tid / 24, r = tid - s * 24;
        float* row = &lg[s][r * NBK];
        float mx = row[0];
        for (int m = 1; m < NBK; m++) mx = fmaxf(mx, row[m]);
        float sv = 0.f;
        for (int m = 0; m < NBK; m++) { row[m] = expf(row[m] - mx); sv += row[m]; }
        float inv = 1.f / sv;
        for (int m = 0; m < NBK; m++) row[m] *= inv;
    }
    __syncthreads();
    for (int idx = tid; idx < SW * 768; idx += 1024) {
        int s = idx / 768, r = idx - s * 768;
        int n = r >> 7, d = r & 127, h = d >> 5;
        float a = 0.f;
#pragma unroll
        for (int m = 0; m < NBK; m++) a += lg[s][h * 36 + n * NBK + m] * vcb[s][m * 128 + d];
        coT[r][s] = a;
    }
    __syncthreads();

    // ---- P5: co @ Wo_c (direct-L2) + masked select ----
    if (tid < 600) {
        const int n2 = tid / 100, w2 = tid - n2 * 100;
        float acc5[SW];
#pragma unroll
        for (int s = 0; s < SW; s++) acc5[s] = 0.f;
#pragma unroll 4
        for (int d = 0; d < 128; d++) {
            float wv = Wo_c[d * BS + w2];
            f32x4 cv = *(const f32x4*)&coT[n2 * 128 + d][0];
#pragma unroll
            for (int s = 0; s < SW; s++) acc5[s] += wv * cv[s];
        }
        f32x4 res;
#pragma unroll
        for (int s = 0; s < SW; s++) {
            float hc = hnT[n2 * BS + w2][s] + acc5[s];
            res[s] = (mk[s][n2] > 0.5f) ? hc : hbT[n2 * BS + w2][s];
        }
        *(f32x4*)&hbT[n2 * BS + w2][0] = res;    // reuse hbT as output staging
    }
    __syncthreads();
    // ---- P6: coalesced global writes ----
    for (int i = tid; i < SW * NHID; i += 1024) {
        int s = i / NHID, j = i - s * NHID;
        h_out[(long)(b0 + s) * NHID + j] = hbT[j][s];
    }
    for (int i = tid; i < SW * DECKP; i += 1024) {
        int s = i / DECKP, col = i - s * DECKP;
        A_dec[(rowd0 + s) * DECKP + col] = f2b(col < NHID ? hbT[col][s] : 0.f);
    }
}

// ===== host launch =====
extern "C" void kernel_launch(void* const* d_in, const int* in_sizes, int n_in,
                              void* d_out, int out_size, void* d_ws, size_t ws_size,
                              hipStream_t stream)
{
    const float* input = (const float*)d_in[0];
    const float* h0    = (const float*)d_in[1];
    const float* masks = (const float*)d_in[2];
    const float* enc_W = (const float*)d_in[3];
    const float* enc_b = (const float*)d_in[4];
    const float* Wq_in = (const float*)d_in[5];
    const float* Wk_in = (const float*)d_in[6];
    const float* Wv_in = (const float*)d_in[7];
    const float* W_ih  = (const float*)d_in[8];
    const float* W_hh  = (const float*)d_in[9];
    const float* b_ih  = (const float*)d_in[10];
    const float* b_hh  = (const float*)d_in[11];
    const float* Wq_c  = (const float*)d_in[12];
    const float* Wk_c  = (const float*)d_in[13];
    const float* Wv_c  = (const float*)d_in[14];
    const float* Wo_c  = (const float*)d_in[15];
    const float* dec_W = (const float*)d_in[16];
    const float* dec_b = (const float*)d_in[17];
    float* out = (float*)d_out;

    const size_t AL = 256;
    auto pad = [&](size_t x) { return (x + AL - 1) & ~(AL - 1); };
    size_t fixedB = pad((size_t)NTOK * CNP * 4)
                  + pad((size_t)NTOK * 256 * 4)
                  + pad((size_t)HH * DK * BS * 4)
                  + pad((size_t)256 * 4)
                  + pad((size_t)CNP * 4)
                  + pad((size_t)CNP * 3 * KV0 * 2)
                  + pad((size_t)24 * UNP * 3 * UK0 * 2)
                  + pad((size_t)NTOK * DECKP * 2)
                  + 2 * pad((size_t)BATCH * NHID * 4);
    auto perC = [&](int C) {
        size_t MU = (size_t)C * BATCH;
        return pad(MU * 3 * KV0 * 2)
             + pad(MU * CNP * 4)
             + pad((size_t)HH * MU * 3 * UK0 * 2)
             + pad((size_t)24 * MU * G3 * 4)
             + pad(MU * DECKP * 2);
    };
    int C = 8;
    while (C > 1 && fixedB + perC(C) > ws_size) C >>= 1;
    const int MU = C * BATCH;
    const int NCH = T_STEPS / C;

    char* p = (char*)d_ws;
    auto alloc = [&](size_t bytes) { char* r = p; p += pad(bytes); return r; };
    float*          EWfull = (float*)alloc((size_t)NTOK * CNP * 4);
    float*          EWk    = (float*)alloc((size_t)NTOK * 256 * 4);
    float*          WqT    = (float*)alloc((size_t)HH * DK * BS * 4);
    float*          kbf    = (float*)alloc((size_t)256 * 4);
    float*          bias_c = (float*)alloc((size_t)CNP * 4);
    unsigned short* B_vkap = (unsigned short*)alloc((size_t)CNP * 3 * KV0 * 2);
    unsigned short* B_U    = (unsigned short*)alloc((size_t)24 * UNP * 3 * UK0 * 2);
    unsigned short* B_dec  = (unsigned short*)alloc((size_t)NTOK * DECKP * 2);
    float*          hA     = (float*)alloc((size_t)BATCH * NHID * 4);
    float*          hB     = (float*)alloc((size_t)BATCH * NHID * 4);
    unsigned short* A_in   = (unsigned short*)alloc((size_t)MU * 3 * KV0 * 2);
    float*          Cbuf   = (float*)alloc((size_t)MU * CNP * 4);
    unsigned short* A_U    = (unsigned short*)alloc((size_t)HH * MU * 3 * UK0 * 2);
    float*          Ubuf   = (float*)alloc((size_t)24 * MU * G3 * 4);
    unsigned short* A_dec  = (unsigned short*)alloc((size_t)MU * DECKP * 2);

    dim3 blk(256);
    ZOff z0 = {1, 0, 0};

    // ---- setup ----
    sgemm<<<dim3(6, 4, 1), blk, 0, stream>>>(
        enc_W, z0, NINP, Wv_in, z0, HH * DV, EWfull, z0, CNP, NTOK, VN, NINP);
    sgemm<<<dim3(4, 4, 1), blk, 0, stream>>>(
        enc_W, z0, NINP, Wk_in, z0, HH * DK, EWk, z0, 256, NTOK, HH * DK, NINP);
    prep_wqt<<<dim3((HH * DK * BS + 255) / 256), blk, 0, stream>>>(Wq_in, WqT);
    sgemm<<<dim3(2, 4, HH), blk, 0, stream>>>(
        EWk, ZOff{1, DK, 0}, 256, WqT, ZOff{1, (long)DK * BS, 0}, BS,
        EWfull + VN, ZOff{1, BS, 0}, CNP, NTOK, BS, DK);
    bias_k<<<dim3(1), blk, 0, stream>>>(enc_b, Wk_in, kbf);
    bias_c_kernel<<<dim3(3), blk, 0, stream>>>(enc_b, Wv_in, kbf, WqT, bias_c);
    cvt_split_ew<<<dim3((CNP * NTOK + 255) / 256), blk, 0, stream>>>(EWfull, B_vkap);
    cvt_split_bu<<<dim3((24 * UNP * UK0 + 255) / 256), blk, 0, stream>>>(W_ih, B_U);
    cvt_dec<<<dim3((NTOK * DECKP + 255) / 256), blk, 0, stream>>>(dec_W, B_dec);

    const float* hp = h0;
    float* hbufs[2] = { hA, hB };
    int t = 0;
    for (int c = 0; c < NCH; c++) {
        cvt_split_in<<<dim3(2048), blk, 0, stream>>>(
            input + (size_t)c * MU * NTOK, A_in, MU);
        gemm6<<<dim3(CNP / 128, MU / 128, 1), blk, 0, stream>>>(
            A_in, 0, 1, B_vkap, 0, Cbuf, 0, CNP, CN, bias_c, KV0);
        cvt_split_vu<<<dim3(2048), blk, 0, stream>>>(Cbuf, A_U, MU);
        gemm6<<<dim3(UNP / 128, MU / 128, 24), blk, 0, stream>>>(
            A_U, (long)MU * 3 * UK0, NBK, B_U, (long)UNP * 3 * UK0,
            Ubuf, (long)MU * G3, G3, G3, nullptr, UK0);
        for (int s = 0; s < C; s++, t++) {
            float* hout = hbufs[t & 1];
            step_fused<<<dim3(BATCH / SW), dim3(1024), 0, stream>>>(
                hp, masks + (size_t)t * BATCH, Cbuf, Ubuf, b_ih, b_hh, W_hh,
                Wq_c, Wk_c, Wv_c, Wo_c, hout, A_dec, s, MU);
            hp = hout;
        }
        gemm_mfma<<<dim3(NTOK / 128, MU / 128, 1), blk, 0, stream>>>(
            A_dec, B_dec, out + (size_t)c * MU * NTOK, NTOK, dec_b, DECKP);
    }
}

// Round 9
// 6596.753 us; speedup vs baseline: 2.9950x; 1.1430x over previous
//
#include <hip/hip_runtime.h>
#include <math.h>

#define T_STEPS 128
#define BATCH   512
#define NTOK    512
#define NINP    512
#define NHID    600
#define NBK     6
#define BS      100
#define HH      4
#define DK      64
#define DV      85
#define ATT     340
#define H2      4
#define DK2     32
#define DV2     32
#define G3      300
#define VN      340
#define KAPN    400
#define CN      740
#define CNP     768
#define UN2     1800     // merged U cols per head (6 blocks x 300)
#define UN2P    1920     // padded to 15*128
#define UK0     128
#define KV0     512
#define DECKP   640
#define SW      2        // samples per step-block -> grid 256 = all CUs

typedef __attribute__((ext_vector_type(8))) short short8;
typedef __attribute__((ext_vector_type(4))) float f32x4;

__device__ __forceinline__ float sigf(float x) { return 1.f / (1.f + expf(-x)); }
__device__ __forceinline__ unsigned short f2b(float f) {
    unsigned u = __float_as_uint(f);
    unsigned r = (u + 0x7fffu + ((u >> 16) & 1u)) >> 16;
    return (unsigned short)r;
}
__device__ __forceinline__ float b2f(unsigned short u) {
    return __uint_as_float(((unsigned)u) << 16);
}
__device__ __forceinline__ void split3(float x, unsigned short& hi,
                                       unsigned short& mid, unsigned short& lo) {
    hi = f2b(x);
    float r1 = x - b2f(hi);
    mid = f2b(r1);
    lo = f2b(r1 - b2f(mid));
}

struct ZOff { int div; long s1; long s2; };
__device__ __forceinline__ long zoff(ZOff z, int bz) {
    return (long)(bz / z.div) * z.s1 + (long)(bz % z.div) * z.s2;
}

// ===== bf16x6 MFMA GEMM: fp32-class C = A@B^T (+bias) via 6 segment passes =====
__global__ __launch_bounds__(256) void gemm6(
    const unsigned short* __restrict__ A, long aZ, int aZdiv,
    const unsigned short* __restrict__ B, long bZ,
    float* __restrict__ C, long cZ, int ldc, int Nreal,
    const float* __restrict__ bias, int K0)
{
    const int z = blockIdx.z;
    A += (long)(z / aZdiv) * aZ;
    B += (long)z * bZ;
    C += (long)z * cZ;
    const int LDA = 3 * K0;
    const int m0 = blockIdx.y * 128, n0 = blockIdx.x * 128;
    __shared__ __align__(16) unsigned short As[128 * 64];
    __shared__ __align__(16) unsigned short Bs[128 * 64];
    const int tid = threadIdx.x;
    const int lane = tid & 63;
    const int wid = tid >> 6;
    const int wr = wid >> 1, wc = wid & 1;

    f32x4 acc[4][4];
#pragma unroll
    for (int m = 0; m < 4; m++)
#pragma unroll
        for (int n = 0; n < 4; n++)
#pragma unroll
            for (int v = 0; v < 4; v++) acc[m][n][v] = 0.f;

    const int segA[6] = {0, 0, 1, 0, 2, 1};
    const int segB[6] = {0, 1, 0, 2, 0, 1};
    for (int p = 0; p < 6; p++) {
        const unsigned short* Ap = A + segA[p] * K0;
        const unsigned short* Bp = B + segB[p] * K0;
        for (int k0 = 0; k0 < K0; k0 += 64) {
            short8 ra[4], rb[4];
#pragma unroll
            for (int q = 0; q < 4; q++) {
                int idx = (q << 8) + tid;
                int r = idx >> 3, ce = (idx & 7) << 3;
                ra[q] = *(const short8*)&Ap[(long)(m0 + r) * LDA + k0 + ce];
                rb[q] = *(const short8*)&Bp[(long)(n0 + r) * LDA + k0 + ce];
            }
            __syncthreads();
#pragma unroll
            for (int q = 0; q < 4; q++) {
                int idx = (q << 8) + tid;
                int r = idx >> 3, ce = (idx & 7) << 3;
                *(short8*)&As[r * 64 + ce] = ra[q];
                *(short8*)&Bs[r * 64 + ce] = rb[q];
            }
            __syncthreads();
#pragma unroll
            for (int kk = 0; kk < 2; kk++) {
                short8 af[4], bfr[4];
#pragma unroll
                for (int m = 0; m < 4; m++)
                    af[m] = *(const short8*)&As[(wr * 64 + m * 16 + (lane & 15)) * 64 + kk * 32 + (lane >> 4) * 8];
#pragma unroll
                for (int n = 0; n < 4; n++)
                    bfr[n] = *(const short8*)&Bs[(wc * 64 + n * 16 + (lane & 15)) * 64 + kk * 32 + (lane >> 4) * 8];
#pragma unroll
                for (int m = 0; m < 4; m++)
#pragma unroll
                    for (int n = 0; n < 4; n++)
                        acc[m][n] = __builtin_amdgcn_mfma_f32_16x16x32_bf16(af[m], bfr[n], acc[m][n], 0, 0, 0);
            }
        }
    }
#pragma unroll
    for (int m = 0; m < 4; m++) {
        int rbase = m0 + wr * 64 + m * 16 + (lane >> 4) * 4;
#pragma unroll
        for (int n = 0; n < 4; n++) {
            int col = n0 + wc * 64 + n * 16 + (lane & 15);
            if (col < Nreal) {
                float bv = bias ? bias[col] : 0.f;
#pragma unroll
                for (int v = 0; v < 4; v++)
                    C[(long)(rbase + v) * ldc + col] = acc[m][n][v] + bv;
            }
        }
    }
}

// ===== plain bf16 MFMA GEMM (decoder only) =====
__global__ __launch_bounds__(256) void gemm_mfma(
    const unsigned short* __restrict__ A,
    const unsigned short* __restrict__ B,
    float* __restrict__ C, int ldc,
    const float* __restrict__ bias, int Kp)
{
    const int m0 = blockIdx.y * 128, n0 = blockIdx.x * 128;
    __shared__ __align__(16) unsigned short As[128 * 64];
    __shared__ __align__(16) unsigned short Bs[128 * 64];
    const int tid = threadIdx.x;
    const int lane = tid & 63;
    const int wid = tid >> 6;
    const int wr = wid >> 1, wc = wid & 1;

    f32x4 acc[4][4];
#pragma unroll
    for (int m = 0; m < 4; m++)
#pragma unroll
        for (int n = 0; n < 4; n++)
#pragma unroll
            for (int v = 0; v < 4; v++) acc[m][n][v] = 0.f;

    for (int k0 = 0; k0 < Kp; k0 += 64) {
        short8 ra[4], rb[4];
#pragma unroll
        for (int q = 0; q < 4; q++) {
            int idx = (q << 8) + tid;
            int r = idx >> 3, ce = (idx & 7) << 3;
            ra[q] = *(const short8*)&A[(long)(m0 + r) * Kp + k0 + ce];
            rb[q] = *(const short8*)&B[(long)(n0 + r) * Kp + k0 + ce];
        }
        __syncthreads();
#pragma unroll
        for (int q = 0; q < 4; q++) {
            int idx = (q << 8) + tid;
            int r = idx >> 3, ce = (idx & 7) << 3;
            *(short8*)&As[r * 64 + ce] = ra[q];
            *(short8*)&Bs[r * 64 + ce] = rb[q];
        }
        __syncthreads();
#pragma unroll
        for (int kk = 0; kk < 2; kk++) {
            short8 af[4], bfr[4];
#pragma unroll
            for (int m = 0; m < 4; m++)
                af[m] = *(const short8*)&As[(wr * 64 + m * 16 + (lane & 15)) * 64 + kk * 32 + (lane >> 4) * 8];
#pragma unroll
            for (int n = 0; n < 4; n++)
                bfr[n] = *(const short8*)&Bs[(wc * 64 + n * 16 + (lane & 15)) * 64 + kk * 32 + (lane >> 4) * 8];
#pragma unroll
            for (int m = 0; m < 4; m++)
#pragma unroll
                for (int n = 0; n < 4; n++)
                    acc[m][n] = __builtin_amdgcn_mfma_f32_16x16x32_bf16(af[m], bfr[n], acc[m][n], 0, 0, 0);
        }
    }
#pragma unroll
    for (int m = 0; m < 4; m++) {
        int rbase = m0 + wr * 64 + m * 16 + (lane >> 4) * 4;
#pragma unroll
        for (int n = 0; n < 4; n++) {
            int col = n0 + wc * 64 + n * 16 + (lane & 15);
            float bv = bias ? bias[col] : 0.f;
#pragma unroll
            for (int v = 0; v < 4; v++)
                C[(long)(rbase + v) * ldc + col] = acc[m][n][v] + bv;
        }
    }
}

// ===== fp32 SGEMM (setup-only small jobs) =====
__global__ __launch_bounds__(256) void sgemm(
    const float* __restrict__ A, ZOff za, int lda,
    const float* __restrict__ B, ZOff zb, int ldb,
    float* __restrict__ C, ZOff zc, int ldc,
    int M, int N, int K)
{
    const int bz = blockIdx.z;
    A += zoff(za, bz);
    B += zoff(zb, bz);
    C += zoff(zc, bz);
    const int m0 = blockIdx.y * 128, n0 = blockIdx.x * 64;
    __shared__ float As[16][132];
    __shared__ float Bs[16][68];
    const int tid = threadIdx.x;
    const int tm = tid >> 4, tn = tid & 15;
    const int ar = tid >> 1, ak = (tid & 1) * 8;
    const int bk = tid >> 4, bn = (tid & 15) * 4;

    float acc[8][4];
#pragma unroll
    for (int i = 0; i < 8; i++)
#pragma unroll
        for (int j = 0; j < 4; j++) acc[i][j] = 0.f;

    for (int k0 = 0; k0 < K; k0 += 16) {
        float av[8], bv[4];
#pragma unroll
        for (int j = 0; j < 8; j++) {
            int gk = k0 + ak + j;
            av[j] = (gk < K) ? A[(long)(m0 + ar) * lda + gk] : 0.f;
        }
#pragma unroll
        for (int j = 0; j < 4; j++) {
            int gk = k0 + bk, gn = n0 + bn + j;
            bv[j] = (gk < K && gn < N) ? B[(long)gk * ldb + gn] : 0.f;
        }
        __syncthreads();
#pragma unroll
        for (int j = 0; j < 8; j++) As[ak + j][ar] = av[j];
#pragma unroll
        for (int j = 0; j < 4; j++) Bs[bk][bn + j] = bv[j];
        __syncthreads();
#pragma unroll
        for (int kk = 0; kk < 16; kk++) {
            float a[8], b[4];
#pragma unroll
            for (int i = 0; i < 8; i++) a[i] = As[kk][tm * 8 + i];
#pragma unroll
            for (int j = 0; j < 4; j++) b[j] = Bs[kk][tn * 4 + j];
#pragma unroll
            for (int i = 0; i < 8; i++)
#pragma unroll
                for (int j = 0; j < 4; j++)
                    acc[i][j] += a[i] * b[j];
        }
    }
#pragma unroll
    for (int i = 0; i < 8; i++) {
        int gm = m0 + tm * 8 + i;
#pragma unroll
        for (int j = 0; j < 4; j++) {
            int gn = n0 + tn * 4 + j;
            if (gn < N) C[(long)gm * ldc + gn] = acc[i][j];
        }
    }
}

// ===== prep kernels =====
__global__ __launch_bounds__(256) void prep_wqt(const float* __restrict__ Wq_in,
                                                float* __restrict__ WqT)
{
    int idx = blockIdx.x * 256 + threadIdx.x;
    if (idx >= HH * DK * BS) return;
    int h = idx / (DK * BS), r = idx - h * DK * BS, d = r / BS, w = r - d * BS;
    WqT[idx] = Wq_in[w * (HH * DK) + h * DK + d];
}

__global__ __launch_bounds__(256) void bias_k(const float* __restrict__ enc_b,
                                              const float* __restrict__ Wk,
                                              float* __restrict__ kbf)
{
    int j = threadIdx.x;
    if (j >= HH * DK) return;
    float acc = 0.f;
    for (int d = 0; d < NINP; d++) acc += enc_b[d] * Wk[d * (HH * DK) + j];
    kbf[j] = acc;
}

__global__ __launch_bounds__(256) void bias_c_kernel(const float* __restrict__ enc_b,
                                                     const float* __restrict__ Wv,
                                                     const float* __restrict__ kbf,
                                                     const float* __restrict__ WqT,
                                                     float* __restrict__ bias_c)
{
    int j = blockIdx.x * 256 + threadIdx.x;
    if (j >= CNP) return;
    float acc = 0.f;
    if (j < VN) {
        for (int d = 0; d < NINP; d++) acc += enc_b[d] * Wv[d * (HH * DV) + j];
    } else if (j < CN) {
        int r = j - VN;
        int h = r / BS, w = r - h * BS;
        for (int d = 0; d < DK; d++)
            acc += kbf[h * DK + d] * WqT[(h * DK + d) * BS + w];
    }
    bias_c[j] = acc;
}

__global__ __launch_bounds__(256) void cvt_dec(const float* __restrict__ dec_W,
                                               unsigned short* __restrict__ dst)
{
    int idx = blockIdx.x * 256 + threadIdx.x;
    if (idx >= NTOK * DECKP) return;
    int n = idx / DECKP, k = idx - n * DECKP;
    dst[idx] = f2b(k < NHID ? dec_W[k * NTOK + n] : 0.f);
}

__global__ __launch_bounds__(256) void cvt_split_ew(const float* __restrict__ EWfull,
                                                    unsigned short* __restrict__ dst)
{
    int idx = blockIdx.x * 256 + threadIdx.x;
    if (idx >= CNP * NTOK) return;
    int n = idx / NTOK, k = idx - n * NTOK;
    float x = (n < CN) ? EWfull[(long)k * CNP + n] : 0.f;
    unsigned short hi, mid, lo;
    split3(x, hi, mid, lo);
    long base = (long)n * (3 * KV0) + k;
    dst[base] = hi;
    dst[base + KV0] = mid;
    dst[base + 2 * KV0] = lo;
}

// W_ih -> B_U2: [4][1920][3*128]; col j = n*300 + e
__global__ __launch_bounds__(256) void cvt_split_bu2(const float* __restrict__ W_ih,
                                                     unsigned short* __restrict__ dst)
{
    int idx = blockIdx.x * 256 + threadIdx.x;
    if (idx >= HH * UN2P * UK0) return;
    int h = idx / (UN2P * UK0), r = idx - h * (UN2P * UK0);
    int j = r / UK0, kk = r - j * UK0;
    float x = 0.f;
    if (kk < DV && j < UN2) {
        int n = j / G3, e = j - n * G3;
        x = W_ih[((long)n * ATT + h * DV + kk) * G3 + e];
    }
    unsigned short hi, mid, lo;
    split3(x, hi, mid, lo);
    long base = ((long)h * UN2P + j) * (3 * UK0) + kk;
    dst[base] = hi;
    dst[base + UK0] = mid;
    dst[base + 2 * UK0] = lo;
}

__global__ __launch_bounds__(256) void cvt_split_in(const float* __restrict__ src,
                                                    unsigned short* __restrict__ dst, long rows)
{
    long total = rows * NTOK;
    long i = (long)blockIdx.x * 256 + threadIdx.x;
    long stride = (long)gridDim.x * 256;
    for (; i < total; i += stride) {
        long row = i / NTOK; int k = (int)(i - row * NTOK);
        unsigned short hi, mid, lo;
        split3(src[i], hi, mid, lo);
        long base = row * (3 * KV0) + k;
        dst[base] = hi;
        dst[base + KV0] = mid;
        dst[base + 2 * KV0] = lo;
    }
}

__global__ __launch_bounds__(256) void cvt_split_vu(const float* __restrict__ Cbuf,
                                                    unsigned short* __restrict__ dst, int MU)
{
    long total = (long)HH * MU * UK0;
    long i = (long)blockIdx.x * 256 + threadIdx.x;
    long stride = (long)gridDim.x * 256;
    for (; i < total; i += stride) {
        int h = (int)(i / ((long)MU * UK0));
        long r = i - (long)h * MU * UK0;
        long row = r / UK0; int kk = (int)(r - row * UK0);
        float x = (kk < DV) ? Cbuf[row * CNP + h * DV + kk] : 0.f;
        unsigned short hi, mid, lo;
        split3(x, hi, mid, lo);
        long base = ((long)h * MU + row) * (3 * UK0) + kk;
        dst[base] = hi;
        dst[base + UK0] = mid;
        dst[base + 2 * UK0] = lo;
    }
}

// ===== step kernel v5: 1024 threads, SW=2 -> grid 256 (all CUs), direct-L2 weights =====
__global__ __launch_bounds__(1024) void step_fused(
    const float* __restrict__ h_prev,       // [512,600]
    const float* __restrict__ masks_t,      // [512]
    const float* __restrict__ Cbuf,         // [MU,768]
    const float* __restrict__ U,            // [4,MU,1800]
    const float* __restrict__ b_ih, const float* __restrict__ b_hh,
    const float* __restrict__ W_hh,         // [6,100,300]
    const float* __restrict__ Wq_c, const float* __restrict__ Wk_c,
    const float* __restrict__ Wv_c, const float* __restrict__ Wo_c,
    float* __restrict__ h_out,              // [512,600]
    unsigned short* __restrict__ A_dec,     // [MU,640] bf16
    int s_step, int MU)
{
    const int b0 = blockIdx.x * SW, tid = threadIdx.x;
    __shared__ __align__(16) float hbT[NHID][SW];
    __shared__ __align__(16) float hnT[NHID][SW];
    __shared__ __align__(16) float kp[SW][KAPN];
    __shared__ __align__(16) float qcb[SW][768], kcb[SW][768], vcb[SW][768];
    __shared__ __align__(16) float coT[NBK * 128][SW];
    __shared__ float part[SW * 96];
    __shared__ float att[SW][24], mk[SW][NBK];
    __shared__ float lg[SW][144];

    const long rowd0 = (long)s_step * BATCH + b0;

    // ---- P0: load state (transposed) + kappa ----
    for (int i = tid; i < SW * NHID; i += 1024) {
        int s = i / NHID, j = i - s * NHID;
        hbT[j][s] = h_prev[(long)(b0 + s) * NHID + j] * masks_t[b0 + s];
    }
    for (int i = tid; i < SW * KAPN; i += 1024) {
        int s = i / KAPN, j = i - s * KAPN;
        kp[s][j] = Cbuf[(rowd0 + s) * CNP + VN + j];
    }
    __syncthreads();
    // ---- P1: input-attention logits (partial dots over 4x25) ----
    if (tid < SW * 96) {
        int g = tid >> 2, q = tid & 3;      // g = s*24 + (n*4+h)
        int s = g / 24, r = g - s * 24;
        int n = r >> 2, h = r & 3;
        float acc = 0.f;
        int w0 = q * 25;
        for (int w = w0; w < w0 + 25; w++) acc += hbT[n * BS + w][s] * kp[s][h * BS + w];
        part[tid] = acc;
    }
    __syncthreads();
    if (tid < SW * 24) {
        int s = tid / 24, r = tid - s * 24;
        float l = part[tid * 4] + part[tid * 4 + 1] + part[tid * 4 + 2] + part[tid * 4 + 3];
        att[s][r] = sigf(l * 0.125f);        // softmax([l,0])[0] == sigmoid(l)
    }
    __syncthreads();
    // top-k mask: one thread per sample (mk consumed in P5; barriers in between)
    if (tid < SW) {
        float a[NBK], av[NBK];
        for (int n = 0; n < NBK; n++) {
            av[n] = 0.25f * (att[tid][n * 4] + att[tid][n * 4 + 1] + att[tid][n * 4 + 2] + att[tid][n * 4 + 3]);
            a[n] = av[n];
        }
        for (int i = 0; i < 4; i++) {
            int mx = i;
            for (int j = i + 1; j < NBK; j++) if (a[j] > a[mx]) mx = j;
            float t = a[i]; a[i] = a[mx]; a[mx] = t;
        }
        float kth = a[3];
        for (int n = 0; n < NBK; n++) mk[tid][n] = (av[n] >= kth) ? 1.f : 0.f;
    }

    // ---- P2: GRU — gi (U gather, att-weighted) + gh (direct-L2 W_hh) + pointwise ----
    if (tid < 600) {
        const int n2 = tid / 100, w2 = tid - n2 * 100;
        float gi[3][SW], gh[3][SW];
#pragma unroll
        for (int g = 0; g < 3; g++) {
            float bi = b_ih[n2 * G3 + g * BS + w2];
            float bh = b_hh[n2 * G3 + g * BS + w2];
#pragma unroll
            for (int s = 0; s < SW; s++) { gi[g][s] = bi; gh[g][s] = bh; }
        }
#pragma unroll
        for (int h = 0; h < HH; h++) {
            const float* Uh = U + ((long)h * MU + rowd0) * UN2 + n2 * G3;
#pragma unroll
            for (int s = 0; s < SW; s++) {
                float a = att[s][n2 * 4 + h];
#pragma unroll
                for (int g = 0; g < 3; g++)
                    gi[g][s] += a * Uh[(long)s * UN2 + g * BS + w2];
            }
        }
        const float* Wn = W_hh + (long)n2 * BS * G3;
#pragma unroll 4
        for (int d = 0; d < BS; d++) {
            float w0v = Wn[d * G3 + w2];
            float w1v = Wn[d * G3 + BS + w2];
            float w2v = Wn[d * G3 + 2 * BS + w2];
            float2 hv = *(const float2*)&hbT[n2 * BS + d][0];
            gh[0][0] += w0v * hv.x; gh[0][1] += w0v * hv.y;
            gh[1][0] += w1v * hv.x; gh[1][1] += w1v * hv.y;
            gh[2][0] += w2v * hv.x; gh[2][1] += w2v * hv.y;
        }
        float2 hnv;
        {
            float rr0 = sigf(gi[0][0] + gh[0][0]);
            float zz0 = sigf(gi[1][0] + gh[1][0]);
            float ng0 = tanhf(gi[2][0] + rr0 * gh[2][0]);
            hnv.x = (1.f - zz0) * ng0 + zz0 * hbT[n2 * BS + w2][0];
            float rr1 = sigf(gi[0][1] + gh[0][1]);
            float zz1 = sigf(gi[1][1] + gh[1][1]);
            float ng1 = tanhf(gi[2][1] + rr1 * gh[2][1]);
            hnv.y = (1.f - zz1) * ng1 + zz1 * hbT[n2 * BS + w2][1];
        }
        *(float2*)&hnT[n2 * BS + w2][0] = hnv;
    }
    __syncthreads();

    // ---- P3: comm projections (direct-L2 Wq/k/v_c; thread = (mat, ng, c)) ----
    if (tid < 768) {
        const int mat = tid >> 8, r = tid & 255, ng = r >> 7, c = r & 127;
        const float* W = (mat == 0) ? Wq_c : ((mat == 1) ? Wk_c : Wv_c);
        float acc[3][SW];
#pragma unroll
        for (int j = 0; j < 3; j++)
#pragma unroll
            for (int s = 0; s < SW; s++) acc[j][s] = 0.f;
#pragma unroll 4
        for (int d = 0; d < BS; d++) {
            float wv = W[d * 128 + c];
#pragma unroll
            for (int j = 0; j < 3; j++) {
                float2 hv = *(const float2*)&hnT[(ng * 3 + j) * BS + d][0];
                acc[j][0] += wv * hv.x;
                acc[j][1] += wv * hv.y;
            }
        }
        float (*dst)[768] = (mat == 0) ? qcb : ((mat == 1) ? kcb : vcb);
#pragma unroll
        for (int j = 0; j < 3; j++)
#pragma unroll
            for (int s = 0; s < SW; s++)
                dst[s][(ng * 3 + j) * 128 + c] = acc[j][s];
    }
    __syncthreads();

    // ---- P4: comm attention logits + softmax + co ----
    if (tid < SW * 144) {
        int s = tid / 144, r = tid - s * 144;
        int h = r / 36, r2 = r - h * 36, n = r2 / NBK, m = r2 - n * NBK;
        float sv = 0.f;
#pragma unroll
        for (int e4 = 0; e4 < 8; e4++) {
            f32x4 qv = *(const f32x4*)&qcb[s][n * 128 + h * 32 + e4 * 4];
            f32x4 kv = *(const f32x4*)&kcb[s][m * 128 + h * 32 + e4 * 4];
            sv += qv[0] * kv[0] + qv[1] * kv[1] + qv[2] * kv[2] + qv[3] * kv[3];
        }
        lg[s][r] = sv * 0.17677669529663687f;
    }
    __syncthreads();
    if (tid < SW * 24) {
        int s = tid / 24, r = tid - s * 24;
        float* row = &lg[s][r * NBK];
        float mx = row[0];
        for (int m = 1; m < NBK; m++) mx = fmaxf(mx, row[m]);
        float sv = 0.f;
        for (int m = 0; m < NBK; m++) { row[m] = expf(row[m] - mx); sv += row[m]; }
        float inv = 1.f / sv;
        for (int m = 0; m < NBK; m++) row[m] *= inv;
    }
    __syncthreads();
    for (int idx = tid; idx < SW * 768; idx += 1024) {
        int s = idx / 768, r = idx - s * 768;
        int n = r >> 7, d = r & 127, h = d >> 5;
        float a = 0.f;
#pragma unroll
        for (int m = 0; m < NBK; m++) a += lg[s][h * 36 + n * NBK + m] * vcb[s][m * 128 + d];
        coT[r][s] = a;
    }
    __syncthreads();

    // ---- P5: co @ Wo_c (direct-L2) + masked select ----
    if (tid < 600) {
        const int n2 = tid / 100, w2 = tid - n2 * 100;
        float a0 = 0.f, a1 = 0.f;
#pragma unroll 4
        for (int d = 0; d < 128; d++) {
            float wv = Wo_c[d * BS + w2];
            float2 cv = *(const float2*)&coT[n2 * 128 + d][0];
            a0 += wv * cv.x;
            a1 += wv * cv.y;
        }
        float2 res;
        float hc0 = hnT[n2 * BS + w2][0] + a0;
        float hc1 = hnT[n2 * BS + w2][1] + a1;
        res.x = (mk[0][n2] > 0.5f) ? hc0 : hbT[n2 * BS + w2][0];
        res.y = (mk[1][n2] > 0.5f) ? hc1 : hbT[n2 * BS + w2][1];
        *(float2*)&hbT[n2 * BS + w2][0] = res;   // reuse hbT as output staging
    }
    __syncthreads();
    // ---- P6: coalesced global writes ----
    for (int i = tid; i < SW * NHID; i += 1024) {
        int s = i / NHID, j = i - s * NHID;
        h_out[(long)(b0 + s) * NHID + j] = hbT[j][s];
    }
    for (int i = tid; i < SW * DECKP; i += 1024) {
        int s = i / DECKP, col = i - s * DECKP;
        A_dec[(rowd0 + s) * DECKP + col] = f2b(col < NHID ? hbT[col][s] : 0.f);
    }
}

// ===== host launch =====
extern "C" void kernel_launch(void* const* d_in, const int* in_sizes, int n_in,
                              void* d_out, int out_size, void* d_ws, size_t ws_size,
                              hipStream_t stream)
{
    const float* input = (const float*)d_in[0];
    const float* h0    = (const float*)d_in[1];
    const float* masks = (const float*)d_in[2];
    const float* enc_W = (const float*)d_in[3];
    const float* enc_b = (const float*)d_in[4];
    const float* Wq_in = (const float*)d_in[5];
    const float* Wk_in = (const float*)d_in[6];
    const float* Wv_in = (const float*)d_in[7];
    const float* W_ih  = (const float*)d_in[8];
    const float* W_hh  = (const float*)d_in[9];
    const float* b_ih  = (const float*)d_in[10];
    const float* b_hh  = (const float*)d_in[11];
    const float* Wq_c  = (const float*)d_in[12];
    const float* Wk_c  = (const float*)d_in[13];
    const float* Wv_c  = (const float*)d_in[14];
    const float* Wo_c  = (const float*)d_in[15];
    const float* dec_W = (const float*)d_in[16];
    const float* dec_b = (const float*)d_in[17];
    float* out = (float*)d_out;

    const size_t AL = 256;
    auto pad = [&](size_t x) { return (x + AL - 1) & ~(AL - 1); };
    size_t fixedB = pad((size_t)NTOK * CNP * 4)
                  + pad((size_t)NTOK * 256 * 4)
                  + pad((size_t)HH * DK * BS * 4)
                  + pad((size_t)256 * 4)
                  + pad((size_t)CNP * 4)
                  + pad((size_t)CNP * 3 * KV0 * 2)
                  + pad((size_t)HH * UN2P * 3 * UK0 * 2)
                  + pad((size_t)NTOK * DECKP * 2)
                  + 2 * pad((size_t)BATCH * NHID * 4);
    auto perC = [&](int C) {
        size_t MU = (size_t)C * BATCH;
        return pad(MU * 3 * KV0 * 2)
             + pad(MU * CNP * 4)
             + pad((size_t)HH * MU * 3 * UK0 * 2)
             + pad((size_t)HH * MU * UN2 * 4)
             + pad(MU * DECKP * 2);
    };
    int C = 8;
    while (C > 1 && fixedB + perC(C) > ws_size) C >>= 1;
    const int MU = C * BATCH;
    const int NCH = T_STEPS / C;

    char* p = (char*)d_ws;
    auto alloc = [&](size_t bytes) { char* r = p; p += pad(bytes); return r; };
    float*          EWfull = (float*)alloc((size_t)NTOK * CNP * 4);
    float*          EWk    = (float*)alloc((size_t)NTOK * 256 * 4);
    float*          WqT    = (float*)alloc((size_t)HH * DK * BS * 4);
    float*          kbf    = (float*)alloc((size_t)256 * 4);
    float*          bias_c = (float*)alloc((size_t)CNP * 4);
    unsigned short* B_vkap = (unsigned short*)alloc((size_t)CNP * 3 * KV0 * 2);
    unsigned short* B_U    = (unsigned short*)alloc((size_t)HH * UN2P * 3 * UK0 * 2);
    unsigned short* B_dec  = (unsigned short*)alloc((size_t)NTOK * DECKP * 2);
    float*          hA     = (float*)alloc((size_t)BATCH * NHID * 4);
    float*          hB     = (float*)alloc((size_t)BATCH * NHID * 4);
    unsigned short* A_in   = (unsigned short*)alloc((size_t)MU * 3 * KV0 * 2);
    float*          Cbuf   = (float*)alloc((size_t)MU * CNP * 4);
    unsigned short* A_U    = (unsigned short*)alloc((size_t)HH * MU * 3 * UK0 * 2);
    float*          Ubuf   = (float*)alloc((size_t)HH * MU * UN2 * 4);
    unsigned short* A_dec  = (unsigned short*)alloc((size_t)MU * DECKP * 2);

    dim3 blk(256);
    ZOff z0 = {1, 0, 0};

    // ---- setup ----
    sgemm<<<dim3(6, 4, 1), blk, 0, stream>>>(
        enc_W, z0, NINP, Wv_in, z0, HH * DV, EWfull, z0, CNP, NTOK, VN, NINP);
    sgemm<<<dim3(4, 4, 1), blk, 0, stream>>>(
        enc_W, z0, NINP, Wk_in, z0, HH * DK, EWk, z0, 256, NTOK, HH * DK, NINP);
    prep_wqt<<<dim3((HH * DK * BS + 255) / 256), blk, 0, stream>>>(Wq_in, WqT);
    sgemm<<<dim3(2, 4, HH), blk, 0, stream>>>(
        EWk, ZOff{1, DK, 0}, 256, WqT, ZOff{1, (long)DK * BS, 0}, BS,
        EWfull + VN, ZOff{1, BS, 0}, CNP, NTOK, BS, DK);
    bias_k<<<dim3(1), blk, 0, stream>>>(enc_b, Wk_in, kbf);
    bias_c_kernel<<<dim3(3), blk, 0, stream>>>(enc_b, Wv_in, kbf, WqT, bias_c);
    cvt_split_ew<<<dim3((CNP * NTOK + 255) / 256), blk, 0, stream>>>(EWfull, B_vkap);
    cvt_split_bu2<<<dim3((HH * UN2P * UK0 + 255) / 256), blk, 0, stream>>>(W_ih, B_U);
    cvt_dec<<<dim3((NTOK * DECKP + 255) / 256), blk, 0, stream>>>(dec_W, B_dec);

    const float* hp = h0;
    float* hbufs[2] = { hA, hB };
    int t = 0;
    for (int c = 0; c < NCH; c++) {
        cvt_split_in<<<dim3(2048), blk, 0, stream>>>(
            input + (size_t)c * MU * NTOK, A_in, MU);
        gemm6<<<dim3(CNP / 128, MU / 128, 1), blk, 0, stream>>>(
            A_in, 0, 1, B_vkap, 0, Cbuf, 0, CNP, CN, bias_c, KV0);
        cvt_split_vu<<<dim3(2048), blk, 0, stream>>>(Cbuf, A_U, MU);
        // U: z=h (4 batches), N=1800 merged over n
        gemm6<<<dim3(UN2P / 128, MU / 128, HH), blk, 0, stream>>>(
            A_U, (long)MU * 3 * UK0, 1, B_U, (long)UN2P * 3 * UK0,
            Ubuf, (long)MU * UN2, UN2, UN2, nullptr, UK0);
        for (int s = 0; s < C; s++, t++) {
            float* hout = hbufs[t & 1];
            step_fused<<<dim3(BATCH / SW), dim3(1024), 0, stream>>>(
                hp, masks + (size_t)t * BATCH, Cbuf, Ubuf, b_ih, b_hh, W_hh,
                Wq_c, Wk_c, Wv_c, Wo_c, hout, A_dec, s, MU);
            hp = hout;
        }
        gemm_mfma<<<dim3(NTOK / 128, MU / 128, 1), blk, 0, stream>>>(
            A_dec, B_dec, out + (size_t)c * MU * NTOK, NTOK, dec_b, DECKP);
    }
}

// Round 10
// 6536.813 us; speedup vs baseline: 3.0224x; 1.0092x over previous
//
#include <hip/hip_runtime.h>
#include <math.h>

#define T_STEPS 128
#define BATCH   512
#define NTOK    512
#define NINP    512
#define NHID    600
#define NBK     6
#define BS      100
#define HH      4
#define DK      64
#define DV      85
#define ATT     340
#define H2      4
#define DK2     32
#define DV2     32
#define G3      300
#define VN      340
#define KAPN    400
#define CN      740
#define CNP     768
#define UN2     1800     // merged U cols per head (6 blocks x 300)
#define UN2P    1920     // padded to 15*128
#define UK0     128
#define KV0     512
#define DECKP   640
#define SW      2        // samples per step-block -> grid 256 = all CUs

typedef __attribute__((ext_vector_type(8))) short short8;
typedef __attribute__((ext_vector_type(4))) float f32x4;

__device__ __forceinline__ float sigf(float x) { return 1.f / (1.f + expf(-x)); }
__device__ __forceinline__ unsigned short f2b(float f) {
    unsigned u = __float_as_uint(f);
    unsigned r = (u + 0x7fffu + ((u >> 16) & 1u)) >> 16;
    return (unsigned short)r;
}
__device__ __forceinline__ float b2f(unsigned short u) {
    return __uint_as_float(((unsigned)u) << 16);
}
__device__ __forceinline__ void split3(float x, unsigned short& hi,
                                       unsigned short& mid, unsigned short& lo) {
    hi = f2b(x);
    float r1 = x - b2f(hi);
    mid = f2b(r1);
    lo = f2b(r1 - b2f(mid));
}

struct ZOff { int div; long s1; long s2; };
__device__ __forceinline__ long zoff(ZOff z, int bz) {
    return (long)(bz / z.div) * z.s1 + (long)(bz % z.div) * z.s2;
}

// XCD-chunked bijective swizzle + y-fastest decode (requires nwg % 8 == 0).
// Consecutive work within an XCD shares the B tile (x const) and streams A panels.
__device__ __forceinline__ void swz_decode(int& x, int& y, int& z) {
    int gx = gridDim.x, gy = gridDim.y;
    int flat = (blockIdx.z * gy + blockIdx.y) * gx + blockIdx.x;
    int nwg = gx * gy * gridDim.z;
    int per = nwg >> 3;
    int nf = (flat & 7) * per + (flat >> 3);
    y = nf % gy; int t2 = nf / gy; x = t2 % gx; z = t2 / gx;
}

// ===== bf16x6 MFMA GEMM core loop (shared via macro-ish duplication) =====
// A [rows][3*K0] (hi|mid|lo), B^T [Ntiles*128][3*K0]. 6 passes -> fp32-class.
__global__ __launch_bounds__(256) void gemm6(
    const unsigned short* __restrict__ A, long aZ, int aZdiv,
    const unsigned short* __restrict__ B, long bZ,
    float* __restrict__ C, long cZ, int ldc, int Nreal,
    const float* __restrict__ bias, int K0)
{
    int bx, by, bz;
    swz_decode(bx, by, bz);
    A += (long)(bz / aZdiv) * aZ;
    B += (long)bz * bZ;
    C += (long)bz * cZ;
    const int LDA = 3 * K0;
    const int m0 = by * 128, n0 = bx * 128;
    __shared__ __align__(16) unsigned short As[128 * 64];
    __shared__ __align__(16) unsigned short Bs[128 * 64];
    const int tid = threadIdx.x;
    const int lane = tid & 63;
    const int wid = tid >> 6;
    const int wr = wid >> 1, wc = wid & 1;

    f32x4 acc[4][4];
#pragma unroll
    for (int m = 0; m < 4; m++)
#pragma unroll
        for (int n = 0; n < 4; n++)
#pragma unroll
            for (int v = 0; v < 4; v++) acc[m][n][v] = 0.f;

    const int segA[6] = {0, 0, 1, 0, 2, 1};
    const int segB[6] = {0, 1, 0, 2, 0, 1};
    for (int p = 0; p < 6; p++) {
        const unsigned short* Ap = A + segA[p] * K0;
        const unsigned short* Bp = B + segB[p] * K0;
        for (int k0 = 0; k0 < K0; k0 += 64) {
            short8 ra[4], rb[4];
#pragma unroll
            for (int q = 0; q < 4; q++) {
                int idx = (q << 8) + tid;
                int r = idx >> 3, ce = (idx & 7) << 3;
                ra[q] = *(const short8*)&Ap[(long)(m0 + r) * LDA + k0 + ce];
                rb[q] = *(const short8*)&Bp[(long)(n0 + r) * LDA + k0 + ce];
            }
            __syncthreads();
#pragma unroll
            for (int q = 0; q < 4; q++) {
                int idx = (q << 8) + tid;
                int r = idx >> 3, ce = (idx & 7) << 3;
                *(short8*)&As[r * 64 + ce] = ra[q];
                *(short8*)&Bs[r * 64 + ce] = rb[q];
            }
            __syncthreads();
#pragma unroll
            for (int kk = 0; kk < 2; kk++) {
                short8 af[4], bfr[4];
#pragma unroll
                for (int m = 0; m < 4; m++)
                    af[m] = *(const short8*)&As[(wr * 64 + m * 16 + (lane & 15)) * 64 + kk * 32 + (lane >> 4) * 8];
#pragma unroll
                for (int n = 0; n < 4; n++)
                    bfr[n] = *(const short8*)&Bs[(wc * 64 + n * 16 + (lane & 15)) * 64 + kk * 32 + (lane >> 4) * 8];
#pragma unroll
                for (int m = 0; m < 4; m++)
#pragma unroll
                    for (int n = 0; n < 4; n++)
                        acc[m][n] = __builtin_amdgcn_mfma_f32_16x16x32_bf16(af[m], bfr[n], acc[m][n], 0, 0, 0);
            }
        }
    }
#pragma unroll
    for (int m = 0; m < 4; m++) {
        int rbase = m0 + wr * 64 + m * 16 + (lane >> 4) * 4;
#pragma unroll
        for (int n = 0; n < 4; n++) {
            int col = n0 + wc * 64 + n * 16 + (lane & 15);
            if (col < Nreal) {
                float bv = bias ? bias[col] : 0.f;
#pragma unroll
                for (int v = 0; v < 4; v++)
                    C[(long)(rbase + v) * ldc + col] = acc[m][n][v] + bv;
            }
        }
    }
}

// kv-variant: same core, fused epilogue -> A_U splits (v cols) + Kbuf fp32 (kappa cols)
__global__ __launch_bounds__(256) void gemm6_kv(
    const unsigned short* __restrict__ A,
    const unsigned short* __restrict__ B,
    unsigned short* __restrict__ A_U,       // [4][MU][3*UK0]
    float* __restrict__ Kbuf,               // [MU][400]
    const float* __restrict__ bias, int K0, int MU)
{
    int bx, by, bz;
    swz_decode(bx, by, bz);
    const int LDA = 3 * K0;
    const int m0 = by * 128, n0 = bx * 128;
    __shared__ __align__(16) unsigned short As[128 * 64];
    __shared__ __align__(16) unsigned short Bs[128 * 64];
    const int tid = threadIdx.x;
    const int lane = tid & 63;
    const int wid = tid >> 6;
    const int wr = wid >> 1, wc = wid & 1;

    f32x4 acc[4][4];
#pragma unroll
    for (int m = 0; m < 4; m++)
#pragma unroll
        for (int n = 0; n < 4; n++)
#pragma unroll
            for (int v = 0; v < 4; v++) acc[m][n][v] = 0.f;

    const int segA[6] = {0, 0, 1, 0, 2, 1};
    const int segB[6] = {0, 1, 0, 2, 0, 1};
    for (int p = 0; p < 6; p++) {
        const unsigned short* Ap = A + segA[p] * K0;
        const unsigned short* Bp = B + segB[p] * K0;
        for (int k0 = 0; k0 < K0; k0 += 64) {
            short8 ra[4], rb[4];
#pragma unroll
            for (int q = 0; q < 4; q++) {
                int idx = (q << 8) + tid;
                int r = idx >> 3, ce = (idx & 7) << 3;
                ra[q] = *(const short8*)&Ap[(long)(m0 + r) * LDA + k0 + ce];
                rb[q] = *(const short8*)&Bp[(long)(n0 + r) * LDA + k0 + ce];
            }
            __syncthreads();
#pragma unroll
            for (int q = 0; q < 4; q++) {
                int idx = (q << 8) + tid;
                int r = idx >> 3, ce = (idx & 7) << 3;
                *(short8*)&As[r * 64 + ce] = ra[q];
                *(short8*)&Bs[r * 64 + ce] = rb[q];
            }
            __syncthreads();
#pragma unroll
            for (int kk = 0; kk < 2; kk++) {
                short8 af[4], bfr[4];
#pragma unroll
                for (int m = 0; m < 4; m++)
                    af[m] = *(const short8*)&As[(wr * 64 + m * 16 + (lane & 15)) * 64 + kk * 32 + (lane >> 4) * 8];
#pragma unroll
                for (int n = 0; n < 4; n++)
                    bfr[n] = *(const short8*)&Bs[(wc * 64 + n * 16 + (lane & 15)) * 64 + kk * 32 + (lane >> 4) * 8];
#pragma unroll
                for (int m = 0; m < 4; m++)
#pragma unroll
                    for (int n = 0; n < 4; n++)
                        acc[m][n] = __builtin_amdgcn_mfma_f32_16x16x32_bf16(af[m], bfr[n], acc[m][n], 0, 0, 0);
            }
        }
    }
#pragma unroll
    for (int m = 0; m < 4; m++) {
        int rbase = m0 + wr * 64 + m * 16 + (lane >> 4) * 4;
#pragma unroll
        for (int n = 0; n < 4; n++) {
            int col = n0 + wc * 64 + n * 16 + (lane & 15);
            if (col < CN) {
                float bv = bias[col];
                if (col < VN) {
                    int h = col / DV, kk2 = col - h * DV;
#pragma unroll
                    for (int v = 0; v < 4; v++) {
                        float val = acc[m][n][v] + bv;
                        unsigned short hi, mid, lo;
                        split3(val, hi, mid, lo);
                        long base = ((long)h * MU + (rbase + v)) * (3 * UK0) + kk2;
                        A_U[base] = hi;
                        A_U[base + UK0] = mid;
                        A_U[base + 2 * UK0] = lo;
                    }
                } else {
                    int kc = col - VN;
#pragma unroll
                    for (int v = 0; v < 4; v++)
                        Kbuf[(long)(rbase + v) * KAPN + kc] = acc[m][n][v] + bv;
                }
            }
        }
    }
}

// ===== plain bf16 MFMA GEMM (decoder only) =====
__global__ __launch_bounds__(256) void gemm_mfma(
    const unsigned short* __restrict__ A,
    const unsigned short* __restrict__ B,
    float* __restrict__ C, int ldc,
    const float* __restrict__ bias, int Kp)
{
    const int m0 = blockIdx.y * 128, n0 = blockIdx.x * 128;
    __shared__ __align__(16) unsigned short As[128 * 64];
    __shared__ __align__(16) unsigned short Bs[128 * 64];
    const int tid = threadIdx.x;
    const int lane = tid & 63;
    const int wid = tid >> 6;
    const int wr = wid >> 1, wc = wid & 1;

    f32x4 acc[4][4];
#pragma unroll
    for (int m = 0; m < 4; m++)
#pragma unroll
        for (int n = 0; n < 4; n++)
#pragma unroll
            for (int v = 0; v < 4; v++) acc[m][n][v] = 0.f;

    for (int k0 = 0; k0 < Kp; k0 += 64) {
        short8 ra[4], rb[4];
#pragma unroll
        for (int q = 0; q < 4; q++) {
            int idx = (q << 8) + tid;
            int r = idx >> 3, ce = (idx & 7) << 3;
            ra[q] = *(const short8*)&A[(long)(m0 + r) * Kp + k0 + ce];
            rb[q] = *(const short8*)&B[(long)(n0 + r) * Kp + k0 + ce];
        }
        __syncthreads();
#pragma unroll
        for (int q = 0; q < 4; q++) {
            int idx = (q << 8) + tid;
            int r = idx >> 3, ce = (idx & 7) << 3;
            *(short8*)&As[r * 64 + ce] = ra[q];
            *(short8*)&Bs[r * 64 + ce] = rb[q];
        }
        __syncthreads();
#pragma unroll
        for (int kk = 0; kk < 2; kk++) {
            short8 af[4], bfr[4];
#pragma unroll
            for (int m = 0; m < 4; m++)
                af[m] = *(const short8*)&As[(wr * 64 + m * 16 + (lane & 15)) * 64 + kk * 32 + (lane >> 4) * 8];
#pragma unroll
            for (int n = 0; n < 4; n++)
                bfr[n] = *(const short8*)&Bs[(wc * 64 + n * 16 + (lane & 15)) * 64 + kk * 32 + (lane >> 4) * 8];
#pragma unroll
            for (int m = 0; m < 4; m++)
#pragma unroll
                for (int n = 0; n < 4; n++)
                    acc[m][n] = __builtin_amdgcn_mfma_f32_16x16x32_bf16(af[m], bfr[n], acc[m][n], 0, 0, 0);
        }
    }
#pragma unroll
    for (int m = 0; m < 4; m++) {
        int rbase = m0 + wr * 64 + m * 16 + (lane >> 4) * 4;
#pragma unroll
        for (int n = 0; n < 4; n++) {
            int col = n0 + wc * 64 + n * 16 + (lane & 15);
            float bv = bias ? bias[col] : 0.f;
#pragma unroll
            for (int v = 0; v < 4; v++)
                C[(long)(rbase + v) * ldc + col] = acc[m][n][v] + bv;
        }
    }
}

// ===== fp32 SGEMM (setup-only small jobs) =====
__global__ __launch_bounds__(256) void sgemm(
    const float* __restrict__ A, ZOff za, int lda,
    const float* __restrict__ B, ZOff zb, int ldb,
    float* __restrict__ C, ZOff zc, int ldc,
    int M, int N, int K)
{
    const int bz = blockIdx.z;
    A += zoff(za, bz);
    B += zoff(zb, bz);
    C += zoff(zc, bz);
    const int m0 = blockIdx.y * 128, n0 = blockIdx.x * 64;
    __shared__ float As[16][132];
    __shared__ float Bs[16][68];
    const int tid = threadIdx.x;
    const int tm = tid >> 4, tn = tid & 15;
    const int ar = tid >> 1, ak = (tid & 1) * 8;
    const int bk = tid >> 4, bn = (tid & 15) * 4;

    float acc[8][4];
#pragma unroll
    for (int i = 0; i < 8; i++)
#pragma unroll
        for (int j = 0; j < 4; j++) acc[i][j] = 0.f;

    for (int k0 = 0; k0 < K; k0 += 16) {
        float av[8], bv[4];
#pragma unroll
        for (int j = 0; j < 8; j++) {
            int gk = k0 + ak + j;
            av[j] = (gk < K) ? A[(long)(m0 + ar) * lda + gk] : 0.f;
        }
#pragma unroll
        for (int j = 0; j < 4; j++) {
            int gk = k0 + bk, gn = n0 + bn + j;
            bv[j] = (gk < K && gn < N) ? B[(long)gk * ldb + gn] : 0.f;
        }
        __syncthreads();
#pragma unroll
        for (int j = 0; j < 8; j++) As[ak + j][ar] = av[j];
#pragma unroll
        for (int j = 0; j < 4; j++) Bs[bk][bn + j] = bv[j];
        __syncthreads();
#pragma unroll
        for (int kk = 0; kk < 16; kk++) {
            float a[8], b[4];
#pragma unroll
            for (int i = 0; i < 8; i++) a[i] = As[kk][tm * 8 + i];
#pragma unroll
            for (int j = 0; j < 4; j++) b[j] = Bs[kk][tn * 4 + j];
#pragma unroll
            for (int i = 0; i < 8; i++)
#pragma unroll
                for (int j = 0; j < 4; j++)
                    acc[i][j] += a[i] * b[j];
        }
    }
#pragma unroll
    for (int i = 0; i < 8; i++) {
        int gm = m0 + tm * 8 + i;
#pragma unroll
        for (int j = 0; j < 4; j++) {
            int gn = n0 + tn * 4 + j;
            if (gn < N) C[(long)gm * ldc + gn] = acc[i][j];
        }
    }
}

// ===== prep kernels =====
__global__ __launch_bounds__(256) void prep_wqt(const float* __restrict__ Wq_in,
                                                float* __restrict__ WqT)
{
    int idx = blockIdx.x * 256 + threadIdx.x;
    if (idx >= HH * DK * BS) return;
    int h = idx / (DK * BS), r = idx - h * DK * BS, d = r / BS, w = r - d * BS;
    WqT[idx] = Wq_in[w * (HH * DK) + h * DK + d];
}

// W_hh[n][d][g*100+w] -> Whh4[n][d][w][4] (g in lanes 0..2)
__global__ __launch_bounds__(256) void prep_whh4(const float* __restrict__ W_hh,
                                                 float* __restrict__ Whh4)
{
    int idx = blockIdx.x * 256 + threadIdx.x;
    if (idx >= NBK * BS * G3) return;
    int n = idx / (BS * G3), r = idx - n * (BS * G3);
    int d = r / G3, e = r - d * G3;
    int g = e / BS, w = e - g * BS;
    Whh4[(((long)n * BS + d) * BS + w) * 4 + g] = W_hh[idx];
}

__global__ __launch_bounds__(256) void bias_k(const float* __restrict__ enc_b,
                                              const float* __restrict__ Wk,
                                              float* __restrict__ kbf)
{
    int j = threadIdx.x;
    if (j >= HH * DK) return;
    float acc = 0.f;
    for (int d = 0; d < NINP; d++) acc += enc_b[d] * Wk[d * (HH * DK) + j];
    kbf[j] = acc;
}

__global__ __launch_bounds__(256) void bias_c_kernel(const float* __restrict__ enc_b,
                                                     const float* __restrict__ Wv,
                                                     const float* __restrict__ kbf,
                                                     const float* __restrict__ WqT,
                                                     float* __restrict__ bias_c)
{
    int j = blockIdx.x * 256 + threadIdx.x;
    if (j >= CNP) return;
    float acc = 0.f;
    if (j < VN) {
        for (int d = 0; d < NINP; d++) acc += enc_b[d] * Wv[d * (HH * DV) + j];
    } else if (j < CN) {
        int r = j - VN;
        int h = r / BS, w = r - h * BS;
        for (int d = 0; d < DK; d++)
            acc += kbf[h * DK + d] * WqT[(h * DK + d) * BS + w];
    }
    bias_c[j] = acc;
}

__global__ __launch_bounds__(256) void cvt_dec(const float* __restrict__ dec_W,
                                               unsigned short* __restrict__ dst)
{
    int idx = blockIdx.x * 256 + threadIdx.x;
    if (idx >= NTOK * DECKP) return;
    int n = idx / DECKP, k = idx - n * DECKP;
    dst[idx] = f2b(k < NHID ? dec_W[k * NTOK + n] : 0.f);
}

__global__ __launch_bounds__(256) void cvt_split_ew(const float* __restrict__ EWfull,
                                                    unsigned short* __restrict__ dst)
{
    int idx = blockIdx.x * 256 + threadIdx.x;
    if (idx >= CNP * NTOK) return;
    int n = idx / NTOK, k = idx - n * NTOK;
    float x = (n < CN) ? EWfull[(long)k * CNP + n] : 0.f;
    unsigned short hi, mid, lo;
    split3(x, hi, mid, lo);
    long base = (long)n * (3 * KV0) + k;
    dst[base] = hi;
    dst[base + KV0] = mid;
    dst[base + 2 * KV0] = lo;
}

// W_ih -> B_U2: [4][1920][3*128]; col j = n*300 + e
__global__ __launch_bounds__(256) void cvt_split_bu2(const float* __restrict__ W_ih,
                                                     unsigned short* __restrict__ dst)
{
    int idx = blockIdx.x * 256 + threadIdx.x;
    if (idx >= HH * UN2P * UK0) return;
    int h = idx / (UN2P * UK0), r = idx - h * (UN2P * UK0);
    int j = r / UK0, kk = r - j * UK0;
    float x = 0.f;
    if (kk < DV && j < UN2) {
        int n = j / G3, e = j - n * G3;
        x = W_ih[((long)n * ATT + h * DV + kk) * G3 + e];
    }
    unsigned short hi, mid, lo;
    split3(x, hi, mid, lo);
    long base = ((long)h * UN2P + j) * (3 * UK0) + kk;
    dst[base] = hi;
    dst[base + UK0] = mid;
    dst[base + 2 * UK0] = lo;
}

__global__ __launch_bounds__(256) void cvt_split_in(const float* __restrict__ src,
                                                    unsigned short* __restrict__ dst, long rows)
{
    long total = rows * NTOK;
    long i = (long)blockIdx.x * 256 + threadIdx.x;
    long stride = (long)gridDim.x * 256;
    for (; i < total; i += stride) {
        long row = i / NTOK; int k = (int)(i - row * NTOK);
        unsigned short hi, mid, lo;
        split3(src[i], hi, mid, lo);
        long base = row * (3 * KV0) + k;
        dst[base] = hi;
        dst[base + KV0] = mid;
        dst[base + 2 * KV0] = lo;
    }
}

// ===== step kernel v6: 1024 threads, SW=2, f32x4 W_hh reads =====
__global__ __launch_bounds__(1024) void step_fused(
    const float* __restrict__ h_prev,       // [512,600]
    const float* __restrict__ masks_t,      // [512]
    const float* __restrict__ Kbuf,         // [MU,400]
    const float* __restrict__ U,            // [4,MU,1800]
    const float* __restrict__ b_ih, const float* __restrict__ b_hh,
    const float* __restrict__ Whh4,         // [6][100][100][4]
    const float* __restrict__ Wq_c, const float* __restrict__ Wk_c,
    const float* __restrict__ Wv_c, const float* __restrict__ Wo_c,
    float* __restrict__ h_out,              // [512,600]
    unsigned short* __restrict__ A_dec,     // [MU,640] bf16
    int s_step, int MU)
{
    const int b0 = blockIdx.x * SW, tid = threadIdx.x;
    __shared__ __align__(16) float hbT[NHID][SW];
    __shared__ __align__(16) float hnT[NHID][SW];
    __shared__ __align__(16) float kp[SW][KAPN];
    __shared__ __align__(16) float qcb[SW][768], kcb[SW][768], vcb[SW][768];
    __shared__ __align__(16) float coT[NBK * 128][SW];
    __shared__ float part[SW * 96];
    __shared__ float att[SW][24], mk[SW][NBK];
    __shared__ float lg[SW][144];

    const long rowd0 = (long)s_step * BATCH + b0;

    // ---- P0: load state (transposed) + kappa ----
    for (int i = tid; i < SW * NHID; i += 1024) {
        int s = i / NHID, j = i - s * NHID;
        hbT[j][s] = h_prev[(long)(b0 + s) * NHID + j] * masks_t[b0 + s];
    }
    for (int i = tid; i < SW * KAPN; i += 1024) {
        int s = i / KAPN, j = i - s * KAPN;
        kp[s][j] = Kbuf[(rowd0 + s) * KAPN + j];
    }
    __syncthreads();
    // ---- P1: input-attention logits ----
    if (tid < SW * 96) {
        int g = tid >> 2, q = tid & 3;
        int s = g / 24, r = g - s * 24;
        int n = r >> 2, h = r & 3;
        float acc = 0.f;
        int w0 = q * 25;
        for (int w = w0; w < w0 + 25; w++) acc += hbT[n * BS + w][s] * kp[s][h * BS + w];
        part[tid] = acc;
    }
    __syncthreads();
    if (tid < SW * 24) {
        int s = tid / 24, r = tid - s * 24;
        float l = part[tid * 4] + part[tid * 4 + 1] + part[tid * 4 + 2] + part[tid * 4 + 3];
        att[s][r] = sigf(l * 0.125f);        // softmax([l,0])[0] == sigmoid(l)
    }
    __syncthreads();
    if (tid < SW) {
        float a[NBK], av[NBK];
        for (int n = 0; n < NBK; n++) {
            av[n] = 0.25f * (att[tid][n * 4] + att[tid][n * 4 + 1] + att[tid][n * 4 + 2] + att[tid][n * 4 + 3]);
            a[n] = av[n];
        }
        for (int i = 0; i < 4; i++) {
            int mx = i;
            for (int j = i + 1; j < NBK; j++) if (a[j] > a[mx]) mx = j;
            float t = a[i]; a[i] = a[mx]; a[mx] = t;
        }
        float kth = a[3];
        for (int n = 0; n < NBK; n++) mk[tid][n] = (av[n] >= kth) ? 1.f : 0.f;
    }

    // ---- P2: GRU — gi (U gather) + gh (f32x4 Whh4) + pointwise ----
    if (tid < 600) {
        const int n2 = tid / 100, w2 = tid - n2 * 100;
        float gi[3][SW], gh[3][SW];
#pragma unroll
        for (int g = 0; g < 3; g++) {
            float bi = b_ih[n2 * G3 + g * BS + w2];
            float bh = b_hh[n2 * G3 + g * BS + w2];
#pragma unroll
            for (int s = 0; s < SW; s++) { gi[g][s] = bi; gh[g][s] = bh; }
        }
#pragma unroll
        for (int h = 0; h < HH; h++) {
            const float* Uh = U + ((long)h * MU + rowd0) * UN2 + n2 * G3;
#pragma unroll
            for (int s = 0; s < SW; s++) {
                float a = att[s][n2 * 4 + h];
#pragma unroll
                for (int g = 0; g < 3; g++)
                    gi[g][s] += a * Uh[(long)s * UN2 + g * BS + w2];
            }
        }
        const f32x4* Wn4 = ((const f32x4*)Whh4) + (long)n2 * BS * BS + w2;
#pragma unroll 4
        for (int d = 0; d < BS; d++) {
            f32x4 wv = Wn4[(long)d * BS];
            float2 hv = *(const float2*)&hbT[n2 * BS + d][0];
            gh[0][0] += wv[0] * hv.x; gh[0][1] += wv[0] * hv.y;
            gh[1][0] += wv[1] * hv.x; gh[1][1] += wv[1] * hv.y;
            gh[2][0] += wv[2] * hv.x; gh[2][1] += wv[2] * hv.y;
        }
        float2 hnv;
        {
            float rr0 = sigf(gi[0][0] + gh[0][0]);
            float zz0 = sigf(gi[1][0] + gh[1][0]);
            float ng0 = tanhf(gi[2][0] + rr0 * gh[2][0]);
            hnv.x = (1.f - zz0) * ng0 + zz0 * hbT[n2 * BS + w2][0];
            float rr1 = sigf(gi[0][1] + gh[0][1]);
            float zz1 = sigf(gi[1][1] + gh[1][1]);
            float ng1 = tanhf(gi[2][1] + rr1 * gh[2][1]);
            hnv.y = (1.f - zz1) * ng1 + zz1 * hbT[n2 * BS + w2][1];
        }
        *(float2*)&hnT[n2 * BS + w2][0] = hnv;
    }
    __syncthreads();

    // ---- P3: comm projections (direct-L2 Wq/k/v_c) ----
    if (tid < 768) {
        const int mat = tid >> 8, r = tid & 255, ng = r >> 7, c = r & 127;
        const float* W = (mat == 0) ? Wq_c : ((mat == 1) ? Wk_c : Wv_c);
        float acc[3][SW];
#pragma unroll
        for (int j = 0; j < 3; j++)
#pragma unroll
            for (int s = 0; s < SW; s++) acc[j][s] = 0.f;
#pragma unroll 4
        for (int d = 0; d < BS; d++) {
            float wv = W[d * 128 + c];
#pragma unroll
            for (int j = 0; j < 3; j++) {
                float2 hv = *(const float2*)&hnT[(ng * 3 + j) * BS + d][0];
                acc[j][0] += wv * hv.x;
                acc[j][1] += wv * hv.y;
            }
        }
        float (*dst)[768] = (mat == 0) ? qcb : ((mat == 1) ? kcb : vcb);
#pragma unroll
        for (int j = 0; j < 3; j++)
#pragma unroll
            for (int s = 0; s < SW; s++)
                dst[s][(ng * 3 + j) * 128 + c] = acc[j][s];
    }
    __syncthreads();

    // ---- P4: comm attention logits + softmax + co ----
    if (tid < SW * 144) {
        int s = tid / 144, r = tid - s * 144;
        int h = r / 36, r2 = r - h * 36, n = r2 / NBK, m = r2 - n * NBK;
        float sv = 0.f;
#pragma unroll
        for (int e4 = 0; e4 < 8; e4++) {
            f32x4 qv = *(const f32x4*)&qcb[s][n * 128 + h * 32 + e4 * 4];
            f32x4 kv = *(const f32x4*)&kcb[s][m * 128 + h * 32 + e4 * 4];
            sv += qv[0] * kv[0] + qv[1] * kv[1] + qv[2] * kv[2] + qv[3] * kv[3];
        }
        lg[s][r] = sv * 0.17677669529663687f;
    }
    __syncthreads();
    if (tid < SW * 24) {
        int s = tid / 24, r = tid - s * 24;
        float* row = &lg[s][r * NBK];
        float mx = row[0];
        for (int m = 1; m < NBK; m++) mx = fmaxf(mx, row[m]);
        float sv = 0.f;
        for (int m = 0; m < NBK; m++) { row[m] = expf(row[m] - mx); sv += row[m]; }
        float inv = 1.f / sv;
        for (int m = 0; m < NBK; m++) row[m] *= inv;
    }
    __syncthreads();
    for (int idx = tid; idx < SW * 768; idx += 1024) {
        int s = idx / 768, r = idx - s * 768;
        int n = r >> 7, d = r & 127, h = d >> 5;
        float a = 0.f;
#pragma unroll
        for (int m = 0; m < NBK; m++) a += lg[s][h * 36 + n * NBK + m] * vcb[s][m * 128 + d];
        coT[r][s] = a;
    }
    __syncthreads();

    // ---- P5: co @ Wo_c + masked select ----
    if (tid < 600) {
        const int n2 = tid / 100, w2 = tid - n2 * 100;
        float a0 = 0.f, a1 = 0.f;
#pragma unroll 4
        for (int d = 0; d < 128; d++) {
            float wv = Wo_c[d * BS + w2];
            float2 cv = *(const float2*)&coT[n2 * 128 + d][0];
            a0 += wv * cv.x;
            a1 += wv * cv.y;
        }
        float2 res;
        float hc0 = hnT[n2 * BS + w2][0] + a0;
        float hc1 = hnT[n2 * BS + w2][1] + a1;
        res.x = (mk[0][n2] > 0.5f) ? hc0 : hbT[n2 * BS + w2][0];
        res.y = (mk[1][n2] > 0.5f) ? hc1 : hbT[n2 * BS + w2][1];
        *(float2*)&hbT[n2 * BS + w2][0] = res;
    }
    __syncthreads();
    // ---- P6: coalesced global writes ----
    for (int i = tid; i < SW * NHID; i += 1024) {
        int s = i / NHID, j = i - s * NHID;
        h_out[(long)(b0 + s) * NHID + j] = hbT[j][s];
    }
    for (int i = tid; i < SW * DECKP; i += 1024) {
        int s = i / DECKP, col = i - s * DECKP;
        A_dec[(rowd0 + s) * DECKP + col] = f2b(col < NHID ? hbT[col][s] : 0.f);
    }
}

// ===== host launch =====
extern "C" void kernel_launch(void* const* d_in, const int* in_sizes, int n_in,
                              void* d_out, int out_size, void* d_ws, size_t ws_size,
                              hipStream_t stream)
{
    const float* input = (const float*)d_in[0];
    const float* h0    = (const float*)d_in[1];
    const float* masks = (const float*)d_in[2];
    const float* enc_W = (const float*)d_in[3];
    const float* enc_b = (const float*)d_in[4];
    const float* Wq_in = (const float*)d_in[5];
    const float* Wk_in = (const float*)d_in[6];
    const float* Wv_in = (const float*)d_in[7];
    const float* W_ih  = (const float*)d_in[8];
    const float* W_hh  = (const float*)d_in[9];
    const float* b_ih  = (const float*)d_in[10];
    const float* b_hh  = (const float*)d_in[11];
    const float* Wq_c  = (const float*)d_in[12];
    const float* Wk_c  = (const float*)d_in[13];
    const float* Wv_c  = (const float*)d_in[14];
    const float* Wo_c  = (const float*)d_in[15];
    const float* dec_W = (const float*)d_in[16];
    const float* dec_b = (const float*)d_in[17];
    float* out = (float*)d_out;

    const size_t AL = 256;
    auto pad = [&](size_t x) { return (x + AL - 1) & ~(AL - 1); };
    size_t fixedB = pad((size_t)NTOK * CNP * 4)
                  + pad((size_t)NTOK * 256 * 4)
                  + pad((size_t)HH * DK * BS * 4)
                  + pad((size_t)256 * 4)
                  + pad((size_t)CNP * 4)
                  + pad((size_t)NBK * BS * BS * 4 * 4)     // Whh4
                  + pad((size_t)CNP * 3 * KV0 * 2)
                  + pad((size_t)HH * UN2P * 3 * UK0 * 2)
                  + pad((size_t)NTOK * DECKP * 2)
                  + 2 * pad((size_t)BATCH * NHID * 4);
    auto perC = [&](int C) {
        size_t MU = (size_t)C * BATCH;
        return pad(MU * 3 * KV0 * 2)
             + pad(MU * KAPN * 4)
             + pad((size_t)HH * MU * 3 * UK0 * 2)
             + pad((size_t)HH * MU * UN2 * 4)
             + pad(MU * DECKP * 2);
    };
    int C = 8;
    while (C > 1 && fixedB + perC(C) > ws_size) C >>= 1;
    const int MU = C * BATCH;
    const int NCH = T_STEPS / C;

    char* p = (char*)d_ws;
    auto alloc = [&](size_t bytes) { char* r = p; p += pad(bytes); return r; };
    float*          EWfull = (float*)alloc((size_t)NTOK * CNP * 4);
    float*          EWk    = (float*)alloc((size_t)NTOK * 256 * 4);
    float*          WqT    = (float*)alloc((size_t)HH * DK * BS * 4);
    float*          kbf    = (float*)alloc((size_t)256 * 4);
    float*          bias_c = (float*)alloc((size_t)CNP * 4);
    float*          Whh4   = (float*)alloc((size_t)NBK * BS * BS * 4 * 4);
    unsigned short* B_vkap = (unsigned short*)alloc((size_t)CNP * 3 * KV0 * 2);
    unsigned short* B_U    = (unsigned short*)alloc((size_t)HH * UN2P * 3 * UK0 * 2);
    unsigned short* B_dec  = (unsigned short*)alloc((size_t)NTOK * DECKP * 2);
    float*          hA     = (float*)alloc((size_t)BATCH * NHID * 4);
    float*          hB     = (float*)alloc((size_t)BATCH * NHID * 4);
    unsigned short* A_in   = (unsigned short*)alloc((size_t)MU * 3 * KV0 * 2);
    float*          Kbuf   = (float*)alloc((size_t)MU * KAPN * 4);
    unsigned short* A_U    = (unsigned short*)alloc((size_t)HH * MU * 3 * UK0 * 2);
    float*          Ubuf   = (float*)alloc((size_t)HH * MU * UN2 * 4);
    unsigned short* A_dec  = (unsigned short*)alloc((size_t)MU * DECKP * 2);

    dim3 blk(256);
    ZOff z0 = {1, 0, 0};

    // ---- setup ----
    sgemm<<<dim3(6, 4, 1), blk, 0, stream>>>(
        enc_W, z0, NINP, Wv_in, z0, HH * DV, EWfull, z0, CNP, NTOK, VN, NINP);
    sgemm<<<dim3(4, 4, 1), blk, 0, stream>>>(
        enc_W, z0, NINP, Wk_in, z0, HH * DK, EWk, z0, 256, NTOK, HH * DK, NINP);
    prep_wqt<<<dim3((HH * DK * BS + 255) / 256), blk, 0, stream>>>(Wq_in, WqT);
    prep_whh4<<<dim3((NBK * BS * G3 + 255) / 256), blk, 0, stream>>>(W_hh, Whh4);
    sgemm<<<dim3(2, 4, HH), blk, 0, stream>>>(
        EWk, ZOff{1, DK, 0}, 256, WqT, ZOff{1, (long)DK * BS, 0}, BS,
        EWfull + VN, ZOff{1, BS, 0}, CNP, NTOK, BS, DK);
    bias_k<<<dim3(1), blk, 0, stream>>>(enc_b, Wk_in, kbf);
    bias_c_kernel<<<dim3(3), blk, 0, stream>>>(enc_b, Wv_in, kbf, WqT, bias_c);
    cvt_split_ew<<<dim3((CNP * NTOK + 255) / 256), blk, 0, stream>>>(EWfull, B_vkap);
    cvt_split_bu2<<<dim3((HH * UN2P * UK0 + 255) / 256), blk, 0, stream>>>(W_ih, B_U);
    cvt_dec<<<dim3((NTOK * DECKP + 255) / 256), blk, 0, stream>>>(dec_W, B_dec);

    const float* hp = h0;
    float* hbufs[2] = { hA, hB };
    int t = 0;
    for (int c = 0; c < NCH; c++) {
        cvt_split_in<<<dim3(2048), blk, 0, stream>>>(
            input + (size_t)c * MU * NTOK, A_in, MU);
        // kv + kappa, fused epilogue -> A_U (v splits) + Kbuf
        gemm6_kv<<<dim3(CNP / 128, MU / 128, 1), blk, 0, stream>>>(
            A_in, B_vkap, A_U, Kbuf, bias_c, KV0, MU);
        // U: z=h, N=1800 merged over n
        gemm6<<<dim3(UN2P / 128, MU / 128, HH), blk, 0, stream>>>(
            A_U, (long)MU * 3 * UK0, 1, B_U, (long)UN2P * 3 * UK0,
            Ubuf, (long)MU * UN2, UN2, UN2, nullptr, UK0);
        for (int s = 0; s < C; s++, t++) {
            float* hout = hbufs[t & 1];
            step_fused<<<dim3(BATCH / SW), dim3(1024), 0, stream>>>(
                hp, masks + (size_t)t * BATCH, Kbuf, Ubuf, b_ih, b_hh, Whh4,
                Wq_c, Wk_c, Wv_c, Wo_c, hout, A_dec, s, MU);
            hp = hout;
        }
        gemm_mfma<<<dim3(NTOK / 128, MU / 128, 1), blk, 0, stream>>>(
            A_dec, B_dec, out + (size_t)c * MU * NTOK, NTOK, dec_b, DECKP);
    }
}

// Round 11
// 6374.080 us; speedup vs baseline: 3.0996x; 1.0255x over previous
//
#include <hip/hip_runtime.h>
#include <math.h>

#define T_STEPS 128
#define BATCH   512
#define NTOK    512
#define NINP    512
#define NHID    600
#define NBK     6
#define BS      100
#define HH      4
#define DK      64
#define DV      85
#define ATT     340
#define H2      4
#define DK2     32
#define DV2     32
#define G3      300
#define VN      340
#define KAPN    400
#define CN      740
#define CNP     768
#define UN2     1800     // merged U cols per head (6 blocks x 300)
#define UN2P    1920     // padded to 15*128
#define UK0     128
#define KV0     512
#define DECKP   640
#define SW      2        // samples per step-block -> grid 256 = all CUs

typedef __attribute__((ext_vector_type(8))) short short8;
typedef __attribute__((ext_vector_type(4))) float f32x4;

__device__ __forceinline__ float sigf(float x) { return 1.f / (1.f + expf(-x)); }
__device__ __forceinline__ unsigned short f2b(float f) {
    unsigned u = __float_as_uint(f);
    unsigned r = (u + 0x7fffu + ((u >> 16) & 1u)) >> 16;
    return (unsigned short)r;
}
__device__ __forceinline__ float b2f(unsigned short u) {
    return __uint_as_float(((unsigned)u) << 16);
}
__device__ __forceinline__ void split3(float x, unsigned short& hi,
                                       unsigned short& mid, unsigned short& lo) {
    hi = f2b(x);
    float r1 = x - b2f(hi);
    mid = f2b(r1);
    lo = f2b(r1 - b2f(mid));
}

struct ZOff { int div; long s1; long s2; };
__device__ __forceinline__ long zoff(ZOff z, int bz) {
    return (long)(bz / z.div) * z.s1 + (long)(bz % z.div) * z.s2;
}

// ===== bf16x6 MFMA GEMM: fp32-class C = A@B^T (+bias) via 6 segment passes =====
// (plain block mapping: R10 measured the XCD swizzle as a 6% regression here)
__global__ __launch_bounds__(256) void gemm6(
    const unsigned short* __restrict__ A, long aZ, int aZdiv,
    const unsigned short* __restrict__ B, long bZ,
    float* __restrict__ C, long cZ, int ldc, int Nreal,
    const float* __restrict__ bias, int K0)
{
    const int bz = blockIdx.z;
    A += (long)(bz / aZdiv) * aZ;
    B += (long)bz * bZ;
    C += (long)bz * cZ;
    const int LDA = 3 * K0;
    const int m0 = blockIdx.y * 128, n0 = blockIdx.x * 128;
    __shared__ __align__(16) unsigned short As[128 * 64];
    __shared__ __align__(16) unsigned short Bs[128 * 64];
    const int tid = threadIdx.x;
    const int lane = tid & 63;
    const int wid = tid >> 6;
    const int wr = wid >> 1, wc = wid & 1;

    f32x4 acc[4][4];
#pragma unroll
    for (int m = 0; m < 4; m++)
#pragma unroll
        for (int n = 0; n < 4; n++)
#pragma unroll
            for (int v = 0; v < 4; v++) acc[m][n][v] = 0.f;

    const int segA[6] = {0, 0, 1, 0, 2, 1};
    const int segB[6] = {0, 1, 0, 2, 0, 1};
    for (int p = 0; p < 6; p++) {
        const unsigned short* Ap = A + segA[p] * K0;
        const unsigned short* Bp = B + segB[p] * K0;
        for (int k0 = 0; k0 < K0; k0 += 64) {
            short8 ra[4], rb[4];
#pragma unroll
            for (int q = 0; q < 4; q++) {
                int idx = (q << 8) + tid;
                int r = idx >> 3, ce = (idx & 7) << 3;
                ra[q] = *(const short8*)&Ap[(long)(m0 + r) * LDA + k0 + ce];
                rb[q] = *(const short8*)&Bp[(long)(n0 + r) * LDA + k0 + ce];
            }
            __syncthreads();
#pragma unroll
            for (int q = 0; q < 4; q++) {
                int idx = (q << 8) + tid;
                int r = idx >> 3, ce = (idx & 7) << 3;
                *(short8*)&As[r * 64 + ce] = ra[q];
                *(short8*)&Bs[r * 64 + ce] = rb[q];
            }
            __syncthreads();
#pragma unroll
            for (int kk = 0; kk < 2; kk++) {
                short8 af[4], bfr[4];
#pragma unroll
                for (int m = 0; m < 4; m++)
                    af[m] = *(const short8*)&As[(wr * 64 + m * 16 + (lane & 15)) * 64 + kk * 32 + (lane >> 4) * 8];
#pragma unroll
                for (int n = 0; n < 4; n++)
                    bfr[n] = *(const short8*)&Bs[(wc * 64 + n * 16 + (lane & 15)) * 64 + kk * 32 + (lane >> 4) * 8];
#pragma unroll
                for (int m = 0; m < 4; m++)
#pragma unroll
                    for (int n = 0; n < 4; n++)
                        acc[m][n] = __builtin_amdgcn_mfma_f32_16x16x32_bf16(af[m], bfr[n], acc[m][n], 0, 0, 0);
            }
        }
    }
#pragma unroll
    for (int m = 0; m < 4; m++) {
        int rbase = m0 + wr * 64 + m * 16 + (lane >> 4) * 4;
#pragma unroll
        for (int n = 0; n < 4; n++) {
            int col = n0 + wc * 64 + n * 16 + (lane & 15);
            if (col < Nreal) {
                float bv = bias ? bias[col] : 0.f;
#pragma unroll
                for (int v = 0; v < 4; v++)
                    C[(long)(rbase + v) * ldc + col] = acc[m][n][v] + bv;
            }
        }
    }
}

// kv-variant: fused epilogue -> A_U splits (v cols) + Kbuf fp32 (kappa cols)
__global__ __launch_bounds__(256) void gemm6_kv(
    const unsigned short* __restrict__ A,
    const unsigned short* __restrict__ B,
    unsigned short* __restrict__ A_U,       // [4][MU][3*UK0]
    float* __restrict__ Kbuf,               // [MU][400]
    const float* __restrict__ bias, int K0, int MU)
{
    const int LDA = 3 * K0;
    const int m0 = blockIdx.y * 128, n0 = blockIdx.x * 128;
    __shared__ __align__(16) unsigned short As[128 * 64];
    __shared__ __align__(16) unsigned short Bs[128 * 64];
    const int tid = threadIdx.x;
    const int lane = tid & 63;
    const int wid = tid >> 6;
    const int wr = wid >> 1, wc = wid & 1;

    f32x4 acc[4][4];
#pragma unroll
    for (int m = 0; m < 4; m++)
#pragma unroll
        for (int n = 0; n < 4; n++)
#pragma unroll
            for (int v = 0; v < 4; v++) acc[m][n][v] = 0.f;

    const int segA[6] = {0, 0, 1, 0, 2, 1};
    const int segB[6] = {0, 1, 0, 2, 0, 1};
    for (int p = 0; p < 6; p++) {
        const unsigned short* Ap = A + segA[p] * K0;
        const unsigned short* Bp = B + segB[p] * K0;
        for (int k0 = 0; k0 < K0; k0 += 64) {
            short8 ra[4], rb[4];
#pragma unroll
            for (int q = 0; q < 4; q++) {
                int idx = (q << 8) + tid;
                int r = idx >> 3, ce = (idx & 7) << 3;
                ra[q] = *(const short8*)&Ap[(long)(m0 + r) * LDA + k0 + ce];
                rb[q] = *(const short8*)&Bp[(long)(n0 + r) * LDA + k0 + ce];
            }
            __syncthreads();
#pragma unroll
            for (int q = 0; q < 4; q++) {
                int idx = (q << 8) + tid;
                int r = idx >> 3, ce = (idx & 7) << 3;
                *(short8*)&As[r * 64 + ce] = ra[q];
                *(short8*)&Bs[r * 64 + ce] = rb[q];
            }
            __syncthreads();
#pragma unroll
            for (int kk = 0; kk < 2; kk++) {
                short8 af[4], bfr[4];
#pragma unroll
                for (int m = 0; m < 4; m++)
                    af[m] = *(const short8*)&As[(wr * 64 + m * 16 + (lane & 15)) * 64 + kk * 32 + (lane >> 4) * 8];
#pragma unroll
                for (int n = 0; n < 4; n++)
                    bfr[n] = *(const short8*)&Bs[(wc * 64 + n * 16 + (lane & 15)) * 64 + kk * 32 + (lane >> 4) * 8];
#pragma unroll
                for (int m = 0; m < 4; m++)
#pragma unroll
                    for (int n = 0; n < 4; n++)
                        acc[m][n] = __builtin_amdgcn_mfma_f32_16x16x32_bf16(af[m], bfr[n], acc[m][n], 0, 0, 0);
            }
        }
    }
#pragma unroll
    for (int m = 0; m < 4; m++) {
        int rbase = m0 + wr * 64 + m * 16 + (lane >> 4) * 4;
#pragma unroll
        for (int n = 0; n < 4; n++) {
            int col = n0 + wc * 64 + n * 16 + (lane & 15);
            if (col < CN) {
                float bv = bias[col];
                if (col < VN) {
                    int h = col / DV, kk2 = col - h * DV;
#pragma unroll
                    for (int v = 0; v < 4; v++) {
                        float val = acc[m][n][v] + bv;
                        unsigned short hi, mid, lo;
                        split3(val, hi, mid, lo);
                        long base = ((long)h * MU + (rbase + v)) * (3 * UK0) + kk2;
                        A_U[base] = hi;
                        A_U[base + UK0] = mid;
                        A_U[base + 2 * UK0] = lo;
                    }
                } else {
                    int kc = col - VN;
#pragma unroll
                    for (int v = 0; v < 4; v++)
                        Kbuf[(long)(rbase + v) * KAPN + kc] = acc[m][n][v] + bv;
                }
            }
        }
    }
}

// ===== plain bf16 MFMA GEMM (decoder only) =====
__global__ __launch_bounds__(256) void gemm_mfma(
    const unsigned short* __restrict__ A,
    const unsigned short* __restrict__ B,
    float* __restrict__ C, int ldc,
    const float* __restrict__ bias, int Kp)
{
    const int m0 = blockIdx.y * 128, n0 = blockIdx.x * 128;
    __shared__ __align__(16) unsigned short As[128 * 64];
    __shared__ __align__(16) unsigned short Bs[128 * 64];
    const int tid = threadIdx.x;
    const int lane = tid & 63;
    const int wid = tid >> 6;
    const int wr = wid >> 1, wc = wid & 1;

    f32x4 acc[4][4];
#pragma unroll
    for (int m = 0; m < 4; m++)
#pragma unroll
        for (int n = 0; n < 4; n++)
#pragma unroll
            for (int v = 0; v < 4; v++) acc[m][n][v] = 0.f;

    for (int k0 = 0; k0 < Kp; k0 += 64) {
        short8 ra[4], rb[4];
#pragma unroll
        for (int q = 0; q < 4; q++) {
            int idx = (q << 8) + tid;
            int r = idx >> 3, ce = (idx & 7) << 3;
            ra[q] = *(const short8*)&A[(long)(m0 + r) * Kp + k0 + ce];
            rb[q] = *(const short8*)&B[(long)(n0 + r) * Kp + k0 + ce];
        }
        __syncthreads();
#pragma unroll
        for (int q = 0; q < 4; q++) {
            int idx = (q << 8) + tid;
            int r = idx >> 3, ce = (idx & 7) << 3;
            *(short8*)&As[r * 64 + ce] = ra[q];
            *(short8*)&Bs[r * 64 + ce] = rb[q];
        }
        __syncthreads();
#pragma unroll
        for (int kk = 0; kk < 2; kk++) {
            short8 af[4], bfr[4];
#pragma unroll
            for (int m = 0; m < 4; m++)
                af[m] = *(const short8*)&As[(wr * 64 + m * 16 + (lane & 15)) * 64 + kk * 32 + (lane >> 4) * 8];
#pragma unroll
            for (int n = 0; n < 4; n++)
                bfr[n] = *(const short8*)&Bs[(wc * 64 + n * 16 + (lane & 15)) * 64 + kk * 32 + (lane >> 4) * 8];
#pragma unroll
            for (int m = 0; m < 4; m++)
#pragma unroll
                for (int n = 0; n < 4; n++)
                    acc[m][n] = __builtin_amdgcn_mfma_f32_16x16x32_bf16(af[m], bfr[n], acc[m][n], 0, 0, 0);
        }
    }
#pragma unroll
    for (int m = 0; m < 4; m++) {
        int rbase = m0 + wr * 64 + m * 16 + (lane >> 4) * 4;
#pragma unroll
        for (int n = 0; n < 4; n++) {
            int col = n0 + wc * 64 + n * 16 + (lane & 15);
            float bv = bias ? bias[col] : 0.f;
#pragma unroll
            for (int v = 0; v < 4; v++)
                C[(long)(rbase + v) * ldc + col] = acc[m][n][v] + bv;
        }
    }
}

// ===== fp32 SGEMM (setup-only small jobs) =====
__global__ __launch_bounds__(256) void sgemm(
    const float* __restrict__ A, ZOff za, int lda,
    const float* __restrict__ B, ZOff zb, int ldb,
    float* __restrict__ C, ZOff zc, int ldc,
    int M, int N, int K)
{
    const int bz = blockIdx.z;
    A += zoff(za, bz);
    B += zoff(zb, bz);
    C += zoff(zc, bz);
    const int m0 = blockIdx.y * 128, n0 = blockIdx.x * 64;
    __shared__ float As[16][132];
    __shared__ float Bs[16][68];
    const int tid = threadIdx.x;
    const int tm = tid >> 4, tn = tid & 15;
    const int ar = tid >> 1, ak = (tid & 1) * 8;
    const int bk = tid >> 4, bn = (tid & 15) * 4;

    float acc[8][4];
#pragma unroll
    for (int i = 0; i < 8; i++)
#pragma unroll
        for (int j = 0; j < 4; j++) acc[i][j] = 0.f;

    for (int k0 = 0; k0 < K; k0 += 16) {
        float av[8], bv[4];
#pragma unroll
        for (int j = 0; j < 8; j++) {
            int gk = k0 + ak + j;
            av[j] = (gk < K) ? A[(long)(m0 + ar) * lda + gk] : 0.f;
        }
#pragma unroll
        for (int j = 0; j < 4; j++) {
            int gk = k0 + bk, gn = n0 + bn + j;
            bv[j] = (gk < K && gn < N) ? B[(long)gk * ldb + gn] : 0.f;
        }
        __syncthreads();
#pragma unroll
        for (int j = 0; j < 8; j++) As[ak + j][ar] = av[j];
#pragma unroll
        for (int j = 0; j < 4; j++) Bs[bk][bn + j] = bv[j];
        __syncthreads();
#pragma unroll
        for (int kk = 0; kk < 16; kk++) {
            float a[8], b[4];
#pragma unroll
            for (int i = 0; i < 8; i++) a[i] = As[kk][tm * 8 + i];
#pragma unroll
            for (int j = 0; j < 4; j++) b[j] = Bs[kk][tn * 4 + j];
#pragma unroll
            for (int i = 0; i < 8; i++)
#pragma unroll
                for (int j = 0; j < 4; j++)
                    acc[i][j] += a[i] * b[j];
        }
    }
#pragma unroll
    for (int i = 0; i < 8; i++) {
        int gm = m0 + tm * 8 + i;
#pragma unroll
        for (int j = 0; j < 4; j++) {
            int gn = n0 + tn * 4 + j;
            if (gn < N) C[(long)gm * ldc + gn] = acc[i][j];
        }
    }
}

// ===== prep kernels =====
__global__ __launch_bounds__(256) void prep_wqt(const float* __restrict__ Wq_in,
                                                float* __restrict__ WqT)
{
    int idx = blockIdx.x * 256 + threadIdx.x;
    if (idx >= HH * DK * BS) return;
    int h = idx / (DK * BS), r = idx - h * DK * BS, d = r / BS, w = r - d * BS;
    WqT[idx] = Wq_in[w * (HH * DK) + h * DK + d];
}

// W_hh[n][d][g*100+w] -> Whh4[n][d][w][4]
__global__ __launch_bounds__(256) void prep_whh4(const float* __restrict__ W_hh,
                                                 float* __restrict__ Whh4)
{
    int idx = blockIdx.x * 256 + threadIdx.x;
    if (idx >= NBK * BS * G3) return;
    int n = idx / (BS * G3), r = idx - n * (BS * G3);
    int d = r / G3, e = r - d * G3;
    int g = e / BS, w = e - g * BS;
    Whh4[(((long)n * BS + d) * BS + w) * 4 + g] = W_hh[idx];
}

__global__ __launch_bounds__(256) void bias_k(const float* __restrict__ enc_b,
                                              const float* __restrict__ Wk,
                                              float* __restrict__ kbf)
{
    int j = threadIdx.x;
    if (j >= HH * DK) return;
    float acc = 0.f;
    for (int d = 0; d < NINP; d++) acc += enc_b[d] * Wk[d * (HH * DK) + j];
    kbf[j] = acc;
}

__global__ __launch_bounds__(256) void bias_c_kernel(const float* __restrict__ enc_b,
                                                     const float* __restrict__ Wv,
                                                     const float* __restrict__ kbf,
                                                     const float* __restrict__ WqT,
                                                     float* __restrict__ bias_c)
{
    int j = blockIdx.x * 256 + threadIdx.x;
    if (j >= CNP) return;
    float acc = 0.f;
    if (j < VN) {
        for (int d = 0; d < NINP; d++) acc += enc_b[d] * Wv[d * (HH * DV) + j];
    } else if (j < CN) {
        int r = j - VN;
        int h = r / BS, w = r - h * BS;
        for (int d = 0; d < DK; d++)
            acc += kbf[h * DK + d] * WqT[(h * DK + d) * BS + w];
    }
    bias_c[j] = acc;
}

__global__ __launch_bounds__(256) void cvt_dec(const float* __restrict__ dec_W,
                                               unsigned short* __restrict__ dst)
{
    int idx = blockIdx.x * 256 + threadIdx.x;
    if (idx >= NTOK * DECKP) return;
    int n = idx / DECKP, k = idx - n * DECKP;
    dst[idx] = f2b(k < NHID ? dec_W[k * NTOK + n] : 0.f);
}

__global__ __launch_bounds__(256) void cvt_split_ew(const float* __restrict__ EWfull,
                                                    unsigned short* __restrict__ dst)
{
    int idx = blockIdx.x * 256 + threadIdx.x;
    if (idx >= CNP * NTOK) return;
    int n = idx / NTOK, k = idx - n * NTOK;
    float x = (n < CN) ? EWfull[(long)k * CNP + n] : 0.f;
    unsigned short hi, mid, lo;
    split3(x, hi, mid, lo);
    long base = (long)n * (3 * KV0) + k;
    dst[base] = hi;
    dst[base + KV0] = mid;
    dst[base + 2 * KV0] = lo;
}

// W_ih -> B_U2: [4][1920][3*128]; col j = n*300 + e
__global__ __launch_bounds__(256) void cvt_split_bu2(const float* __restrict__ W_ih,
                                                     unsigned short* __restrict__ dst)
{
    int idx = blockIdx.x * 256 + threadIdx.x;
    if (idx >= HH * UN2P * UK0) return;
    int h = idx / (UN2P * UK0), r = idx - h * (UN2P * UK0);
    int j = r / UK0, kk = r - j * UK0;
    float x = 0.f;
    if (kk < DV && j < UN2) {
        int n = j / G3, e = j - n * G3;
        x = W_ih[((long)n * ATT + h * DV + kk) * G3 + e];
    }
    unsigned short hi, mid, lo;
    split3(x, hi, mid, lo);
    long base = ((long)h * UN2P + j) * (3 * UK0) + kk;
    dst[base] = hi;
    dst[base + UK0] = mid;
    dst[base + 2 * UK0] = lo;
}

__global__ __launch_bounds__(256) void cvt_split_in(const float* __restrict__ src,
                                                    unsigned short* __restrict__ dst, long rows)
{
    long total = rows * NTOK;
    long i = (long)blockIdx.x * 256 + threadIdx.x;
    long stride = (long)gridDim.x * 256;
    for (; i < total; i += stride) {
        long row = i / NTOK; int k = (int)(i - row * NTOK);
        unsigned short hi, mid, lo;
        split3(src[i], hi, mid, lo);
        long base = row * (3 * KV0) + k;
        dst[base] = hi;
        dst[base + KV0] = mid;
        dst[base + 2 * KV0] = lo;
    }
}

// ===== step kernel v7: early-issue U gather + deep unrolls =====
__global__ __launch_bounds__(1024) void step_fused(
    const float* __restrict__ h_prev,       // [512,600]
    const float* __restrict__ masks_t,      // [512]
    const float* __restrict__ Kbuf,         // [MU,400]
    const float* __restrict__ U,            // [4,MU,1800]
    const float* __restrict__ b_ih, const float* __restrict__ b_hh,
    const float* __restrict__ Whh4,         // [6][100][100][4]
    const float* __restrict__ Wq_c, const float* __restrict__ Wk_c,
    const float* __restrict__ Wv_c, const float* __restrict__ Wo_c,
    float* __restrict__ h_out,              // [512,600]
    unsigned short* __restrict__ A_dec,     // [MU,640] bf16
    int s_step, int MU)
{
    const int b0 = blockIdx.x * SW, tid = threadIdx.x;
    __shared__ __align__(16) float hbT[NHID][SW];
    __shared__ __align__(16) float hnT[NHID][SW];
    __shared__ __align__(16) float kp[SW][KAPN];
    __shared__ __align__(16) float qcb[SW][768], kcb[SW][768], vcb[SW][768];
    __shared__ __align__(16) float coT[NBK * 128][SW];
    __shared__ float part[SW * 96];
    __shared__ float att[SW][24], mk[SW][NBK];
    __shared__ float lg[SW][144];

    const long rowd0 = (long)s_step * BATCH + b0;
    const int n2 = (tid < 600) ? tid / 100 : 0;
    const int w2 = (tid < 600) ? tid - n2 * 100 : 0;

    // ---- EARLY ISSUE: U gather (consumed in P2, ~5 barriers later) ----
    float uraw[HH][3][SW];
    if (tid < 600) {
#pragma unroll
        for (int h = 0; h < HH; h++) {
            const float* Uh = U + ((long)h * MU + rowd0) * UN2 + n2 * G3;
#pragma unroll
            for (int s = 0; s < SW; s++)
#pragma unroll
                for (int g = 0; g < 3; g++)
                    uraw[h][g][s] = Uh[(long)s * UN2 + g * BS + w2];
        }
    }

    // ---- P0: load state (transposed) + kappa ----
    for (int i = tid; i < SW * NHID; i += 1024) {
        int s = i / NHID, j = i - s * NHID;
        hbT[j][s] = h_prev[(long)(b0 + s) * NHID + j] * masks_t[b0 + s];
    }
    for (int i = tid; i < SW * KAPN; i += 1024) {
        int s = i / KAPN, j = i - s * KAPN;
        kp[s][j] = Kbuf[(rowd0 + s) * KAPN + j];
    }
    __syncthreads();
    // ---- P1: input-attention logits ----
    if (tid < SW * 96) {
        int g = tid >> 2, q = tid & 3;
        int s = g / 24, r = g - s * 24;
        int n = r >> 2, h = r & 3;
        float acc = 0.f;
        int w0 = q * 25;
        for (int w = w0; w < w0 + 25; w++) acc += hbT[n * BS + w][s] * kp[s][h * BS + w];
        part[tid] = acc;
    }
    __syncthreads();
    if (tid < SW * 24) {
        int s = tid / 24, r = tid - s * 24;
        float l = part[tid * 4] + part[tid * 4 + 1] + part[tid * 4 + 2] + part[tid * 4 + 3];
        att[s][r] = sigf(l * 0.125f);        // softmax([l,0])[0] == sigmoid(l)
    }
    __syncthreads();
    if (tid < SW) {
        float a[NBK], av[NBK];
        for (int n = 0; n < NBK; n++) {
            av[n] = 0.25f * (att[tid][n * 4] + att[tid][n * 4 + 1] + att[tid][n * 4 + 2] + att[tid][n * 4 + 3]);
            a[n] = av[n];
        }
        for (int i = 0; i < 4; i++) {
            int mx = i;
            for (int j = i + 1; j < NBK; j++) if (a[j] > a[mx]) mx = j;
            float t = a[i]; a[i] = a[mx]; a[mx] = t;
        }
        float kth = a[3];
        for (int n = 0; n < NBK; n++) mk[tid][n] = (av[n] >= kth) ? 1.f : 0.f;
    }

    // ---- P2: GRU — gi (early-fetched U) + gh (f32x4 Whh4, deep unroll) ----
    if (tid < 600) {
        float gi[3][SW], gh[3][SW];
#pragma unroll
        for (int g = 0; g < 3; g++) {
            float bi = b_ih[n2 * G3 + g * BS + w2];
            float bh = b_hh[n2 * G3 + g * BS + w2];
#pragma unroll
            for (int s = 0; s < SW; s++) { gi[g][s] = bi; gh[g][s] = bh; }
        }
#pragma unroll
        for (int h = 0; h < HH; h++)
#pragma unroll
            for (int s = 0; s < SW; s++) {
                float a = att[s][n2 * 4 + h];
#pragma unroll
                for (int g = 0; g < 3; g++)
                    gi[g][s] += a * uraw[h][g][s];
            }
        const f32x4* Wn4 = ((const f32x4*)Whh4) + (long)n2 * BS * BS + w2;
#pragma unroll 10
        for (int d = 0; d < BS; d++) {
            f32x4 wv = Wn4[(long)d * BS];
            float2 hv = *(const float2*)&hbT[n2 * BS + d][0];
            gh[0][0] += wv[0] * hv.x; gh[0][1] += wv[0] * hv.y;
            gh[1][0] += wv[1] * hv.x; gh[1][1] += wv[1] * hv.y;
            gh[2][0] += wv[2] * hv.x; gh[2][1] += wv[2] * hv.y;
        }
        float2 hnv;
        {
            float rr0 = sigf(gi[0][0] + gh[0][0]);
            float zz0 = sigf(gi[1][0] + gh[1][0]);
            float ng0 = tanhf(gi[2][0] + rr0 * gh[2][0]);
            hnv.x = (1.f - zz0) * ng0 + zz0 * hbT[n2 * BS + w2][0];
            float rr1 = sigf(gi[0][1] + gh[0][1]);
            float zz1 = sigf(gi[1][1] + gh[1][1]);
            float ng1 = tanhf(gi[2][1] + rr1 * gh[2][1]);
            hnv.y = (1.f - zz1) * ng1 + zz1 * hbT[n2 * BS + w2][1];
        }
        *(float2*)&hnT[n2 * BS + w2][0] = hnv;
    }
    __syncthreads();

    // ---- P3: comm projections (direct-L2 Wq/k/v_c, deep unroll) ----
    if (tid < 768) {
        const int mat = tid >> 8, r = tid & 255, ng = r >> 7, c = r & 127;
        const float* W = (mat == 0) ? Wq_c : ((mat == 1) ? Wk_c : Wv_c);
        float acc[3][SW];
#pragma unroll
        for (int j = 0; j < 3; j++)
#pragma unroll
            for (int s = 0; s < SW; s++) acc[j][s] = 0.f;
#pragma unroll 10
        for (int d = 0; d < BS; d++) {
            float wv = W[d * 128 + c];
#pragma unroll
            for (int j = 0; j < 3; j++) {
                float2 hv = *(const float2*)&hnT[(ng * 3 + j) * BS + d][0];
                acc[j][0] += wv * hv.x;
                acc[j][1] += wv * hv.y;
            }
        }
        float (*dst)[768] = (mat == 0) ? qcb : ((mat == 1) ? kcb : vcb);
#pragma unroll
        for (int j = 0; j < 3; j++)
#pragma unroll
            for (int s = 0; s < SW; s++)
                dst[s][(ng * 3 + j) * 128 + c] = acc[j][s];
    }
    __syncthreads();

    // ---- P4: comm attention logits + softmax + co ----
    if (tid < SW * 144) {
        int s = tid / 144, r = tid - s * 144;
        int h = r / 36, r2 = r - h * 36, n = r2 / NBK, m = r2 - n * NBK;
        float sv = 0.f;
#pragma unroll
        for (int e4 = 0; e4 < 8; e4++) {
            f32x4 qv = *(const f32x4*)&qcb[s][n * 128 + h * 32 + e4 * 4];
            f32x4 kv = *(const f32x4*)&kcb[s][m * 128 + h * 32 + e4 * 4];
            sv += qv[0] * kv[0] + qv[1] * kv[1] + qv[2] * kv[2] + qv[3] * kv[3];
        }
        lg[s][r] = sv * 0.17677669529663687f;
    }
    __syncthreads();
    if (tid < SW * 24) {
        int s = tid / 24, r = tid - s * 24;
        float* row = &lg[s][r * NBK];
        float mx = row[0];
        for (int m = 1; m < NBK; m++) mx = fmaxf(mx, row[m]);
        float sv = 0.f;
        for (int m = 0; m < NBK; m++) { row[m] = expf(row[m] - mx); sv += row[m]; }
        float inv = 1.f / sv;
        for (int m = 0; m < NBK; m++) row[m] *= inv;
    }
    __syncthreads();
    for (int idx = tid; idx < SW * 768; idx += 1024) {
        int s = idx / 768, r = idx - s * 768;
        int n = r >> 7, d = r & 127, h = d >> 5;
        float a = 0.f;
#pragma unroll
        for (int m = 0; m < NBK; m++) a += lg[s][h * 36 + n * NBK + m] * vcb[s][m * 128 + d];
        coT[r][s] = a;
    }
    __syncthreads();

    // ---- P5: co @ Wo_c (deep unroll) + masked select ----
    if (tid < 600) {
        float a0 = 0.f, a1 = 0.f;
#pragma unroll 8
        for (int d = 0; d < 128; d++) {
            float wv = Wo_c[d * BS + w2];
            float2 cv = *(const float2*)&coT[n2 * 128 + d][0];
            a0 += wv * cv.x;
            a1 += wv * cv.y;
        }
        float2 res;
        float hc0 = hnT[n2 * BS + w2][0] + a0;
        float hc1 = hnT[n2 * BS + w2][1] + a1;
        res.x = (mk[0][n2] > 0.5f) ? hc0 : hbT[n2 * BS + w2][0];
        res.y = (mk[1][n2] > 0.5f) ? hc1 : hbT[n2 * BS + w2][1];
        *(float2*)&hbT[n2 * BS + w2][0] = res;
    }
    __syncthreads();
    // ---- P6: coalesced global writes ----
    for (int i = tid; i < SW * NHID; i += 1024) {
        int s = i / NHID, j = i - s * NHID;
        h_out[(long)(b0 + s) * NHID + j] = hbT[j][s];
    }
    for (int i = tid; i < SW * DECKP; i += 1024) {
        int s = i / DECKP, col = i - s * DECKP;
        A_dec[(rowd0 + s) * DECKP + col] = f2b(col < NHID ? hbT[col][s] : 0.f);
    }
}

// ===== host launch =====
extern "C" void kernel_launch(void* const* d_in, const int* in_sizes, int n_in,
                              void* d_out, int out_size, void* d_ws, size_t ws_size,
                              hipStream_t stream)
{
    const float* input = (const float*)d_in[0];
    const float* h0    = (const float*)d_in[1];
    const float* masks = (const float*)d_in[2];
    const float* enc_W = (const float*)d_in[3];
    const float* enc_b = (const float*)d_in[4];
    const float* Wq_in = (const float*)d_in[5];
    const float* Wk_in = (const float*)d_in[6];
    const float* Wv_in = (const float*)d_in[7];
    const float* W_ih  = (const float*)d_in[8];
    const float* W_hh  = (const float*)d_in[9];
    const float* b_ih  = (const float*)d_in[10];
    const float* b_hh  = (const float*)d_in[11];
    const float* Wq_c  = (const float*)d_in[12];
    const float* Wk_c  = (const float*)d_in[13];
    const float* Wv_c  = (const float*)d_in[14];
    const float* Wo_c  = (const float*)d_in[15];
    const float* dec_W = (const float*)d_in[16];
    const float* dec_b = (const float*)d_in[17];
    float* out = (float*)d_out;

    const size_t AL = 256;
    auto pad = [&](size_t x) { return (x + AL - 1) & ~(AL - 1); };
    size_t fixedB = pad((size_t)NTOK * CNP * 4)
                  + pad((size_t)NTOK * 256 * 4)
                  + pad((size_t)HH * DK * BS * 4)
                  + pad((size_t)256 * 4)
                  + pad((size_t)CNP * 4)
                  + pad((size_t)NBK * BS * BS * 4 * 4)     // Whh4
                  + pad((size_t)CNP * 3 * KV0 * 2)
                  + pad((size_t)HH * UN2P * 3 * UK0 * 2)
                  + pad((size_t)NTOK * DECKP * 2)
                  + 2 * pad((size_t)BATCH * NHID * 4);
    auto perC = [&](int C) {
        size_t MU = (size_t)C * BATCH;
        return pad(MU * 3 * KV0 * 2)
             + pad(MU * KAPN * 4)
             + pad((size_t)HH * MU * 3 * UK0 * 2)
             + pad((size_t)HH * MU * UN2 * 4)
             + pad(MU * DECKP * 2);
    };
    int C = 8;
    while (C > 1 && fixedB + perC(C) > ws_size) C >>= 1;
    const int MU = C * BATCH;
    const int NCH = T_STEPS / C;

    char* p = (char*)d_ws;
    auto alloc = [&](size_t bytes) { char* r = p; p += pad(bytes); return r; };
    float*          EWfull = (float*)alloc((size_t)NTOK * CNP * 4);
    float*          EWk    = (float*)alloc((size_t)NTOK * 256 * 4);
    float*          WqT    = (float*)alloc((size_t)HH * DK * BS * 4);
    float*          kbf    = (float*)alloc((size_t)256 * 4);
    float*          bias_c = (float*)alloc((size_t)CNP * 4);
    float*          Whh4   = (float*)alloc((size_t)NBK * BS * BS * 4 * 4);
    unsigned short* B_vkap = (unsigned short*)alloc((size_t)CNP * 3 * KV0 * 2);
    unsigned short* B_U    = (unsigned short*)alloc((size_t)HH * UN2P * 3 * UK0 * 2);
    unsigned short* B_dec  = (unsigned short*)alloc((size_t)NTOK * DECKP * 2);
    float*          hA     = (float*)alloc((size_t)BATCH * NHID * 4);
    float*          hB     = (float*)alloc((size_t)BATCH * NHID * 4);
    unsigned short* A_in   = (unsigned short*)alloc((size_t)MU * 3 * KV0 * 2);
    float*          Kbuf   = (float*)alloc((size_t)MU * KAPN * 4);
    unsigned short* A_U    = (unsigned short*)alloc((size_t)HH * MU * 3 * UK0 * 2);
    float*          Ubuf   = (float*)alloc((size_t)HH * MU * UN2 * 4);
    unsigned short* A_dec  = (unsigned short*)alloc((size_t)MU * DECKP * 2);

    dim3 blk(256);
    ZOff z0 = {1, 0, 0};

    // ---- setup ----
    sgemm<<<dim3(6, 4, 1), blk, 0, stream>>>(
        enc_W, z0, NINP, Wv_in, z0, HH * DV, EWfull, z0, CNP, NTOK, VN, NINP);
    sgemm<<<dim3(4, 4, 1), blk, 0, stream>>>(
        enc_W, z0, NINP, Wk_in, z0, HH * DK, EWk, z0, 256, NTOK, HH * DK, NINP);
    prep_wqt<<<dim3((HH * DK * BS + 255) / 256), blk, 0, stream>>>(Wq_in, WqT);
    prep_whh4<<<dim3((NBK * BS * G3 + 255) / 256), blk, 0, stream>>>(W_hh, Whh4);
    sgemm<<<dim3(2, 4, HH), blk, 0, stream>>>(
        EWk, ZOff{1, DK, 0}, 256, WqT, ZOff{1, (long)DK * BS, 0}, BS,
        EWfull + VN, ZOff{1, BS, 0}, CNP, NTOK, BS, DK);
    bias_k<<<dim3(1), blk, 0, stream>>>(enc_b, Wk_in, kbf);
    bias_c_kernel<<<dim3(3), blk, 0, stream>>>(enc_b, Wv_in, kbf, WqT, bias_c);
    cvt_split_ew<<<dim3((CNP * NTOK + 255) / 256), blk, 0, stream>>>(EWfull, B_vkap);
    cvt_split_bu2<<<dim3((HH * UN2P * UK0 + 255) / 256), blk, 0, stream>>>(W_ih, B_U);
    cvt_dec<<<dim3((NTOK * DECKP + 255) / 256), blk, 0, stream>>>(dec_W, B_dec);

    const float* hp = h0;
    float* hbufs[2] = { hA, hB };
    int t = 0;
    for (int c = 0; c < NCH; c++) {
        cvt_split_in<<<dim3(2048), blk, 0, stream>>>(
            input + (size_t)c * MU * NTOK, A_in, MU);
        gemm6_kv<<<dim3(CNP / 128, MU / 128, 1), blk, 0, stream>>>(
            A_in, B_vkap, A_U, Kbuf, bias_c, KV0, MU);
        gemm6<<<dim3(UN2P / 128, MU / 128, HH), blk, 0, stream>>>(
            A_U, (long)MU * 3 * UK0, 1, B_U, (long)UN2P * 3 * UK0,
            Ubuf, (long)MU * UN2, UN2, UN2, nullptr, UK0);
        for (int s = 0; s < C; s++, t++) {
            float* hout = hbufs[t & 1];
            step_fused<<<dim3(BATCH / SW), dim3(1024), 0, stream>>>(
                hp, masks + (size_t)t * BATCH, Kbuf, Ubuf, b_ih, b_hh, Whh4,
                Wq_c, Wk_c, Wv_c, Wo_c, hout, A_dec, s, MU);
            hp = hout;
        }
        gemm_mfma<<<dim3(NTOK / 128, MU / 128, 1), blk, 0, stream>>>(
            A_dec, B_dec, out + (size_t)c * MU * NTOK, NTOK, dec_b, DECKP);
    }
}